// Round 3
// baseline (832.862 us; speedup 1.0000x reference)
//
#include <hip/hip_runtime.h>

typedef unsigned short u16;
typedef short s16x8 __attribute__((ext_vector_type(8)));
typedef float f32x4 __attribute__((ext_vector_type(4)));
typedef const __attribute__((address_space(1))) unsigned int* as1_u32p;
typedef __attribute__((address_space(3))) unsigned int* as3_u32p;

static_assert(sizeof(s16x8) == 16, "");

struct alignas(8) U16x4 { u16 x, y, z, w; };

__device__ __forceinline__ u16 f2bf(float f) {
  union { float f; unsigned u; } c; c.f = f;
  return (u16)((c.u + 0x7fffu + ((c.u >> 16) & 1u)) >> 16);
}
__device__ __forceinline__ float bf2f(u16 h) {
  union { unsigned u; float f; } c; c.u = ((unsigned)h) << 16;
  return c.f;
}
__device__ __forceinline__ void async16(const void* g, void* l) {
  __builtin_amdgcn_global_load_lds((as1_u32p)g, (as3_u32p)l, 16, 0, 0);
}

// ---------------- fp32 -> bf16 flat convert ----------------
__launch_bounds__(256)
__global__ void cvt_bf16(const float* __restrict__ in, u16* __restrict__ out, long n) {
  long i = ((long)blockIdx.x * 256 + threadIdx.x) * 8;
  if (i >= n) return;
  float4 a = *(const float4*)(in + i);
  float4 b = *(const float4*)(in + i + 4);
  U16x4 o0{f2bf(a.x), f2bf(a.y), f2bf(a.z), f2bf(a.w)};
  U16x4 o1{f2bf(b.x), f2bf(b.y), f2bf(b.z), f2bf(b.w)};
  *(U16x4*)(out + i) = o0;
  *(U16x4*)(out + i + 4) = o1;
}

// ---------------- pack 3 biases into one 9216 vector ----------------
__launch_bounds__(256)
__global__ void pack_bias(const float* __restrict__ a, const float* __restrict__ b,
                          const float* __restrict__ c, float* __restrict__ out) {
  int i = blockIdx.x * 256 + threadIdx.x;
  if (i >= 9216) return;
  out[i] = (i < 3072) ? a[i] : (i < 6144) ? b[i - 3072] : c[i - 6144];
}

// ---------------- weight transpose: W(K=3072,N=3072) f32 -> W^T(N,K) bf16 ----------------
struct WTArgs { const float* src[3]; u16* dst[3]; };

__launch_bounds__(256)
__global__ void transpose_w(WTArgs args) {
  const float* src = args.src[blockIdx.z];
  u16* dst = args.dst[blockIdx.z];
  __shared__ float tile[32][33];
  int k0 = blockIdx.x * 32, n0 = blockIdx.y * 32;
  int r = threadIdx.x >> 3, c4 = (threadIdx.x & 7) * 4;
  float4 v = *(const float4*)(src + (long)(k0 + r) * 3072 + n0 + c4);
  tile[r][c4 + 0] = v.x; tile[r][c4 + 1] = v.y;
  tile[r][c4 + 2] = v.z; tile[r][c4 + 3] = v.w;
  __syncthreads();
  U16x4 o{f2bf(tile[c4 + 0][r]), f2bf(tile[c4 + 1][r]),
          f2bf(tile[c4 + 2][r]), f2bf(tile[c4 + 3][r])};
  *(U16x4*)(dst + (long)(n0 + r) * 3072 + k0 + c4) = o;
}

// ---------------- bf16 head transpose (T,128)->(128,T) per head ----------------
__launch_bounds__(256)
__global__ void transpose_v(const u16* __restrict__ VB, u16* __restrict__ VT, int T) {
  __shared__ u16 tile[32][34];
  int h = blockIdx.z;
  int t0 = blockIdx.x * 32, d0 = blockIdx.y * 32;
  int r = threadIdx.x >> 3, c4 = (threadIdx.x & 7) * 4;
  U16x4 v = *(const U16x4*)(VB + ((long)h * T + t0 + r) * 128 + d0 + c4);
  tile[r][c4 + 0] = v.x; tile[r][c4 + 1] = v.y;
  tile[r][c4 + 2] = v.z; tile[r][c4 + 3] = v.w;
  __syncthreads();
  U16x4 o{tile[c4 + 0][r], tile[c4 + 1][r], tile[c4 + 2][r], tile[c4 + 3][r]};
  *(U16x4*)(VT + ((long)h * 128 + d0 + r) * T + t0 + c4) = o;
}

// ---------------- RMS + to_heads, fp32 input (IP path) ----------------
__launch_bounds__(256)
__global__ void rms_heads(const float* __restrict__ in, int ldin,
                          u16* __restrict__ out, int OT, int t0, int do_rms) {
  const int t = blockIdx.x;
  const int w = threadIdx.x >> 6, lane = threadIdx.x & 63;
#pragma unroll
  for (int hh = 0; hh < 6; ++hh) {
    int h = w * 6 + hh;
    const float* x = in + (long)t * ldin + h * 128 + lane * 2;
    float a = x[0], b = x[1];
    float scale = 1.f;
    if (do_rms) {
      float ss = a * a + b * b;
#pragma unroll
      for (int st = 1; st < 64; st <<= 1) ss += __shfl_xor(ss, st, 64);
      scale = rsqrtf(ss * (1.f / 128.f) + 1e-5f);
    }
    unsigned pa = f2bf(a * scale), pb = f2bf(b * scale);
    *(unsigned*)(out + ((long)h * OT + t0 + t) * 128 + lane * 2) = pa | (pb << 16);
  }
}

// ---------------- fused 3-way RMS/convert from fused (T,9216) bf16 projection ----------------
__launch_bounds__(256)
__global__ void rms3(const u16* __restrict__ in, u16* __restrict__ Qo,
                     u16* __restrict__ Ko, u16* __restrict__ Vo, int t0) {
  const int t = blockIdx.x;
  const int w = threadIdx.x >> 6, lane = threadIdx.x & 63;
#pragma unroll
  for (int seg = 0; seg < 3; ++seg) {
    u16* out = (seg == 0) ? Qo : (seg == 1) ? Ko : Vo;
#pragma unroll
    for (int hh = 0; hh < 6; ++hh) {
      int h = w * 6 + hh;
      unsigned pv = *(const unsigned*)(in + (long)t * 9216 + seg * 3072 + h * 128 + lane * 2);
      float a = bf2f((u16)(pv & 0xffff)), b = bf2f((u16)(pv >> 16));
      float scale = 1.f;
      if (seg < 2) {
        float ss = a * a + b * b;
#pragma unroll
        for (int st = 1; st < 64; st <<= 1) ss += __shfl_xor(ss, st, 64);
        scale = rsqrtf(ss * (1.f / 128.f) + 1e-5f);
      }
      unsigned pa = f2bf(a * scale), pb = f2bf(b * scale);
      *(unsigned*)(out + ((long)h * 2560 + t0 + t) * 128 + lane * 2) = pa | (pb << 16);
    }
  }
}

// ---------------- LoRA (single, fp32 out: final lp path) ----------------
__launch_bounds__(256)
__global__ void lora_dn(const float* __restrict__ X, int ldx,
                        const float* __restrict__ dn, float* __restrict__ t) {
  __shared__ float red[4][16];
  const int m = blockIdx.x;
  const float* xr = X + (long)m * ldx;
  float p[16];
#pragma unroll
  for (int r = 0; r < 16; ++r) p[r] = 0.f;
  for (int k = threadIdx.x; k < 3072; k += 256) {
    float a = xr[k];
    const float* d = dn + (long)k * 16;
#pragma unroll
    for (int r = 0; r < 16; ++r) p[r] += a * d[r];
  }
#pragma unroll
  for (int r = 0; r < 16; ++r)
#pragma unroll
    for (int st = 1; st < 64; st <<= 1) p[r] += __shfl_xor(p[r], st, 64);
  int lane = threadIdx.x & 63, w = threadIdx.x >> 6;
  if (lane == 0) {
#pragma unroll
    for (int r = 0; r < 16; ++r) red[w][r] = p[r];
  }
  __syncthreads();
  if (threadIdx.x < 16) {
    int r = threadIdx.x;
    t[(long)m * 16 + r] = red[0][r] + red[1][r] + red[2][r] + red[3][r];
  }
}

__launch_bounds__(256)
__global__ void lora_up(const float* __restrict__ t, const float* __restrict__ up,
                        float* __restrict__ Y, int ldy) {
  const int m = blockIdx.x;
  float tv[16];
#pragma unroll
  for (int r = 0; r < 16; ++r) tv[r] = t[(long)m * 16 + r];
  float* yr = Y + (long)m * ldy;
  for (int n = threadIdx.x; n < 3072; n += 256) {
    float a = 0.f;
#pragma unroll
    for (int r = 0; r < 16; ++r) a += tv[r] * up[(long)r * 3072 + n];
    yr[n] += a;
  }
}

// ---------------- fused 3-way LoRA (q,k,v): one X pass -> t[m][48] ----------------
__launch_bounds__(256)
__global__ void lora_dn3(const float* __restrict__ X, int ldx,
                         const float* __restrict__ d0, const float* __restrict__ d1,
                         const float* __restrict__ d2, float* __restrict__ t) {
  __shared__ float red[4][48];
  const int m = blockIdx.x;
  const float* xr = X + (long)m * ldx;
  float p[48];
#pragma unroll
  for (int r = 0; r < 48; ++r) p[r] = 0.f;
  for (int k = threadIdx.x; k < 3072; k += 256) {
    float a = xr[k];
    const float* e0 = d0 + (long)k * 16;
    const float* e1 = d1 + (long)k * 16;
    const float* e2 = d2 + (long)k * 16;
#pragma unroll
    for (int r = 0; r < 16; ++r) {
      p[r]      += a * e0[r];
      p[16 + r] += a * e1[r];
      p[32 + r] += a * e2[r];
    }
  }
#pragma unroll
  for (int r = 0; r < 48; ++r)
#pragma unroll
    for (int st = 1; st < 64; st <<= 1) p[r] += __shfl_xor(p[r], st, 64);
  int lane = threadIdx.x & 63, w = threadIdx.x >> 6;
  if (lane == 0) {
#pragma unroll
    for (int r = 0; r < 48; ++r) red[w][r] = p[r];
  }
  __syncthreads();
  if (threadIdx.x < 48) {
    int r = threadIdx.x;
    t[(long)m * 48 + r] = red[0][r] + red[1][r] + red[2][r] + red[3][r];
  }
}

// adds into the fused (m,9216) bf16 projection, all 3 segments
__launch_bounds__(256)
__global__ void lora_up3_bf(const float* __restrict__ t,
                            const float* __restrict__ u0, const float* __restrict__ u1,
                            const float* __restrict__ u2, u16* __restrict__ Y) {
  const int m = blockIdx.x;
  float tv[48];
#pragma unroll
  for (int r = 0; r < 48; ++r) tv[r] = t[(long)m * 48 + r];
  u16* yr = Y + (long)m * 9216;
  for (int n = threadIdx.x; n < 3072; n += 256) {
    float a0 = 0.f, a1 = 0.f, a2 = 0.f;
#pragma unroll
    for (int r = 0; r < 16; ++r) {
      a0 += tv[r]      * u0[(long)r * 3072 + n];
      a1 += tv[16 + r] * u1[(long)r * 3072 + n];
      a2 += tv[32 + r] * u2[(long)r * 3072 + n];
    }
    yr[n]        = f2bf(bf2f(yr[n]) + a0);
    yr[3072 + n] = f2bf(bf2f(yr[3072 + n]) + a1);
    yr[6144 + n] = f2bf(bf2f(yr[6144 + n]) + a2);
  }
}

// ---------------- 128-tile GEMM (small grids): C = A @ B^T + bias ----------------
template <int BM, int MI, int NI, int OUTBF>
__launch_bounds__(256)
__global__ void gemm_bf16(const u16* __restrict__ A, int lda,
                          const u16* __restrict__ B, int ldb,
                          void* __restrict__ Cv, int ldc,
                          const float* __restrict__ bias, int K) {
  constexpr int WCOLS = 128 / (NI * 16);
  constexpr int ABYTES = BM * 128;
  __shared__ char smem[ABYTES + 128 * 128];
  char* As = smem;
  char* Bs = smem + ABYTES;
  const int tid = threadIdx.x;
  const int w = tid >> 6, lane = tid & 63;
  const int lr = lane & 15, lg = lane >> 4;
  const int wr = w / WCOLS, wc = w % WCOLS;
  const int nbx = gridDim.x;
  const int nwg = nbx * gridDim.y;
  const int flat = blockIdx.y * nbx + blockIdx.x;
  const int swz = (flat & 7) * (nwg >> 3) + (flat >> 3);
  const long m0 = (long)(swz % nbx) * BM;
  const long n0 = (long)(swz / nbx) * 128;
  f32x4 acc[MI][NI] = {};
  constexpr int ACH = BM / 32;
  for (int kb = 0; kb < K; kb += 64) {
    __syncthreads();
#pragma unroll
    for (int i = 0; i < ACH; ++i) {
      int x = (tid + 256 * i) * 16;
      int row = x >> 7;
      int sx = x ^ ((row & 7) << 4);
      async16((const char*)(A + (m0 + row) * lda + kb) + (sx & 127),
              As + ((w << 10) + (i << 12)));
    }
#pragma unroll
    for (int i = 0; i < 4; ++i) {
      int x = (tid + 256 * i) * 16;
      int row = x >> 7;
      int sx = x ^ ((row & 7) << 4);
      async16((const char*)(B + (n0 + row) * ldb + kb) + (sx & 127),
              Bs + ((w << 10) + (i << 12)));
    }
    __syncthreads();
#pragma unroll
    for (int kc = 0; kc < 2; ++kc) {
      s16x8 af[MI], bfr[NI];
#pragma unroll
      for (int mi = 0; mi < MI; ++mi) {
        int row = wr * (MI * 16) + mi * 16 + lr;
        int b = ((row << 7) + kc * 64 + lg * 16) ^ ((row & 7) << 4);
        af[mi] = *(const s16x8*)(As + b);
      }
#pragma unroll
      for (int ni = 0; ni < NI; ++ni) {
        int row = wc * (NI * 16) + ni * 16 + lr;
        int b = ((row << 7) + kc * 64 + lg * 16) ^ ((row & 7) << 4);
        bfr[ni] = *(const s16x8*)(Bs + b);
      }
#pragma unroll
      for (int mi = 0; mi < MI; ++mi)
#pragma unroll
        for (int ni = 0; ni < NI; ++ni)
          acc[mi][ni] = __builtin_amdgcn_mfma_f32_16x16x32_bf16(af[mi], bfr[ni], acc[mi][ni], 0, 0, 0);
    }
  }
#pragma unroll
  for (int mi = 0; mi < MI; ++mi) {
#pragma unroll
    for (int ni = 0; ni < NI; ++ni) {
      long col = n0 + wc * (NI * 16) + ni * 16 + lr;
      float bv = bias ? bias[col] : 0.f;
#pragma unroll
      for (int j = 0; j < 4; ++j) {
        long row = m0 + wr * (MI * 16) + mi * 16 + lg * 4 + j;
        if (OUTBF)
          ((u16*)Cv)[row * ldc + col] = f2bf(acc[mi][ni][j] + bv);
        else
          ((float*)Cv)[row * ldc + col] = acc[mi][ni][j] + bv;
      }
    }
  }
}

// ---------------- 256x256 8-wave GEMM, counted-vmcnt pipeline (T3+T4+T5) ----------------
// 512 threads = 8 waves (2M x 4N), per-wave 128x64 output, BK=64.
// LDS 128KB: A[2 buf][256r][128B] + B[2 buf][256r][128B], XOR-swizzled.
// Raw s_barrier + s_waitcnt vmcnt(8): next K-tile's 8 loads stay in flight
// across barriers (no full drain in the main loop).
template <int OUTBF>
__launch_bounds__(512, 2)
__global__ void gemm256(const u16* __restrict__ A, int lda,
                        const u16* __restrict__ B, int ldb,
                        void* __restrict__ Cv, int ldc,
                        const float* __restrict__ bias, int K) {
  __shared__ char smem[131072];
  const int tid = threadIdx.x, w = tid >> 6, lane = tid & 63;
  const int lr = lane & 15, lg = lane >> 4;
  const int wr = w >> 2, wc = w & 3;
  const int nbx = gridDim.x;
  const int nwg = nbx * gridDim.y;
  const int flat = blockIdx.y * nbx + blockIdx.x;
  const int swz = (flat & 7) * (nwg >> 3) + (flat >> 3);
  const long m0 = (long)(swz % nbx) * 256;
  const long n0 = (long)(swz / nbx) * 256;
  f32x4 acc[8][4] = {};

  auto stage = [&](int kb, int buf) {
#pragma unroll
    for (int i = 0; i < 4; ++i) {  // A: 256 rows x 128B
      int x = (tid + 512 * i) * 16;
      int row = x >> 7;
      int sx = (x & 127) ^ ((row & 7) << 4);
      async16((const char*)(A + (m0 + row) * lda + kb) + sx,
              smem + buf * 32768 + (i << 13) + (w << 10));
    }
#pragma unroll
    for (int i = 0; i < 4; ++i) {  // B: 256 rows x 128B
      int x = (tid + 512 * i) * 16;
      int row = x >> 7;
      int sx = (x & 127) ^ ((row & 7) << 4);
      async16((const char*)(B + (n0 + row) * ldb + kb) + sx,
              smem + 65536 + buf * 32768 + (i << 13) + (w << 10));
    }
  };

  stage(0, 0);
  const int NT = K >> 6;
  for (int kt = 0; kt < NT; ++kt) {
    const int cur = kt & 1;
    if (kt + 1 < NT) {
      stage((kt + 1) << 6, cur ^ 1);
      asm volatile("s_waitcnt vmcnt(8)" ::: "memory");
    } else {
      asm volatile("s_waitcnt vmcnt(0)" ::: "memory");
    }
    __builtin_amdgcn_sched_barrier(0);
    __builtin_amdgcn_s_barrier();
    __builtin_amdgcn_sched_barrier(0);
    const char* As = smem + cur * 32768;
    const char* Bs = smem + 65536 + cur * 32768;
#pragma unroll
    for (int kc = 0; kc < 2; ++kc) {
      s16x8 af[8], bfr[4];
#pragma unroll
      for (int mi = 0; mi < 8; ++mi) {
        int row = wr * 128 + mi * 16 + lr;
        af[mi] = *(const s16x8*)(As + ((row << 7) + ((kc * 64 + lg * 16) ^ ((row & 7) << 4))));
      }
#pragma unroll
      for (int ni = 0; ni < 4; ++ni) {
        int row = wc * 64 + ni * 16 + lr;
        bfr[ni] = *(const s16x8*)(Bs + ((row << 7) + ((kc * 64 + lg * 16) ^ ((row & 7) << 4))));
      }
      __builtin_amdgcn_s_setprio(1);
#pragma unroll
      for (int mi = 0; mi < 8; ++mi)
#pragma unroll
        for (int ni = 0; ni < 4; ++ni)
          acc[mi][ni] = __builtin_amdgcn_mfma_f32_16x16x32_bf16(af[mi], bfr[ni], acc[mi][ni], 0, 0, 0);
      __builtin_amdgcn_s_setprio(0);
    }
    __builtin_amdgcn_sched_barrier(0);
    __builtin_amdgcn_s_barrier();
    __builtin_amdgcn_sched_barrier(0);
  }
#pragma unroll
  for (int mi = 0; mi < 8; ++mi) {
#pragma unroll
    for (int ni = 0; ni < 4; ++ni) {
      long col = n0 + wc * 64 + ni * 16 + lr;
      float bv = bias ? bias[col] : 0.f;
#pragma unroll
      for (int j = 0; j < 4; ++j) {
        long row = m0 + wr * 128 + mi * 16 + lg * 4 + j;
        if (OUTBF)
          ((u16*)Cv)[row * ldc + col] = f2bf(acc[mi][ni][j] + bv);
        else
          ((float*)Cv)[row * ldc + col] = acc[mi][ni][j] + bv;
      }
    }
  }
}

// ---------------- main masked attention (static-max softmax, dbuf KV) ----------------
__launch_bounds__(256)
__global__ void attn_main(const u16* __restrict__ QB, const u16* __restrict__ KB,
                          const u16* __restrict__ VT, u16* __restrict__ OutTok) {
  __shared__ char smem[73728];
  const int tid = threadIdx.x, w = tid >> 6, lane = tid & 63;
  const int lr = lane & 15, lg = lane >> 4;
  const int h = blockIdx.y;
  const int q0 = blockIdx.x * 64;
  const u16* Qrow = QB + (long)(h * 2560 + q0 + w * 16 + lr) * 128;
  s16x8 qf[4];
#pragma unroll
  for (int dc = 0; dc < 4; ++dc) qf[dc] = *(const s16x8*)(Qrow + dc * 32 + lg * 8);
  f32x4 accO[8] = {};
  float l_r[4] = {0.f, 0.f, 0.f, 0.f};
  const int kv0 = (q0 >= 1536) ? 1536 : 0;
  const float sc = 0.08838834764831845f;

  auto stage = [&](int kv, int buf) {
#pragma unroll
    for (int i = 0; i < 4; ++i) {
      int x = (tid + 256 * i) * 16;
      int row = x >> 8;
      int sx = x ^ ((row & 7) << 4);
      async16((const char*)(KB + (long)(h * 2560 + kv + row) * 128) + (sx & 255),
              smem + buf * 16384 + ((w << 10) + (i << 12)));
    }
#pragma unroll
    for (int i = 0; i < 4; ++i) {
      int x = (tid + 256 * i) * 16;
      int row = x >> 7;
      int sx = x ^ ((row & 7) << 4);
      async16((const char*)(VT + (long)(h * 128 + row) * 2560 + kv) + (sx & 127),
              smem + 32768 + buf * 16384 + ((w << 10) + (i << 12)));
    }
  };

  stage(kv0, 0);
  __syncthreads();
  int cur = 0;
  for (int kv = kv0; kv < 2560; kv += 64) {
    if (kv + 64 < 2560) stage(kv + 64, cur ^ 1);
    const char* Ks = smem + cur * 16384;
    const char* Vs = smem + 32768 + cur * 16384;
    char* Pw = smem + 65536 + w * 2048;
    f32x4 s[4] = {};
#pragma unroll
    for (int kt = 0; kt < 4; ++kt)
#pragma unroll
      for (int dc = 0; dc < 4; ++dc) {
        int row = kt * 16 + lr;
        int b = ((row << 8) + dc * 64 + lg * 16) ^ ((row & 7) << 4);
        s16x8 kf = *(const s16x8*)(Ks + b);
        s[kt] = __builtin_amdgcn_mfma_f32_16x16x32_bf16(qf[dc], kf, s[kt], 0, 0, 0);
      }
#pragma unroll
    for (int kt = 0; kt < 4; ++kt)
#pragma unroll
      for (int j = 0; j < 4; ++j) {
        float pv = __expf(fmaf(s[kt][j], sc, -12.0f));
        l_r[j] += pv;
        int prow = lg * 4 + j;
        int b = ((prow << 7) + (kt * 16 + lr) * 2) ^ ((prow & 7) << 4);
        *(u16*)(Pw + b) = f2bf(pv);
      }
    asm volatile("s_waitcnt lgkmcnt(0)" ::: "memory");
#pragma unroll
    for (int kc = 0; kc < 2; ++kc) {
      int pb = ((lr << 7) + kc * 64 + lg * 16) ^ ((lr & 7) << 4);
      s16x8 pf = *(const s16x8*)(Pw + pb);
#pragma unroll
      for (int dt = 0; dt < 8; ++dt) {
        int row = dt * 16 + lr;
        int b = ((row << 7) + kc * 64 + lg * 16) ^ ((row & 7) << 4);
        s16x8 vf = *(const s16x8*)(Vs + b);
        accO[dt] = __builtin_amdgcn_mfma_f32_16x16x32_bf16(pf, vf, accO[dt], 0, 0, 0);
      }
    }
    __syncthreads();
    cur ^= 1;
  }
#pragma unroll
  for (int j = 0; j < 4; ++j)
#pragma unroll
    for (int st = 1; st < 16; st <<= 1) l_r[j] += __shfl_xor(l_r[j], st, 16);
#pragma unroll
  for (int j = 0; j < 4; ++j) {
    float inv = 1.f / l_r[j];
    long tok = q0 + w * 16 + lg * 4 + j;
#pragma unroll
    for (int dt = 0; dt < 8; ++dt) {
      long col = h * 128 + dt * 16 + lr;
      OutTok[tok * 3072 + col] = f2bf(accO[dt][j] * inv);
    }
  }
}

// ---------------- IP attention (64 keys), static-max, adds into OutTok rows 512.. ----------------
__launch_bounds__(256)
__global__ void attn_ip(const u16* __restrict__ QB, const u16* __restrict__ KipB,
                        const u16* __restrict__ VipT, u16* __restrict__ OutTok) {
  __shared__ char smem[40960];
  char* Ks = smem;
  char* Vs = smem + 16384;
  char* Ps = smem + 32768;
  const int tid = threadIdx.x, w = tid >> 6, lane = tid & 63;
  const int lr = lane & 15, lg = lane >> 4;
  const int h = blockIdx.y;
  const int q0 = blockIdx.x * 64;
  const u16* Qrow = QB + (long)(h * 2560 + 512 + q0 + w * 16 + lr) * 128;
  s16x8 qf[4];
#pragma unroll
  for (int dc = 0; dc < 4; ++dc) qf[dc] = *(const s16x8*)(Qrow + dc * 32 + lg * 8);
#pragma unroll
  for (int i = 0; i < 4; ++i) {
    int x = (tid + 256 * i) * 16;
    int row = x >> 8;
    int sx = x ^ ((row & 7) << 4);
    async16((const char*)(KipB + (long)(h * 64 + row) * 128) + (sx & 255),
            Ks + ((w << 10) + (i << 12)));
  }
#pragma unroll
  for (int i = 0; i < 4; ++i) {
    int x = (tid + 256 * i) * 16;
    int row = x >> 7;
    int sx = x ^ ((row & 7) << 4);
    async16((const char*)(VipT + (long)(h * 128 + row) * 64) + (sx & 127),
            Vs + ((w << 10) + (i << 12)));
  }
  __syncthreads();
  const float sc = 0.08838834764831845f;
  f32x4 s[4] = {};
#pragma unroll
  for (int kt = 0; kt < 4; ++kt)
#pragma unroll
    for (int dc = 0; dc < 4; ++dc) {
      int row = kt * 16 + lr;
      int b = ((row << 8) + dc * 64 + lg * 16) ^ ((row & 7) << 4);
      s16x8 kf = *(const s16x8*)(Ks + b);
      s[kt] = __builtin_amdgcn_mfma_f32_16x16x32_bf16(qf[dc], kf, s[kt], 0, 0, 0);
    }
  float l[4] = {0.f, 0.f, 0.f, 0.f}, p[4][4];
#pragma unroll
  for (int kt = 0; kt < 4; ++kt)
#pragma unroll
    for (int j = 0; j < 4; ++j) {
      float pv = __expf(fmaf(s[kt][j], sc, -12.0f));
      p[kt][j] = pv;
      l[j] += pv;
    }
#pragma unroll
  for (int j = 0; j < 4; ++j)
#pragma unroll
    for (int st = 1; st < 16; st <<= 1) l[j] += __shfl_xor(l[j], st, 16);
  char* Pw = Ps + w * 2048;
#pragma unroll
  for (int kt = 0; kt < 4; ++kt)
#pragma unroll
    for (int j = 0; j < 4; ++j) {
      int row = lg * 4 + j;
      int b = ((row << 7) + (kt * 16 + lr) * 2) ^ ((row & 7) << 4);
      *(u16*)(Pw + b) = f2bf(p[kt][j]);
    }
  asm volatile("s_waitcnt lgkmcnt(0)" ::: "memory");
  f32x4 accO[8] = {};
#pragma unroll
  for (int kc = 0; kc < 2; ++kc) {
    int pb = ((lr << 7) + kc * 64 + lg * 16) ^ ((lr & 7) << 4);
    s16x8 pf = *(const s16x8*)(Pw + pb);
#pragma unroll
    for (int dt = 0; dt < 8; ++dt) {
      int row = dt * 16 + lr;
      int b = ((row << 7) + kc * 64 + lg * 16) ^ ((row & 7) << 4);
      s16x8 vf = *(const s16x8*)(Vs + b);
      accO[dt] = __builtin_amdgcn_mfma_f32_16x16x32_bf16(pf, vf, accO[dt], 0, 0, 0);
    }
  }
#pragma unroll
  for (int j = 0; j < 4; ++j) {
    float inv = 1.f / l[j];
    long tok = 512 + q0 + w * 16 + lg * 4 + j;
#pragma unroll
    for (int dt = 0; dt < 8; ++dt) {
      long idx = tok * 3072 + h * 128 + dt * 16 + lr;
      OutTok[idx] = f2bf(bf2f(OutTok[idx]) + accO[dt][j] * inv);
    }
  }
}

// =====================================================================

extern "C" void kernel_launch(void* const* d_in, const int* in_sizes, int n_in,
                              void* d_out, int out_size, void* d_ws, size_t ws_size,
                              hipStream_t stream) {
  const float* hs    = (const float*)d_in[0];
  const float* ehs   = (const float*)d_in[1];
  const float* img   = (const float*)d_in[2];
  const float* Wq    = (const float*)d_in[3];
  const float* bq    = (const float*)d_in[4];
  const float* Wk    = (const float*)d_in[5];
  const float* bk    = (const float*)d_in[6];
  const float* Wv    = (const float*)d_in[7];
  const float* bv    = (const float*)d_in[8];
  const float* Waq   = (const float*)d_in[9];
  const float* baq   = (const float*)d_in[10];
  const float* Wak   = (const float*)d_in[11];
  const float* bak   = (const float*)d_in[12];
  const float* Wav   = (const float*)d_in[13];
  const float* bav   = (const float*)d_in[14];
  const float* Wo    = (const float*)d_in[15];
  const float* bo    = (const float*)d_in[16];
  const float* Wao   = (const float*)d_in[17];
  const float* bao   = (const float*)d_in[18];
  const float* Wkip  = (const float*)d_in[19];
  const float* Wvip  = (const float*)d_in[20];
  const float* lq_dn = (const float*)d_in[21];
  const float* lq_up = (const float*)d_in[22];
  const float* lk_dn = (const float*)d_in[23];
  const float* lk_up = (const float*)d_in[24];
  const float* lv_dn = (const float*)d_in[25];
  const float* lv_up = (const float*)d_in[26];
  const float* lp_dn = (const float*)d_in[27];
  const float* lp_up = (const float*)d_in[28];
  float* outp = (float*)d_out;

  char* ws = (char*)d_ws;
  size_t off = 0;
  auto take = [&](size_t b) { char* p = ws + off; off += (b + 255) & ~(size_t)255; return p; };
  u16*   WTb  = (u16*)take(9216LL * 3072 * 2);
  u16*   hsb  = (u16*)take(2048LL * 3072 * 2);
  u16*   ehsb = (u16*)take(512LL * 3072 * 2);
  u16*   imgb = (u16*)take(64LL * 3072 * 2);
  u16*   P0b  = (u16*)take(2048LL * 9216 * 2);
  float* IP0  = (float*)take(64LL * 6144 * 4);
  u16*   QBf  = (u16*)take(24LL * 2560 * 128 * 2);
  u16*   KBf  = (u16*)take(24LL * 2560 * 128 * 2);
  u16*   VBf  = (u16*)take(24LL * 2560 * 128 * 2);
  u16*   KipB = (u16*)take(24LL * 64 * 128 * 2);
  u16*   VipB = (u16*)take(24LL * 64 * 128 * 2);
  u16*   VipT = (u16*)take(24LL * 64 * 128 * 2);
  float* bpk  = (float*)take(9216 * 4);
  float* tl   = (float*)take(1024LL * 48 * 4);
  u16* VTf     = P0b;
  u16* AttnTok = (u16*)((char*)P0b + (16u << 20));

  // 1. convert activations
  cvt_bf16<<<3072, 256, 0, stream>>>(hs, hsb, 2048LL * 3072);
  cvt_bf16<<<768, 256, 0, stream>>>(ehs, ehsb, 512LL * 3072);
  cvt_bf16<<<96, 256, 0, stream>>>(img, imgb, 64LL * 3072);
  pack_bias<<<36, 256, 0, stream>>>(baq, bak, bav, bpk);

  // 2. encoder path: packed [Waq|Wak|Wav], fused N=9216 GEMM -> bf16
  {
    WTArgs a;
    a.src[0] = Waq; a.dst[0] = WTb;
    a.src[1] = Wak; a.dst[1] = WTb + 3072LL * 3072;
    a.src[2] = Wav; a.dst[2] = WTb + 2 * 3072LL * 3072;
    transpose_w<<<dim3(96, 96, 3), 256, 0, stream>>>(a);
  }
  gemm_bf16<128, 4, 4, 1><<<dim3(4, 72), 256, 0, stream>>>(ehsb, 3072, WTb, 3072, P0b, 9216, bpk, 3072);
  rms3<<<512, 256, 0, stream>>>(P0b, QBf, KBf, VBf, 0);

  // 3. IP projections: packed [Wkip|Wvip]
  {
    WTArgs a;
    a.src[0] = Wkip; a.dst[0] = WTb;
    a.src[1] = Wvip; a.dst[1] = WTb + 3072LL * 3072;
    a.src[2] = Wkip; a.dst[2] = WTb;  // unused
    transpose_w<<<dim3(96, 96, 2), 256, 0, stream>>>(a);
  }
  gemm_bf16<64, 4, 2, 0><<<dim3(1, 48), 256, 0, stream>>>(imgb, 3072, WTb, 3072, IP0, 6144, nullptr, 3072);
  rms_heads<<<64, 256, 0, stream>>>(IP0, 6144, KipB, 64, 0, 1);
  rms_heads<<<64, 256, 0, stream>>>(IP0 + 3072, 6144, VipB, 64, 0, 0);
  transpose_v<<<dim3(2, 4, 24), 256, 0, stream>>>(VipB, VipT, 64);

  // 4. main q/k/v: packed [Wq|Wk|Wv], ONE fused 256-tile GEMM (8-wave pipeline)
  {
    WTArgs a;
    a.src[0] = Wq; a.dst[0] = WTb;
    a.src[1] = Wk; a.dst[1] = WTb + 3072LL * 3072;
    a.src[2] = Wv; a.dst[2] = WTb + 2 * 3072LL * 3072;
    transpose_w<<<dim3(96, 96, 3), 256, 0, stream>>>(a);
  }
  pack_bias<<<36, 256, 0, stream>>>(bq, bk, bv, bpk);
  gemm256<1><<<dim3(8, 36), 512, 0, stream>>>(hsb, 3072, WTb, 3072, P0b, 9216, bpk, 3072);
  // fused 3-way LoRA add (rows 1024.., per-segment columns)
  lora_dn3<<<1024, 256, 0, stream>>>(hs + 1024LL * 3072, 3072, lq_dn, lk_dn, lv_dn, tl);
  lora_up3_bf<<<1024, 256, 0, stream>>>(tl, lq_up, lk_up, lv_up, P0b + 1024LL * 9216);
  rms3<<<2048, 256, 0, stream>>>(P0b, QBf, KBf, VBf, 512);
  transpose_v<<<dim3(80, 4, 24), 256, 0, stream>>>(VBf, VTf, 2560);

  // 5. attention
  attn_main<<<dim3(40, 24), 256, 0, stream>>>(QBf, KBf, VTf, AttnTok);
  attn_ip<<<dim3(32, 24), 256, 0, stream>>>(QBf, KipB, VipT, AttnTok);

  // 6. output projections: packed [Wao|Wo]
  {
    WTArgs a;
    a.src[0] = Wao; a.dst[0] = WTb;
    a.src[1] = Wo;  a.dst[1] = WTb + 3072LL * 3072;
    a.src[2] = Wao; a.dst[2] = WTb;  // unused
    transpose_w<<<dim3(96, 96, 2), 256, 0, stream>>>(a);
  }
  gemm_bf16<128, 4, 4, 0><<<dim3(4, 24), 256, 0, stream>>>(AttnTok, 3072, WTb, 3072, outp, 3072, bao, 3072);
  gemm_bf16<128, 4, 4, 0><<<dim3(16, 24), 256, 0, stream>>>(AttnTok + 512LL * 3072, 3072, WTb + 3072LL * 3072, 3072,
                                                            outp + 512LL * 3072, 3072, bo, 3072);
  // 7. final LoRA on post-projection main (rows 1536.. of output)
  lora_dn<<<1024, 256, 0, stream>>>(outp + 1536LL * 3072, 3072, lp_dn, tl);
  lora_up<<<1024, 256, 0, stream>>>(tl, lp_up, outp + 1536LL * 3072, 3072);
}

// Round 4
// 670.322 us; speedup vs baseline: 1.2425x; 1.2425x over previous
//
#include <hip/hip_runtime.h>

typedef unsigned short u16;
typedef short s16x8 __attribute__((ext_vector_type(8)));
typedef float f32x4 __attribute__((ext_vector_type(4)));
typedef const __attribute__((address_space(1))) unsigned int* as1_u32p;
typedef __attribute__((address_space(3))) unsigned int* as3_u32p;

static_assert(sizeof(s16x8) == 16, "");

struct alignas(8) U16x4 { u16 x, y, z, w; };

__device__ __forceinline__ u16 f2bf(float f) {
  union { float f; unsigned u; } c; c.f = f;
  return (u16)((c.u + 0x7fffu + ((c.u >> 16) & 1u)) >> 16);
}
__device__ __forceinline__ float bf2f(u16 h) {
  union { unsigned u; float f; } c; c.u = ((unsigned)h) << 16;
  return c.f;
}
__device__ __forceinline__ void async16(const void* g, void* l) {
  __builtin_amdgcn_global_load_lds((as1_u32p)g, (as3_u32p)l, 16, 0, 0);
}

// ---------------- fp32 -> bf16 flat convert (ehs, img) ----------------
__launch_bounds__(256)
__global__ void cvt_bf16(const float* __restrict__ in, u16* __restrict__ out, long n) {
  long i = ((long)blockIdx.x * 256 + threadIdx.x) * 8;
  if (i >= n) return;
  float4 a = *(const float4*)(in + i);
  float4 b = *(const float4*)(in + i + 4);
  U16x4 o0{f2bf(a.x), f2bf(a.y), f2bf(a.z), f2bf(a.w)};
  U16x4 o1{f2bf(b.x), f2bf(b.y), f2bf(b.z), f2bf(b.w)};
  *(U16x4*)(out + i) = o0;
  *(U16x4*)(out + i + 4) = o1;
}

// ---------------- hs convert into K=3136-strided buffer with LoRA-t tail ----------------
// hsb[m][0..3072) = bf16(hs[m]); hsb[m][3072+i] = (m>=1024 && i<48) ? bf16(tl[m-1024][i]) : 0
__launch_bounds__(256)
__global__ void cvt_hs(const float* __restrict__ hs, const float* __restrict__ tl,
                       u16* __restrict__ hsb) {
  long idx = (long)blockIdx.x * 256 + threadIdx.x;  // chunk of 8
  long m = idx / 392, c = idx % 392;
  U16x4 o0, o1;
  if (c < 384) {
    const float* p = hs + m * 3072 + c * 8;
    float4 a = *(const float4*)p;
    float4 b = *(const float4*)(p + 4);
    o0 = U16x4{f2bf(a.x), f2bf(a.y), f2bf(a.z), f2bf(a.w)};
    o1 = U16x4{f2bf(b.x), f2bf(b.y), f2bf(b.z), f2bf(b.w)};
  } else {
    u16 t[8];
#pragma unroll
    for (int i = 0; i < 8; ++i) {
      int r = (int)(c - 384) * 8 + i;
      float v = (m >= 1024 && r < 48) ? tl[(m - 1024) * 48 + r] : 0.f;
      t[i] = f2bf(v);
    }
    o0 = U16x4{t[0], t[1], t[2], t[3]};
    o1 = U16x4{t[4], t[5], t[6], t[7]};
  }
  u16* d = hsb + m * 3136 + c * 8;
  *(U16x4*)d = o0;
  *(U16x4*)(d + 4) = o1;
}

// ---------------- pack 3 biases into one 9216 vector ----------------
__launch_bounds__(256)
__global__ void pack_bias(const float* __restrict__ a, const float* __restrict__ b,
                          const float* __restrict__ c, float* __restrict__ out) {
  int i = blockIdx.x * 256 + threadIdx.x;
  if (i >= 9216) return;
  out[i] = (i < 3072) ? a[i] : (i < 6144) ? b[i - 3072] : c[i - 6144];
}

// ---------------- weight transpose: W(K=3072,N=3072) f32 -> W^T(N,K)bf16 at ld ldd ----------------
struct WTArgs { const float* src[3]; u16* dst[3]; };

__launch_bounds__(256)
__global__ void transpose_w(WTArgs args, int ldd) {
  const float* src = args.src[blockIdx.z];
  u16* dst = args.dst[blockIdx.z];
  __shared__ float tile[32][33];
  int k0 = blockIdx.x * 32, n0 = blockIdx.y * 32;
  int r = threadIdx.x >> 3, c4 = (threadIdx.x & 7) * 4;
  float4 v = *(const float4*)(src + (long)(k0 + r) * 3072 + n0 + c4);
  tile[r][c4 + 0] = v.x; tile[r][c4 + 1] = v.y;
  tile[r][c4 + 2] = v.z; tile[r][c4 + 3] = v.w;
  __syncthreads();
  U16x4 o{f2bf(tile[c4 + 0][r]), f2bf(tile[c4 + 1][r]),
          f2bf(tile[c4 + 2][r]), f2bf(tile[c4 + 3][r])};
  *(U16x4*)(dst + (long)(n0 + r) * ldd + k0 + c4) = o;
}

// ---------------- B-tail fill: WTb[n][3072+i] = seg-matched up[r][n%3072] else 0 ----------------
__launch_bounds__(256)
__global__ void fill_wtail(const float* __restrict__ u0, const float* __restrict__ u1,
                           const float* __restrict__ u2, u16* __restrict__ WTb) {
  int idx = blockIdx.x * 256 + threadIdx.x;  // over 9216*64
  int n = idx >> 6, i = idx & 63;
  int seg = n / 3072;
  const float* up = (seg == 0) ? u0 : (seg == 1) ? u1 : u2;
  int r = i - seg * 16;
  float v = (r >= 0 && r < 16) ? up[(long)r * 3072 + (n - seg * 3072)] : 0.f;
  WTb[(long)n * 3136 + 3072 + i] = f2bf(v);
}

// ---------------- bf16 head transpose (T,128)->(128,T) per head (Vip only) ----------------
__launch_bounds__(256)
__global__ void transpose_v(const u16* __restrict__ VB, u16* __restrict__ VT, int T) {
  __shared__ u16 tile[32][34];
  int h = blockIdx.z;
  int t0 = blockIdx.x * 32, d0 = blockIdx.y * 32;
  int r = threadIdx.x >> 3, c4 = (threadIdx.x & 7) * 4;
  U16x4 v = *(const U16x4*)(VB + ((long)h * T + t0 + r) * 128 + d0 + c4);
  tile[r][c4 + 0] = v.x; tile[r][c4 + 1] = v.y;
  tile[r][c4 + 2] = v.z; tile[r][c4 + 3] = v.w;
  __syncthreads();
  U16x4 o{tile[c4 + 0][r], tile[c4 + 1][r], tile[c4 + 2][r], tile[c4 + 3][r]};
  *(U16x4*)(VT + ((long)h * 128 + d0 + r) * T + t0 + c4) = o;
}

// ---------------- IP: sum 4 K-split partials + RMS + to_heads ----------------
// in: 4 partials of (64,6144) at stride 64*6144; this call reads col offset col0.
__launch_bounds__(256)
__global__ void rms_heads4(const float* __restrict__ in, int col0,
                           u16* __restrict__ out, int do_rms) {
  const int t = blockIdx.x;  // 64 tokens
  const int w = threadIdx.x >> 6, lane = threadIdx.x & 63;
  const long ps = 64LL * 6144;
#pragma unroll
  for (int hh = 0; hh < 6; ++hh) {
    int h = w * 6 + hh;
    const float* x = in + (long)t * 6144 + col0 + h * 128 + lane * 2;
    float a = x[0] + x[ps] + x[2 * ps] + x[3 * ps];
    float b = x[1] + x[1 + ps] + x[1 + 2 * ps] + x[1 + 3 * ps];
    float scale = 1.f;
    if (do_rms) {
      float ss = a * a + b * b;
#pragma unroll
      for (int st = 1; st < 64; st <<= 1) ss += __shfl_xor(ss, st, 64);
      scale = rsqrtf(ss * (1.f / 128.f) + 1e-5f);
    }
    unsigned pa = f2bf(a * scale), pb = f2bf(b * scale);
    *(unsigned*)(out + ((long)h * 64 + t) * 128 + lane * 2) = pa | (pb << 16);
  }
}

// ---------------- fused 3-way LoRA down: t[m][48] = hs_cond[m] @ [lq|lk|lv]_dn ----------------
__launch_bounds__(256)
__global__ void lora_dn3(const float* __restrict__ X, int ldx,
                         const float* __restrict__ d0, const float* __restrict__ d1,
                         const float* __restrict__ d2, float* __restrict__ t) {
  __shared__ float red[4][48];
  const int m = blockIdx.x;
  const float* xr = X + (long)m * ldx;
  float p[48];
#pragma unroll
  for (int r = 0; r < 48; ++r) p[r] = 0.f;
  for (int k = threadIdx.x; k < 3072; k += 256) {
    float a = xr[k];
    const float* e0 = d0 + (long)k * 16;
    const float* e1 = d1 + (long)k * 16;
    const float* e2 = d2 + (long)k * 16;
#pragma unroll
    for (int r = 0; r < 16; ++r) {
      p[r]      += a * e0[r];
      p[16 + r] += a * e1[r];
      p[32 + r] += a * e2[r];
    }
  }
#pragma unroll
  for (int r = 0; r < 48; ++r)
#pragma unroll
    for (int st = 1; st < 64; st <<= 1) p[r] += __shfl_xor(p[r], st, 64);
  int lane = threadIdx.x & 63, w = threadIdx.x >> 6;
  if (lane == 0) {
#pragma unroll
    for (int r = 0; r < 48; ++r) red[w][r] = p[r];
  }
  __syncthreads();
  if (threadIdx.x < 48) {
    int r = threadIdx.x;
    t[(long)m * 48 + r] = red[0][r] + red[1][r] + red[2][r] + red[3][r];
  }
}

// ---------------- single LoRA (final lp path, fp32) ----------------
__launch_bounds__(256)
__global__ void lora_dn(const float* __restrict__ X, int ldx,
                        const float* __restrict__ dn, float* __restrict__ t) {
  __shared__ float red[4][16];
  const int m = blockIdx.x;
  const float* xr = X + (long)m * ldx;
  float p[16];
#pragma unroll
  for (int r = 0; r < 16; ++r) p[r] = 0.f;
  for (int k = threadIdx.x; k < 3072; k += 256) {
    float a = xr[k];
    const float* d = dn + (long)k * 16;
#pragma unroll
    for (int r = 0; r < 16; ++r) p[r] += a * d[r];
  }
#pragma unroll
  for (int r = 0; r < 16; ++r)
#pragma unroll
    for (int st = 1; st < 64; st <<= 1) p[r] += __shfl_xor(p[r], st, 64);
  int lane = threadIdx.x & 63, w = threadIdx.x >> 6;
  if (lane == 0) {
#pragma unroll
    for (int r = 0; r < 16; ++r) red[w][r] = p[r];
  }
  __syncthreads();
  if (threadIdx.x < 16) {
    int r = threadIdx.x;
    t[(long)m * 16 + r] = red[0][r] + red[1][r] + red[2][r] + red[3][r];
  }
}

__launch_bounds__(256)
__global__ void lora_up(const float* __restrict__ t, const float* __restrict__ up,
                        float* __restrict__ Y, int ldy) {
  const int m = blockIdx.x;
  float tv[16];
#pragma unroll
  for (int r = 0; r < 16; ++r) tv[r] = t[(long)m * 16 + r];
  float* yr = Y + (long)m * ldy;
  for (int n = threadIdx.x; n < 3072; n += 256) {
    float a = 0.f;
#pragma unroll
    for (int r = 0; r < 16; ++r) a += tv[r] * up[(long)r * 3072 + n];
    yr[n] += a;
  }
}

// ---------------- generic 128-col-tile GEMM -> f32 (IP partials) ----------------
// grid z: K-chunk [z*KC, (z+1)*KC), C += z*cstride.
template <int BM, int MI, int NI>
__launch_bounds__(256)
__global__ void gemm_f32(const u16* __restrict__ A, int lda,
                         const u16* __restrict__ B, int ldb,
                         float* __restrict__ C, int ldc,
                         const float* __restrict__ bias, int KC, long cstride) {
  constexpr int WCOLS = 128 / (NI * 16);
  constexpr int ABYTES = BM * 128;
  __shared__ char smem[ABYTES + 128 * 128];
  char* As = smem;
  char* Bs = smem + ABYTES;
  const int tid = threadIdx.x;
  const int w = tid >> 6, lane = tid & 63;
  const int lr = lane & 15, lg = lane >> 4;
  const int wr = w / WCOLS, wc = w % WCOLS;
  const int nbx = gridDim.x;
  const int nwg = nbx * gridDim.y;
  const int flat = blockIdx.y * nbx + blockIdx.x;
  const int swz = (flat & 7) * (nwg >> 3) + (flat >> 3);
  const long m0 = (long)(swz % nbx) * BM;
  const long n0 = (long)(swz / nbx) * 128;
  const int k0 = blockIdx.z * KC;
  C += blockIdx.z * cstride;
  f32x4 acc[MI][NI] = {};
  constexpr int ACH = BM / 32;
  for (int kb = k0; kb < k0 + KC; kb += 64) {
    __syncthreads();
#pragma unroll
    for (int i = 0; i < ACH; ++i) {
      int x = (tid + 256 * i) * 16;
      int row = x >> 7;
      int sx = x ^ ((row & 7) << 4);
      async16((const char*)(A + (m0 + row) * lda + kb) + (sx & 127),
              As + ((w << 10) + (i << 12)));
    }
#pragma unroll
    for (int i = 0; i < 4; ++i) {
      int x = (tid + 256 * i) * 16;
      int row = x >> 7;
      int sx = x ^ ((row & 7) << 4);
      async16((const char*)(B + (n0 + row) * ldb + kb) + (sx & 127),
              Bs + ((w << 10) + (i << 12)));
    }
    __syncthreads();
#pragma unroll
    for (int kc = 0; kc < 2; ++kc) {
      s16x8 af[MI], bfr[NI];
#pragma unroll
      for (int mi = 0; mi < MI; ++mi) {
        int row = wr * (MI * 16) + mi * 16 + lr;
        int b = ((row << 7) + kc * 64 + lg * 16) ^ ((row & 7) << 4);
        af[mi] = *(const s16x8*)(As + b);
      }
#pragma unroll
      for (int ni = 0; ni < NI; ++ni) {
        int row = wc * (NI * 16) + ni * 16 + lr;
        int b = ((row << 7) + kc * 64 + lg * 16) ^ ((row & 7) << 4);
        bfr[ni] = *(const s16x8*)(Bs + b);
      }
#pragma unroll
      for (int mi = 0; mi < MI; ++mi)
#pragma unroll
        for (int ni = 0; ni < NI; ++ni)
          acc[mi][ni] = __builtin_amdgcn_mfma_f32_16x16x32_bf16(af[mi], bfr[ni], acc[mi][ni], 0, 0, 0);
    }
  }
#pragma unroll
  for (int mi = 0; mi < MI; ++mi) {
#pragma unroll
    for (int ni = 0; ni < NI; ++ni) {
      long col = n0 + wc * (NI * 16) + ni * 16 + lr;
      float bv = bias ? bias[col] : 0.f;
#pragma unroll
      for (int j = 0; j < 4; ++j) {
        long row = m0 + wr * (MI * 16) + mi * 16 + lg * 4 + j;
        C[row * ldc + col] = acc[mi][ni][j] + bv;
      }
    }
  }
}

// ---------------- QKV GEMM with fused epilogue: bias + RMS(Q,K) + head-split + V^T write ----------------
// C cols: [0,3072)=Q(rms), [3072,6144)=K(rms), [6144,9216)=V (transposed write).
// N-tile 128 = exactly one head. BM=128, MI=NI=4, WCOLS=2.
__launch_bounds__(256)
__global__ void gemm_qkv(const u16* __restrict__ A, int lda,
                         const u16* __restrict__ B, int ldb,
                         u16* __restrict__ Qo, u16* __restrict__ Ko, u16* __restrict__ VTo,
                         int t0, const float* __restrict__ bias, int K) {
  __shared__ char smem[128 * 128 + 128 * 128];
  char* As = smem;
  char* Bs = smem + 128 * 128;
  const int tid = threadIdx.x;
  const int w = tid >> 6, lane = tid & 63;
  const int lr = lane & 15, lg = lane >> 4;
  const int wr = w >> 1, wc = w & 1;
  const int nbx = gridDim.x;
  const int nwg = nbx * gridDim.y;
  const int flat = blockIdx.y * nbx + blockIdx.x;
  const int swz = (flat & 7) * (nwg >> 3) + (flat >> 3);
  const long m0 = (long)(swz % nbx) * 128;
  const long n0 = (long)(swz / nbx) * 128;
  f32x4 acc[4][4] = {};
  for (int kb = 0; kb < K; kb += 64) {
    __syncthreads();
#pragma unroll
    for (int i = 0; i < 4; ++i) {
      int x = (tid + 256 * i) * 16;
      int row = x >> 7;
      int sx = x ^ ((row & 7) << 4);
      async16((const char*)(A + (m0 + row) * lda + kb) + (sx & 127),
              As + ((w << 10) + (i << 12)));
    }
#pragma unroll
    for (int i = 0; i < 4; ++i) {
      int x = (tid + 256 * i) * 16;
      int row = x >> 7;
      int sx = x ^ ((row & 7) << 4);
      async16((const char*)(B + (n0 + row) * ldb + kb) + (sx & 127),
              Bs + ((w << 10) + (i << 12)));
    }
    __syncthreads();
#pragma unroll
    for (int kc = 0; kc < 2; ++kc) {
      s16x8 af[4], bfr[4];
#pragma unroll
      for (int mi = 0; mi < 4; ++mi) {
        int row = wr * 64 + mi * 16 + lr;
        int b = ((row << 7) + kc * 64 + lg * 16) ^ ((row & 7) << 4);
        af[mi] = *(const s16x8*)(As + b);
      }
#pragma unroll
      for (int ni = 0; ni < 4; ++ni) {
        int row = wc * 64 + ni * 16 + lr;
        int b = ((row << 7) + kc * 64 + lg * 16) ^ ((row & 7) << 4);
        bfr[ni] = *(const s16x8*)(Bs + b);
      }
#pragma unroll
      for (int mi = 0; mi < 4; ++mi)
#pragma unroll
        for (int ni = 0; ni < 4; ++ni)
          acc[mi][ni] = __builtin_amdgcn_mfma_f32_16x16x32_bf16(af[mi], bfr[ni], acc[mi][ni], 0, 0, 0);
    }
  }
  // ---- epilogue ----
  const int seg = (int)(n0 / 3072);
  const int head = (int)((n0 % 3072) >> 7);
#pragma unroll
  for (int ni = 0; ni < 4; ++ni) {
    float bv = bias[n0 + wc * 64 + ni * 16 + lr];
#pragma unroll
    for (int mi = 0; mi < 4; ++mi)
#pragma unroll
      for (int j = 0; j < 4; ++j) acc[mi][ni][j] += bv;
  }
  if (seg < 2) {
    u16* out = (seg == 0) ? Qo : Ko;
    float scl[4][4];
#pragma unroll
    for (int mi = 0; mi < 4; ++mi)
#pragma unroll
      for (int j = 0; j < 4; ++j) {
        float s = 0.f;
#pragma unroll
        for (int ni = 0; ni < 4; ++ni) s += acc[mi][ni][j] * acc[mi][ni][j];
#pragma unroll
        for (int st = 1; st < 16; st <<= 1) s += __shfl_xor(s, st, 16);
        scl[mi][j] = s;
      }
    __syncthreads();
    float* red = (float*)smem;
    if (lr == 0) {
#pragma unroll
      for (int mi = 0; mi < 4; ++mi)
#pragma unroll
        for (int j = 0; j < 4; ++j)
          red[((((wr * 4 + mi) * 4 + lg) * 4 + j) << 1) + wc] = scl[mi][j];
    }
    __syncthreads();
#pragma unroll
    for (int mi = 0; mi < 4; ++mi)
#pragma unroll
      for (int j = 0; j < 4; ++j) {
        int ix = (((wr * 4 + mi) * 4 + lg) * 4 + j) << 1;
        float t = red[ix] + red[ix + 1];
        scl[mi][j] = rsqrtf(t * (1.f / 128.f) + 1e-5f);
      }
#pragma unroll
    for (int mi = 0; mi < 4; ++mi)
#pragma unroll
      for (int ni = 0; ni < 4; ++ni) {
        int d = wc * 64 + ni * 16 + lr;
#pragma unroll
        for (int j = 0; j < 4; ++j) {
          long tok = t0 + m0 + wr * 64 + mi * 16 + lg * 4 + j;
          out[((long)head * 2560 + tok) * 128 + d] = f2bf(acc[mi][ni][j] * scl[mi][j]);
        }
      }
  } else {
#pragma unroll
    for (int mi = 0; mi < 4; ++mi)
#pragma unroll
      for (int ni = 0; ni < 4; ++ni) {
        long tok0 = t0 + m0 + wr * 64 + mi * 16 + lg * 4;
        int d = wc * 64 + ni * 16 + lr;
        U16x4 o{f2bf(acc[mi][ni][0]), f2bf(acc[mi][ni][1]),
                f2bf(acc[mi][ni][2]), f2bf(acc[mi][ni][3])};
        *(U16x4*)(VTo + ((long)head * 128 + d) * 2560 + tok0) = o;
      }
  }
}

// ---------------- fused output projection: enc(Wao) + main(Wo) in one dispatch ----------------
// grid (20,24): m-blocks 0..3 -> enc, 4..19 -> main. K=3072, ldb=3136.
__launch_bounds__(256)
__global__ void gemm_out(const u16* __restrict__ Atok, const u16* __restrict__ WT,
                         float* __restrict__ outp, const float* __restrict__ bao,
                         const float* __restrict__ bo) {
  __shared__ char smem[128 * 128 + 128 * 128];
  char* As = smem;
  char* Bs = smem + 128 * 128;
  const int tid = threadIdx.x;
  const int w = tid >> 6, lane = tid & 63;
  const int lr = lane & 15, lg = lane >> 4;
  const int wr = w >> 1, wc = w & 1;
  const int flat = blockIdx.y * 20 + blockIdx.x;
  const int swz = (flat & 7) * 60 + (flat >> 3);
  const int mx = swz % 20;
  const long n0 = (long)(swz / 20) * 128;
  const u16* A;
  const u16* B;
  const float* bias;
  float* C;
  long m0;
  if (mx < 4) { A = Atok; B = WT; bias = bao; C = outp; m0 = (long)mx * 128; }
  else { A = Atok + 512L * 3072; B = WT + 3072L * 3136; bias = bo; C = outp + 512L * 3072; m0 = (long)(mx - 4) * 128; }
  f32x4 acc[4][4] = {};
  for (int kb = 0; kb < 3072; kb += 64) {
    __syncthreads();
#pragma unroll
    for (int i = 0; i < 4; ++i) {
      int x = (tid + 256 * i) * 16;
      int row = x >> 7;
      int sx = x ^ ((row & 7) << 4);
      async16((const char*)(A + (m0 + row) * 3072 + kb) + (sx & 127),
              As + ((w << 10) + (i << 12)));
    }
#pragma unroll
    for (int i = 0; i < 4; ++i) {
      int x = (tid + 256 * i) * 16;
      int row = x >> 7;
      int sx = x ^ ((row & 7) << 4);
      async16((const char*)(B + (n0 + row) * 3136 + kb) + (sx & 127),
              Bs + ((w << 10) + (i << 12)));
    }
    __syncthreads();
#pragma unroll
    for (int kc = 0; kc < 2; ++kc) {
      s16x8 af[4], bfr[4];
#pragma unroll
      for (int mi = 0; mi < 4; ++mi) {
        int row = wr * 64 + mi * 16 + lr;
        int b = ((row << 7) + kc * 64 + lg * 16) ^ ((row & 7) << 4);
        af[mi] = *(const s16x8*)(As + b);
      }
#pragma unroll
      for (int ni = 0; ni < 4; ++ni) {
        int row = wc * 64 + ni * 16 + lr;
        int b = ((row << 7) + kc * 64 + lg * 16) ^ ((row & 7) << 4);
        bfr[ni] = *(const s16x8*)(Bs + b);
      }
#pragma unroll
      for (int mi = 0; mi < 4; ++mi)
#pragma unroll
        for (int ni = 0; ni < 4; ++ni)
          acc[mi][ni] = __builtin_amdgcn_mfma_f32_16x16x32_bf16(af[mi], bfr[ni], acc[mi][ni], 0, 0, 0);
    }
  }
#pragma unroll
  for (int mi = 0; mi < 4; ++mi) {
#pragma unroll
    for (int ni = 0; ni < 4; ++ni) {
      long col = n0 + wc * 64 + ni * 16 + lr;
      float bv = bias[col];
#pragma unroll
      for (int j = 0; j < 4; ++j) {
        long row = m0 + wr * 64 + mi * 16 + lg * 4 + j;
        C[row * 3072 + col] = acc[mi][ni][j] + bv;
      }
    }
  }
}

// ---------------- fused attention: 128 q/block (8 waves), dbuf KV, static-max softmax, IP fused ----------------
__launch_bounds__(512, 4)
__global__ void attn_fused(const u16* __restrict__ QB, const u16* __restrict__ KB,
                           const u16* __restrict__ VT, const u16* __restrict__ KipB,
                           const u16* __restrict__ VipT, u16* __restrict__ OutTok) {
  __shared__ char smem[81920];  // K dbuf 2x16KB @0, V dbuf 2x16KB @32768, P 16KB @65536
  const int tid = threadIdx.x, w = tid >> 6, lane = tid & 63;
  const int lr = lane & 15, lg = lane >> 4;
  const int h = blockIdx.y;
  const int q0 = blockIdx.x * 128;
  const bool ip = (q0 >= 512);
  const u16* Qrow = QB + (long)(h * 2560 + q0 + w * 16 + lr) * 128;
  s16x8 qf[4];
#pragma unroll
  for (int dc = 0; dc < 4; ++dc) qf[dc] = *(const s16x8*)(Qrow + dc * 32 + lg * 8);
  f32x4 accO[8] = {};
  float l_r[4] = {0.f, 0.f, 0.f, 0.f};
  const int kv0 = (q0 >= 1536) ? 1536 : 0;
  const float sc = 0.08838834764831845f;

  auto stage_main = [&](int kv, int buf) {
#pragma unroll
    for (int i = 0; i < 2; ++i) {  // K tile: 64 rows x 256B
      int x = (tid + 512 * i) * 16;
      int row = x >> 8;
      int sx = x ^ ((row & 7) << 4);
      async16((const char*)(KB + (long)(h * 2560 + kv + row) * 128) + (sx & 255),
              smem + buf * 16384 + ((i << 13) + (w << 10)));
    }
#pragma unroll
    for (int i = 0; i < 2; ++i) {  // V^T tile: 128 rows x 128B
      int x = (tid + 512 * i) * 16;
      int row = x >> 7;
      int sx = x ^ ((row & 7) << 4);
      async16((const char*)(VT + (long)(h * 128 + row) * 2560 + kv) + (sx & 127),
              smem + 32768 + buf * 16384 + ((i << 13) + (w << 10)));
    }
  };
  auto stage_ip = [&](int buf) {
#pragma unroll
    for (int i = 0; i < 2; ++i) {
      int x = (tid + 512 * i) * 16;
      int row = x >> 8;
      int sx = x ^ ((row & 7) << 4);
      async16((const char*)(KipB + (long)(h * 64 + row) * 128) + (sx & 255),
              smem + buf * 16384 + ((i << 13) + (w << 10)));
    }
#pragma unroll
    for (int i = 0; i < 2; ++i) {
      int x = (tid + 512 * i) * 16;
      int row = x >> 7;
      int sx = x ^ ((row & 7) << 4);
      async16((const char*)(VipT + (long)(h * 128 + row) * 64) + (sx & 127),
              smem + 32768 + buf * 16384 + ((i << 13) + (w << 10)));
    }
  };

  stage_main(kv0, 0);
  __syncthreads();
  int cur = 0;
  for (int kv = kv0; kv < 2560; kv += 64) {
    if (kv + 64 < 2560) stage_main(kv + 64, cur ^ 1);
    else if (ip) stage_ip(cur ^ 1);
    const char* Ks = smem + cur * 16384;
    const char* Vs = smem + 32768 + cur * 16384;
    char* Pw = smem + 65536 + w * 2048;
    f32x4 s[4] = {};
#pragma unroll
    for (int kt = 0; kt < 4; ++kt)
#pragma unroll
      for (int dc = 0; dc < 4; ++dc) {
        int row = kt * 16 + lr;
        int b = ((row << 8) + dc * 64 + lg * 16) ^ ((row & 7) << 4);
        s16x8 kf = *(const s16x8*)(Ks + b);
        s[kt] = __builtin_amdgcn_mfma_f32_16x16x32_bf16(qf[dc], kf, s[kt], 0, 0, 0);
      }
#pragma unroll
    for (int kt = 0; kt < 4; ++kt)
#pragma unroll
      for (int j = 0; j < 4; ++j) {
        float pv = __expf(fmaf(s[kt][j], sc, -12.0f));
        l_r[j] += pv;
        int prow = lg * 4 + j;
        int b = ((prow << 7) + (kt * 16 + lr) * 2) ^ ((prow & 7) << 4);
        *(u16*)(Pw + b) = f2bf(pv);
      }
    asm volatile("s_waitcnt lgkmcnt(0)" ::: "memory");
#pragma unroll
    for (int kc = 0; kc < 2; ++kc) {
      int pb = ((lr << 7) + kc * 64 + lg * 16) ^ ((lr & 7) << 4);
      s16x8 pf = *(const s16x8*)(Pw + pb);
#pragma unroll
      for (int dt = 0; dt < 8; ++dt) {
        int row = dt * 16 + lr;
        int b = ((row << 7) + kc * 64 + lg * 16) ^ ((row & 7) << 4);
        s16x8 vf = *(const s16x8*)(Vs + b);
        accO[dt] = __builtin_amdgcn_mfma_f32_16x16x32_bf16(pf, vf, accO[dt], 0, 0, 0);
      }
    }
    __syncthreads();
    cur ^= 1;
  }
  // normalize main
#pragma unroll
  for (int j = 0; j < 4; ++j) {
#pragma unroll
    for (int st = 1; st < 16; st <<= 1) l_r[j] += __shfl_xor(l_r[j], st, 16);
    l_r[j] = 1.f / l_r[j];
  }
#pragma unroll
  for (int dt = 0; dt < 8; ++dt)
#pragma unroll
    for (int j = 0; j < 4; ++j) accO[dt][j] *= l_r[j];
  // fused IP attention (single 64-key tile, closed-form softmax, normalized P)
  if (ip) {
    const char* Ks = smem + cur * 16384;
    const char* Vs = smem + 32768 + cur * 16384;
    char* Pw = smem + 65536 + w * 2048;
    f32x4 s2[4] = {};
#pragma unroll
    for (int kt = 0; kt < 4; ++kt)
#pragma unroll
      for (int dc = 0; dc < 4; ++dc) {
        int row = kt * 16 + lr;
        int b = ((row << 8) + dc * 64 + lg * 16) ^ ((row & 7) << 4);
        s16x8 kf = *(const s16x8*)(Ks + b);
        s2[kt] = __builtin_amdgcn_mfma_f32_16x16x32_bf16(qf[dc], kf, s2[kt], 0, 0, 0);
      }
    float p2[4][4];
    float l2[4] = {0.f, 0.f, 0.f, 0.f};
#pragma unroll
    for (int kt = 0; kt < 4; ++kt)
#pragma unroll
      for (int j = 0; j < 4; ++j) {
        float pv = __expf(fmaf(s2[kt][j], sc, -12.0f));
        p2[kt][j] = pv;
        l2[j] += pv;
      }
#pragma unroll
    for (int j = 0; j < 4; ++j) {
#pragma unroll
      for (int st = 1; st < 16; st <<= 1) l2[j] += __shfl_xor(l2[j], st, 16);
      l2[j] = 1.f / l2[j];
    }
#pragma unroll
    for (int kt = 0; kt < 4; ++kt)
#pragma unroll
      for (int j = 0; j < 4; ++j) {
        int prow = lg * 4 + j;
        int b = ((prow << 7) + (kt * 16 + lr) * 2) ^ ((prow & 7) << 4);
        *(u16*)(Pw + b) = f2bf(p2[kt][j] * l2[j]);
      }
    asm volatile("s_waitcnt lgkmcnt(0)" ::: "memory");
#pragma unroll
    for (int kc = 0; kc < 2; ++kc) {
      int pb = ((lr << 7) + kc * 64 + lg * 16) ^ ((lr & 7) << 4);
      s16x8 pf = *(const s16x8*)(Pw + pb);
#pragma unroll
      for (int dt = 0; dt < 8; ++dt) {
        int row = dt * 16 + lr;
        int b = ((row << 7) + kc * 64 + lg * 16) ^ ((row & 7) << 4);
        s16x8 vf = *(const s16x8*)(Vs + b);
        accO[dt] = __builtin_amdgcn_mfma_f32_16x16x32_bf16(pf, vf, accO[dt], 0, 0, 0);
      }
    }
  }
  // write
#pragma unroll
  for (int j = 0; j < 4; ++j) {
    long tok = q0 + w * 16 + lg * 4 + j;
#pragma unroll
    for (int dt = 0; dt < 8; ++dt) {
      long col = h * 128 + dt * 16 + lr;
      OutTok[tok * 3072 + col] = f2bf(accO[dt][j]);
    }
  }
}

// =====================================================================

extern "C" void kernel_launch(void* const* d_in, const int* in_sizes, int n_in,
                              void* d_out, int out_size, void* d_ws, size_t ws_size,
                              hipStream_t stream) {
  const float* hs    = (const float*)d_in[0];
  const float* ehs   = (const float*)d_in[1];
  const float* img   = (const float*)d_in[2];
  const float* Wq    = (const float*)d_in[3];
  const float* bq    = (const float*)d_in[4];
  const float* Wk    = (const float*)d_in[5];
  const float* bk    = (const float*)d_in[6];
  const float* Wv    = (const float*)d_in[7];
  const float* bv    = (const float*)d_in[8];
  const float* Waq   = (const float*)d_in[9];
  const float* baq   = (const float*)d_in[10];
  const float* Wak   = (const float*)d_in[11];
  const float* bak   = (const float*)d_in[12];
  const float* Wav   = (const float*)d_in[13];
  const float* bav   = (const float*)d_in[14];
  const float* Wo    = (const float*)d_in[15];
  const float* bo    = (const float*)d_in[16];
  const float* Wao   = (const float*)d_in[17];
  const float* bao   = (const float*)d_in[18];
  const float* Wkip  = (const float*)d_in[19];
  const float* Wvip  = (const float*)d_in[20];
  const float* lq_dn = (const float*)d_in[21];
  const float* lq_up = (const float*)d_in[22];
  const float* lk_dn = (const float*)d_in[23];
  const float* lk_up = (const float*)d_in[24];
  const float* lv_dn = (const float*)d_in[25];
  const float* lv_up = (const float*)d_in[26];
  const float* lp_dn = (const float*)d_in[27];
  const float* lp_up = (const float*)d_in[28];
  float* outp = (float*)d_out;

  char* ws = (char*)d_ws;
  size_t off = 0;
  auto take = [&](size_t b) { char* p = ws + off; off += (b + 255) & ~(size_t)255; return p; };
  u16*   WTb  = (u16*)take(9216LL * 3136 * 2);   // transposed weights (ld 3136), reused
  u16*   hsb  = (u16*)take(2048LL * 3136 * 2);   // hs bf16 + LoRA-t tail
  u16*   ehsb = (u16*)take(512LL * 3072 * 2);
  u16*   imgb = (u16*)take(64LL * 3072 * 2);
  u16*   QBf  = (u16*)take(24LL * 2560 * 128 * 2);
  u16*   KBf  = (u16*)take(24LL * 2560 * 128 * 2);
  u16*   VTf  = (u16*)take(24LL * 128 * 2560 * 2);
  u16*   AttnTok = (u16*)take(2560LL * 3072 * 2);
  float* IP0  = (float*)take(4LL * 64 * 6144 * 4);  // 4 K-split partials
  u16*   KipB = (u16*)take(24LL * 64 * 128 * 2);
  u16*   VipB = (u16*)take(24LL * 64 * 128 * 2);
  u16*   VipT = (u16*)take(24LL * 128 * 64 * 2);
  float* bpk  = (float*)take(9216 * 4);
  float* tl   = (float*)take(1024LL * 48 * 4);

  // 1. LoRA-down (reads fp32 hs), then activation converts (hsb embeds t tail)
  lora_dn3<<<1024, 256, 0, stream>>>(hs + 1024LL * 3072, 3072, lq_dn, lk_dn, lv_dn, tl);
  cvt_hs<<<3136, 256, 0, stream>>>(hs, tl, hsb);
  cvt_bf16<<<768, 256, 0, stream>>>(ehs, ehsb, 512LL * 3072);
  cvt_bf16<<<96, 256, 0, stream>>>(img, imgb, 64LL * 3072);

  // 2. encoder path: packed [Waq|Wak|Wav], fused GEMM + RMS/head epilogue
  pack_bias<<<36, 256, 0, stream>>>(baq, bak, bav, bpk);
  {
    WTArgs a;
    a.src[0] = Waq; a.dst[0] = WTb;
    a.src[1] = Wak; a.dst[1] = WTb + 3072LL * 3136;
    a.src[2] = Wav; a.dst[2] = WTb + 2 * 3072LL * 3136;
    transpose_w<<<dim3(96, 96, 3), 256, 0, stream>>>(a, 3136);
  }
  gemm_qkv<<<dim3(4, 72), 256, 0, stream>>>(ehsb, 3072, WTb, 3136, QBf, KBf, VTf, 0, bpk, 3072);

  // 3. IP projections: packed [Wkip|Wvip], K-split x4 partials, fused sum+RMS
  {
    WTArgs a;
    a.src[0] = Wkip; a.dst[0] = WTb;
    a.src[1] = Wvip; a.dst[1] = WTb + 3072LL * 3136;
    a.src[2] = Wkip; a.dst[2] = WTb;  // unused
    transpose_w<<<dim3(96, 96, 2), 256, 0, stream>>>(a, 3136);
  }
  gemm_f32<64, 4, 2><<<dim3(1, 48, 4), 256, 0, stream>>>(imgb, 3072, WTb, 3136, IP0, 6144,
                                                          nullptr, 768, 64LL * 6144);
  rms_heads4<<<64, 256, 0, stream>>>(IP0, 0, KipB, 1);
  rms_heads4<<<64, 256, 0, stream>>>(IP0, 3072, VipB, 0);
  transpose_v<<<dim3(2, 4, 24), 256, 0, stream>>>(VipB, VipT, 64);

  // 4. main q/k/v: packed [Wq|Wk|Wv] + LoRA tail in K (3072->3136)
  pack_bias<<<36, 256, 0, stream>>>(bq, bk, bv, bpk);
  {
    WTArgs a;
    a.src[0] = Wq; a.dst[0] = WTb;
    a.src[1] = Wk; a.dst[1] = WTb + 3072LL * 3136;
    a.src[2] = Wv; a.dst[2] = WTb + 2 * 3072LL * 3136;
    transpose_w<<<dim3(96, 96, 3), 256, 0, stream>>>(a, 3136);
  }
  fill_wtail<<<2304, 256, 0, stream>>>(lq_up, lk_up, lv_up, WTb);
  gemm_qkv<<<dim3(16, 72), 256, 0, stream>>>(hsb, 3136, WTb, 3136, QBf, KBf, VTf, 512, bpk, 3136);

  // 5. attention (IP fused into main-token blocks)
  attn_fused<<<dim3(20, 24), 512, 0, stream>>>(QBf, KBf, VTf, KipB, VipT, AttnTok);

  // 6. output projections: packed [Wao|Wo], single 480-block dispatch
  {
    WTArgs a;
    a.src[0] = Wao; a.dst[0] = WTb;
    a.src[1] = Wo;  a.dst[1] = WTb + 3072LL * 3136;
    a.src[2] = Wao; a.dst[2] = WTb;  // unused
    transpose_w<<<dim3(96, 96, 2), 256, 0, stream>>>(a, 3136);
  }
  gemm_out<<<dim3(20, 24), 256, 0, stream>>>(AttnTok, WTb, outp, bao, bo);

  // 7. final LoRA on post-projection main (rows 1536.. of output)
  lora_dn<<<1024, 256, 0, stream>>>(outp + 1536LL * 3072, 3072, lp_dn, tl);
  lora_up<<<1024, 256, 0, stream>>>(tl, lp_up, outp + 1536LL * 3072, 3072);
}

// Round 5
// 668.470 us; speedup vs baseline: 1.2459x; 1.0028x over previous
//
#include <hip/hip_runtime.h>

typedef unsigned short u16;
typedef short s16x8 __attribute__((ext_vector_type(8)));
typedef float f32x4 __attribute__((ext_vector_type(4)));
typedef const __attribute__((address_space(1))) unsigned int* as1_u32p;
typedef __attribute__((address_space(3))) unsigned int* as3_u32p;

static_assert(sizeof(s16x8) == 16, "");

struct alignas(8) U16x4 { u16 x, y, z, w; };

__device__ __forceinline__ u16 f2bf(float f) {
  union { float f; unsigned u; } c; c.f = f;
  return (u16)((c.u + 0x7fffu + ((c.u >> 16) & 1u)) >> 16);
}
__device__ __forceinline__ float bf2f(u16 h) {
  union { unsigned u; float f; } c; c.u = ((unsigned)h) << 16;
  return c.f;
}
__device__ __forceinline__ void async16(const void* g, void* l) {
  __builtin_amdgcn_global_load_lds((as1_u32p)g, (as3_u32p)l, 16, 0, 0);
}

// ---------------- fp32 -> bf16 flat convert (ehs, img) ----------------
__launch_bounds__(256)
__global__ void cvt_bf16(const float* __restrict__ in, u16* __restrict__ out, long n) {
  long i = ((long)blockIdx.x * 256 + threadIdx.x) * 8;
  if (i >= n) return;
  float4 a = *(const float4*)(in + i);
  float4 b = *(const float4*)(in + i + 4);
  U16x4 o0{f2bf(a.x), f2bf(a.y), f2bf(a.z), f2bf(a.w)};
  U16x4 o1{f2bf(b.x), f2bf(b.y), f2bf(b.z), f2bf(b.w)};
  *(U16x4*)(out + i) = o0;
  *(U16x4*)(out + i + 4) = o1;
}

// ---------------- hs convert into K=3136-strided buffer with LoRA-t tail ----------------
__launch_bounds__(256)
__global__ void cvt_hs(const float* __restrict__ hs, const float* __restrict__ tl,
                       u16* __restrict__ hsb) {
  long idx = (long)blockIdx.x * 256 + threadIdx.x;  // chunk of 8
  long m = idx / 392, c = idx % 392;
  U16x4 o0, o1;
  if (c < 384) {
    const float* p = hs + m * 3072 + c * 8;
    float4 a = *(const float4*)p;
    float4 b = *(const float4*)(p + 4);
    o0 = U16x4{f2bf(a.x), f2bf(a.y), f2bf(a.z), f2bf(a.w)};
    o1 = U16x4{f2bf(b.x), f2bf(b.y), f2bf(b.z), f2bf(b.w)};
  } else {
    u16 t[8];
#pragma unroll
    for (int i = 0; i < 8; ++i) {
      int r = (int)(c - 384) * 8 + i;
      float v = (m >= 1024 && r < 48) ? tl[(m - 1024) * 48 + r] : 0.f;
      t[i] = f2bf(v);
    }
    o0 = U16x4{t[0], t[1], t[2], t[3]};
    o1 = U16x4{t[4], t[5], t[6], t[7]};
  }
  u16* d = hsb + m * 3136 + c * 8;
  *(U16x4*)d = o0;
  *(U16x4*)(d + 4) = o1;
}

// ---------------- pack 3 biases into one 9216 vector ----------------
__launch_bounds__(256)
__global__ void pack_bias(const float* __restrict__ a, const float* __restrict__ b,
                          const float* __restrict__ c, float* __restrict__ out) {
  int i = blockIdx.x * 256 + threadIdx.x;
  if (i >= 9216) return;
  out[i] = (i < 3072) ? a[i] : (i < 6144) ? b[i - 3072] : c[i - 6144];
}

// ---------------- weight transpose: W(K=3072,N=3072) f32 -> W^T(N,K)bf16 at ld ldd ----------------
struct WTArgs { const float* src[3]; u16* dst[3]; };

__launch_bounds__(256)
__global__ void transpose_w(WTArgs args, int ldd) {
  const float* src = args.src[blockIdx.z];
  u16* dst = args.dst[blockIdx.z];
  __shared__ float tile[32][33];
  int k0 = blockIdx.x * 32, n0 = blockIdx.y * 32;
  int r = threadIdx.x >> 3, c4 = (threadIdx.x & 7) * 4;
  float4 v = *(const float4*)(src + (long)(k0 + r) * 3072 + n0 + c4);
  tile[r][c4 + 0] = v.x; tile[r][c4 + 1] = v.y;
  tile[r][c4 + 2] = v.z; tile[r][c4 + 3] = v.w;
  __syncthreads();
  U16x4 o{f2bf(tile[c4 + 0][r]), f2bf(tile[c4 + 1][r]),
          f2bf(tile[c4 + 2][r]), f2bf(tile[c4 + 3][r])};
  *(U16x4*)(dst + (long)(n0 + r) * ldd + k0 + c4) = o;
}

// ---------------- B-tail fill: WTb[n][3072+i] = seg-matched up[r][n%3072] else 0 ----------------
__launch_bounds__(256)
__global__ void fill_wtail(const float* __restrict__ u0, const float* __restrict__ u1,
                           const float* __restrict__ u2, u16* __restrict__ WTb) {
  int idx = blockIdx.x * 256 + threadIdx.x;  // over 9216*64
  int n = idx >> 6, i = idx & 63;
  int seg = n / 3072;
  const float* up = (seg == 0) ? u0 : (seg == 1) ? u1 : u2;
  int r = i - seg * 16;
  float v = (r >= 0 && r < 16) ? up[(long)r * 3072 + (n - seg * 3072)] : 0.f;
  WTb[(long)n * 3136 + 3072 + i] = f2bf(v);
}

// ---------------- bf16 head transpose (T,128)->(128,T) per head (Vip only) ----------------
__launch_bounds__(256)
__global__ void transpose_v(const u16* __restrict__ VB, u16* __restrict__ VT, int T) {
  __shared__ u16 tile[32][34];
  int h = blockIdx.z;
  int t0 = blockIdx.x * 32, d0 = blockIdx.y * 32;
  int r = threadIdx.x >> 3, c4 = (threadIdx.x & 7) * 4;
  U16x4 v = *(const U16x4*)(VB + ((long)h * T + t0 + r) * 128 + d0 + c4);
  tile[r][c4 + 0] = v.x; tile[r][c4 + 1] = v.y;
  tile[r][c4 + 2] = v.z; tile[r][c4 + 3] = v.w;
  __syncthreads();
  U16x4 o{tile[c4 + 0][r], tile[c4 + 1][r], tile[c4 + 2][r], tile[c4 + 3][r]};
  *(U16x4*)(VT + ((long)h * 128 + d0 + r) * T + t0 + c4) = o;
}

// ---------------- IP: sum 4 K-split partials + RMS + to_heads ----------------
__launch_bounds__(256)
__global__ void rms_heads4(const float* __restrict__ in, int col0,
                           u16* __restrict__ out, int do_rms) {
  const int t = blockIdx.x;  // 64 tokens
  const int w = threadIdx.x >> 6, lane = threadIdx.x & 63;
  const long ps = 64LL * 6144;
#pragma unroll
  for (int hh = 0; hh < 6; ++hh) {
    int h = w * 6 + hh;
    const float* x = in + (long)t * 6144 + col0 + h * 128 + lane * 2;
    float a = x[0] + x[ps] + x[2 * ps] + x[3 * ps];
    float b = x[1] + x[1 + ps] + x[1 + 2 * ps] + x[1 + 3 * ps];
    float scale = 1.f;
    if (do_rms) {
      float ss = a * a + b * b;
#pragma unroll
      for (int st = 1; st < 64; st <<= 1) ss += __shfl_xor(ss, st, 64);
      scale = rsqrtf(ss * (1.f / 128.f) + 1e-5f);
    }
    unsigned pa = f2bf(a * scale), pb = f2bf(b * scale);
    *(unsigned*)(out + ((long)h * 64 + t) * 128 + lane * 2) = pa | (pb << 16);
  }
}

// ---------------- fused 3-way LoRA down ----------------
__launch_bounds__(256)
__global__ void lora_dn3(const float* __restrict__ X, int ldx,
                         const float* __restrict__ d0, const float* __restrict__ d1,
                         const float* __restrict__ d2, float* __restrict__ t) {
  __shared__ float red[4][48];
  const int m = blockIdx.x;
  const float* xr = X + (long)m * ldx;
  float p[48];
#pragma unroll
  for (int r = 0; r < 48; ++r) p[r] = 0.f;
  for (int k = threadIdx.x; k < 3072; k += 256) {
    float a = xr[k];
    const float* e0 = d0 + (long)k * 16;
    const float* e1 = d1 + (long)k * 16;
    const float* e2 = d2 + (long)k * 16;
#pragma unroll
    for (int r = 0; r < 16; ++r) {
      p[r]      += a * e0[r];
      p[16 + r] += a * e1[r];
      p[32 + r] += a * e2[r];
    }
  }
#pragma unroll
  for (int r = 0; r < 48; ++r)
#pragma unroll
    for (int st = 1; st < 64; st <<= 1) p[r] += __shfl_xor(p[r], st, 64);
  int lane = threadIdx.x & 63, w = threadIdx.x >> 6;
  if (lane == 0) {
#pragma unroll
    for (int r = 0; r < 48; ++r) red[w][r] = p[r];
  }
  __syncthreads();
  if (threadIdx.x < 48) {
    int r = threadIdx.x;
    t[(long)m * 48 + r] = red[0][r] + red[1][r] + red[2][r] + red[3][r];
  }
}

// ---------------- single LoRA (final lp path, fp32) ----------------
__launch_bounds__(256)
__global__ void lora_dn(const float* __restrict__ X, int ldx,
                        const float* __restrict__ dn, float* __restrict__ t) {
  __shared__ float red[4][16];
  const int m = blockIdx.x;
  const float* xr = X + (long)m * ldx;
  float p[16];
#pragma unroll
  for (int r = 0; r < 16; ++r) p[r] = 0.f;
  for (int k = threadIdx.x; k < 3072; k += 256) {
    float a = xr[k];
    const float* d = dn + (long)k * 16;
#pragma unroll
    for (int r = 0; r < 16; ++r) p[r] += a * d[r];
  }
#pragma unroll
  for (int r = 0; r < 16; ++r)
#pragma unroll
    for (int st = 1; st < 64; st <<= 1) p[r] += __shfl_xor(p[r], st, 64);
  int lane = threadIdx.x & 63, w = threadIdx.x >> 6;
  if (lane == 0) {
#pragma unroll
    for (int r = 0; r < 16; ++r) red[w][r] = p[r];
  }
  __syncthreads();
  if (threadIdx.x < 16) {
    int r = threadIdx.x;
    t[(long)m * 16 + r] = red[0][r] + red[1][r] + red[2][r] + red[3][r];
  }
}

__launch_bounds__(256)
__global__ void lora_up(const float* __restrict__ t, const float* __restrict__ up,
                        float* __restrict__ Y, int ldy) {
  const int m = blockIdx.x;
  float tv[16];
#pragma unroll
  for (int r = 0; r < 16; ++r) tv[r] = t[(long)m * 16 + r];
  float* yr = Y + (long)m * ldy;
  for (int n = threadIdx.x; n < 3072; n += 256) {
    float a = 0.f;
#pragma unroll
    for (int r = 0; r < 16; ++r) a += tv[r] * up[(long)r * 3072 + n];
    yr[n] += a;
  }
}

// ---------------- generic 128-col-tile GEMM -> f32 (IP partials) ----------------
template <int BM, int MI, int NI>
__launch_bounds__(256)
__global__ void gemm_f32(const u16* __restrict__ A, int lda,
                         const u16* __restrict__ B, int ldb,
                         float* __restrict__ C, int ldc,
                         const float* __restrict__ bias, int KC, long cstride) {
  constexpr int WCOLS = 128 / (NI * 16);
  constexpr int ABYTES = BM * 128;
  __shared__ char smem[ABYTES + 128 * 128];
  char* As = smem;
  char* Bs = smem + ABYTES;
  const int tid = threadIdx.x;
  const int w = tid >> 6, lane = tid & 63;
  const int lr = lane & 15, lg = lane >> 4;
  const int wr = w / WCOLS, wc = w % WCOLS;
  const int nbx = gridDim.x;
  const int nwg = nbx * gridDim.y;
  const int flat = blockIdx.y * nbx + blockIdx.x;
  const int swz = (flat & 7) * (nwg >> 3) + (flat >> 3);
  const long m0 = (long)(swz % nbx) * BM;
  const long n0 = (long)(swz / nbx) * 128;
  const int k0 = blockIdx.z * KC;
  C += blockIdx.z * cstride;
  f32x4 acc[MI][NI] = {};
  constexpr int ACH = BM / 32;
  for (int kb = k0; kb < k0 + KC; kb += 64) {
    __syncthreads();
#pragma unroll
    for (int i = 0; i < ACH; ++i) {
      int x = (tid + 256 * i) * 16;
      int row = x >> 7;
      int sx = x ^ ((row & 7) << 4);
      async16((const char*)(A + (m0 + row) * lda + kb) + (sx & 127),
              As + ((w << 10) + (i << 12)));
    }
#pragma unroll
    for (int i = 0; i < 4; ++i) {
      int x = (tid + 256 * i) * 16;
      int row = x >> 7;
      int sx = x ^ ((row & 7) << 4);
      async16((const char*)(B + (n0 + row) * ldb + kb) + (sx & 127),
              Bs + ((w << 10) + (i << 12)));
    }
    __syncthreads();
#pragma unroll
    for (int kc = 0; kc < 2; ++kc) {
      s16x8 af[MI], bfr[NI];
#pragma unroll
      for (int mi = 0; mi < MI; ++mi) {
        int row = wr * (MI * 16) + mi * 16 + lr;
        int b = ((row << 7) + kc * 64 + lg * 16) ^ ((row & 7) << 4);
        af[mi] = *(const s16x8*)(As + b);
      }
#pragma unroll
      for (int ni = 0; ni < NI; ++ni) {
        int row = wc * (NI * 16) + ni * 16 + lr;
        int b = ((row << 7) + kc * 64 + lg * 16) ^ ((row & 7) << 4);
        bfr[ni] = *(const s16x8*)(Bs + b);
      }
#pragma unroll
      for (int mi = 0; mi < MI; ++mi)
#pragma unroll
        for (int ni = 0; ni < NI; ++ni)
          acc[mi][ni] = __builtin_amdgcn_mfma_f32_16x16x32_bf16(af[mi], bfr[ni], acc[mi][ni], 0, 0, 0);
    }
  }
#pragma unroll
  for (int mi = 0; mi < MI; ++mi) {
#pragma unroll
    for (int ni = 0; ni < NI; ++ni) {
      long col = n0 + wc * (NI * 16) + ni * 16 + lr;
      float bv = bias ? bias[col] : 0.f;
#pragma unroll
      for (int j = 0; j < 4; ++j) {
        long row = m0 + wr * (MI * 16) + mi * 16 + lg * 4 + j;
        C[row * ldc + col] = acc[mi][ni][j] + bv;
      }
    }
  }
}

// ---------------- QKV GEMM v2: BM=128 x BN=256, wave-per-head, LDS-bounce stores ----------------
// 4 waves: wr=w>>1 (64-row m-half), wc=w&1 (head within 256-col tile).
// Per wave: MI=4 x NI=8 = 32 fragments (full 128-d head) -> in-wave RMS.
// Epilogue: 2-phase LDS bounce (XOR-swizzled) -> coalesced 16B global stores.
__launch_bounds__(256, 2)
__global__ void gemm_qkv(const u16* __restrict__ A, int lda,
                         const u16* __restrict__ B, int ldb,
                         u16* __restrict__ Qo, u16* __restrict__ Ko, u16* __restrict__ VTo,
                         int t0, const float* __restrict__ bias, int K) {
  __shared__ char smem[49152];  // As 16KB, Bs 32KB; epilogue reuses first 32KB
  char* As = smem;
  char* Bs = smem + 16384;
  const int tid = threadIdx.x;
  const int w = tid >> 6, lane = tid & 63;
  const int lr = lane & 15, lg = lane >> 4;
  const int wr = w >> 1, wc = w & 1;
  const int nbx = gridDim.x;
  const int nwg = nbx * gridDim.y;
  const int flat = blockIdx.y * nbx + blockIdx.x;
  const int swz = (flat & 7) * (nwg >> 3) + (flat >> 3);
  const long m0 = (long)(swz % nbx) * 128;
  const long n0 = (long)(swz / nbx) * 256;
  f32x4 acc[4][8] = {};
  for (int kb = 0; kb < K; kb += 64) {
    __syncthreads();
#pragma unroll
    for (int i = 0; i < 4; ++i) {  // A: 128 rows x 128B
      int x = (tid + 256 * i) * 16;
      int row = x >> 7;
      int sx = (x & 127) ^ ((row & 7) << 4);
      async16((const char*)(A + (m0 + row) * lda + kb) + sx, As + x);
    }
#pragma unroll
    for (int i = 0; i < 8; ++i) {  // B: 256 rows x 128B
      int x = (tid + 256 * i) * 16;
      int row = x >> 7;
      int sx = (x & 127) ^ ((row & 7) << 4);
      async16((const char*)(B + (n0 + row) * ldb + kb) + sx, Bs + x);
    }
    __syncthreads();
#pragma unroll
    for (int kc = 0; kc < 2; ++kc) {
      s16x8 af[4], bfr[8];
#pragma unroll
      for (int mi = 0; mi < 4; ++mi) {
        int row = wr * 64 + mi * 16 + lr;
        af[mi] = *(const s16x8*)(As + (row << 7) + ((kc * 64 + lg * 16) ^ ((row & 7) << 4)));
      }
#pragma unroll
      for (int ni = 0; ni < 8; ++ni) {
        int row = wc * 128 + ni * 16 + lr;
        bfr[ni] = *(const s16x8*)(Bs + (row << 7) + ((kc * 64 + lg * 16) ^ ((row & 7) << 4)));
      }
#pragma unroll
      for (int mi = 0; mi < 4; ++mi)
#pragma unroll
        for (int ni = 0; ni < 8; ++ni)
          acc[mi][ni] = __builtin_amdgcn_mfma_f32_16x16x32_bf16(af[mi], bfr[ni], acc[mi][ni], 0, 0, 0);
    }
  }
  // ---- epilogue ----
  const int seg = (int)(n0 / 3072);
  const int head0 = (int)((n0 % 3072) >> 7);  // even; this wave's head = head0 + wc
#pragma unroll
  for (int ni = 0; ni < 8; ++ni) {
    float bv = bias[n0 + wc * 128 + ni * 16 + lr];
#pragma unroll
    for (int mi = 0; mi < 4; ++mi)
#pragma unroll
      for (int j = 0; j < 4; ++j) acc[mi][ni][j] += bv;
  }
  float scl[4][4];
  if (seg < 2) {  // in-wave RMS over the head's 128 dims
#pragma unroll
    for (int mi = 0; mi < 4; ++mi)
#pragma unroll
      for (int j = 0; j < 4; ++j) {
        float s = 0.f;
#pragma unroll
        for (int ni = 0; ni < 8; ++ni) s += acc[mi][ni][j] * acc[mi][ni][j];
#pragma unroll
        for (int st = 1; st < 16; st <<= 1) s += __shfl_xor(s, st, 16);
        scl[mi][j] = rsqrtf(s * (1.f / 128.f) + 1e-5f);
      }
  }
#pragma unroll
  for (int ph = 0; ph < 2; ++ph) {
    __syncthreads();
    if (wc == ph) {
      if (seg < 2) {  // LDS [tok][d] bf16, XOR-swizzled
#pragma unroll
        for (int mi = 0; mi < 4; ++mi)
#pragma unroll
          for (int ni = 0; ni < 8; ++ni) {
            int d2 = (ni * 16 + lr) * 2;
#pragma unroll
            for (int j = 0; j < 4; ++j) {
              int tok = wr * 64 + mi * 16 + lg * 4 + j;
              *(u16*)(smem + tok * 256 + (d2 ^ ((tok & 7) << 4))) =
                  f2bf(acc[mi][ni][j] * scl[mi][j]);
            }
          }
      } else {  // LDS [d][tok] bf16, XOR-swizzled, 8B packed writes
#pragma unroll
        for (int mi = 0; mi < 4; ++mi)
#pragma unroll
          for (int ni = 0; ni < 8; ++ni) {
            int d = ni * 16 + lr;
            int tok0b = (wr * 64 + mi * 16 + lg * 4) * 2;
            U16x4 o{f2bf(acc[mi][ni][0]), f2bf(acc[mi][ni][1]),
                    f2bf(acc[mi][ni][2]), f2bf(acc[mi][ni][3])};
            *(U16x4*)(smem + d * 256 + (tok0b ^ ((d & 7) << 4))) = o;
          }
      }
    }
    __syncthreads();
    // cooperative coalesced store of the 32KB tile (128 rows x 256B)
    const int headp = head0 + ph;
#pragma unroll
    for (int i = 0; i < 8; ++i) {
      int x = (tid + 256 * i) * 16;
      int row = x >> 8, col = x & 255;
      s16x8 vdat = *(const s16x8*)(smem + row * 256 + (col ^ ((row & 7) << 4)));
      if (seg < 2) {
        u16* g = (seg == 0 ? Qo : Ko) + ((long)headp * 2560 + t0 + m0 + row) * 128;
        *(s16x8*)((char*)g + col) = vdat;
      } else {
        u16* g = VTo + ((long)headp * 128 + row) * 2560 + t0 + m0;
        *(s16x8*)((char*)g + col) = vdat;
      }
    }
  }
}

// ---------------- fused output projection: enc(Wao) + main(Wo) in one dispatch ----------------
__launch_bounds__(256)
__global__ void gemm_out(const u16* __restrict__ Atok, const u16* __restrict__ WT,
                         float* __restrict__ outp, const float* __restrict__ bao,
                         const float* __restrict__ bo) {
  __shared__ char smem[128 * 128 + 128 * 128];
  char* As = smem;
  char* Bs = smem + 128 * 128;
  const int tid = threadIdx.x;
  const int w = tid >> 6, lane = tid & 63;
  const int lr = lane & 15, lg = lane >> 4;
  const int wr = w >> 1, wc = w & 1;
  const int flat = blockIdx.y * 20 + blockIdx.x;
  const int swz = (flat & 7) * 60 + (flat >> 3);
  const int mx = swz % 20;
  const long n0 = (long)(swz / 20) * 128;
  const u16* A;
  const u16* B;
  const float* bias;
  float* C;
  long m0;
  if (mx < 4) { A = Atok; B = WT; bias = bao; C = outp; m0 = (long)mx * 128; }
  else { A = Atok + 512L * 3072; B = WT + 3072L * 3136; bias = bo; C = outp + 512L * 3072; m0 = (long)(mx - 4) * 128; }
  f32x4 acc[4][4] = {};
  for (int kb = 0; kb < 3072; kb += 64) {
    __syncthreads();
#pragma unroll
    for (int i = 0; i < 4; ++i) {
      int x = (tid + 256 * i) * 16;
      int row = x >> 7;
      int sx = x ^ ((row & 7) << 4);
      async16((const char*)(A + (m0 + row) * 3072 + kb) + (sx & 127),
              As + ((w << 10) + (i << 12)));
    }
#pragma unroll
    for (int i = 0; i < 4; ++i) {
      int x = (tid + 256 * i) * 16;
      int row = x >> 7;
      int sx = x ^ ((row & 7) << 4);
      async16((const char*)(B + (n0 + row) * 3136 + kb) + (sx & 127),
              Bs + ((w << 10) + (i << 12)));
    }
    __syncthreads();
#pragma unroll
    for (int kc = 0; kc < 2; ++kc) {
      s16x8 af[4], bfr[4];
#pragma unroll
      for (int mi = 0; mi < 4; ++mi) {
        int row = wr * 64 + mi * 16 + lr;
        int b = ((row << 7) + kc * 64 + lg * 16) ^ ((row & 7) << 4);
        af[mi] = *(const s16x8*)(As + b);
      }
#pragma unroll
      for (int ni = 0; ni < 4; ++ni) {
        int row = wc * 64 + ni * 16 + lr;
        int b = ((row << 7) + kc * 64 + lg * 16) ^ ((row & 7) << 4);
        bfr[ni] = *(const s16x8*)(Bs + b);
      }
#pragma unroll
      for (int mi = 0; mi < 4; ++mi)
#pragma unroll
        for (int ni = 0; ni < 4; ++ni)
          acc[mi][ni] = __builtin_amdgcn_mfma_f32_16x16x32_bf16(af[mi], bfr[ni], acc[mi][ni], 0, 0, 0);
    }
  }
#pragma unroll
  for (int mi = 0; mi < 4; ++mi) {
#pragma unroll
    for (int ni = 0; ni < 4; ++ni) {
      long col = n0 + wc * 64 + ni * 16 + lr;
      float bv = bias[col];
#pragma unroll
      for (int j = 0; j < 4; ++j) {
        long row = m0 + wr * 64 + mi * 16 + lg * 4 + j;
        C[row * 3072 + col] = acc[mi][ni][j] + bv;
      }
    }
  }
}

// ---------------- fused attention: 128 q/block (8 waves), dbuf KV, static-max softmax, IP fused ----------------
__launch_bounds__(512, 4)
__global__ void attn_fused(const u16* __restrict__ QB, const u16* __restrict__ KB,
                           const u16* __restrict__ VT, const u16* __restrict__ KipB,
                           const u16* __restrict__ VipT, u16* __restrict__ OutTok) {
  __shared__ char smem[81920];
  const int tid = threadIdx.x, w = tid >> 6, lane = tid & 63;
  const int lr = lane & 15, lg = lane >> 4;
  const int h = blockIdx.y;
  const int q0 = blockIdx.x * 128;
  const bool ip = (q0 >= 512);
  const u16* Qrow = QB + (long)(h * 2560 + q0 + w * 16 + lr) * 128;
  s16x8 qf[4];
#pragma unroll
  for (int dc = 0; dc < 4; ++dc) qf[dc] = *(const s16x8*)(Qrow + dc * 32 + lg * 8);
  f32x4 accO[8] = {};
  float l_r[4] = {0.f, 0.f, 0.f, 0.f};
  const int kv0 = (q0 >= 1536) ? 1536 : 0;
  const float sc = 0.08838834764831845f;

  auto stage_main = [&](int kv, int buf) {
#pragma unroll
    for (int i = 0; i < 2; ++i) {
      int x = (tid + 512 * i) * 16;
      int row = x >> 8;
      int sx = x ^ ((row & 7) << 4);
      async16((const char*)(KB + (long)(h * 2560 + kv + row) * 128) + (sx & 255),
              smem + buf * 16384 + ((i << 13) + (w << 10)));
    }
#pragma unroll
    for (int i = 0; i < 2; ++i) {
      int x = (tid + 512 * i) * 16;
      int row = x >> 7;
      int sx = x ^ ((row & 7) << 4);
      async16((const char*)(VT + (long)(h * 128 + row) * 2560 + kv) + (sx & 127),
              smem + 32768 + buf * 16384 + ((i << 13) + (w << 10)));
    }
  };
  auto stage_ip = [&](int buf) {
#pragma unroll
    for (int i = 0; i < 2; ++i) {
      int x = (tid + 512 * i) * 16;
      int row = x >> 8;
      int sx = x ^ ((row & 7) << 4);
      async16((const char*)(KipB + (long)(h * 64 + row) * 128) + (sx & 255),
              smem + buf * 16384 + ((i << 13) + (w << 10)));
    }
#pragma unroll
    for (int i = 0; i < 2; ++i) {
      int x = (tid + 512 * i) * 16;
      int row = x >> 7;
      int sx = x ^ ((row & 7) << 4);
      async16((const char*)(VipT + (long)(h * 128 + row) * 64) + (sx & 127),
              smem + 32768 + buf * 16384 + ((i << 13) + (w << 10)));
    }
  };

  stage_main(kv0, 0);
  __syncthreads();
  int cur = 0;
  for (int kv = kv0; kv < 2560; kv += 64) {
    if (kv + 64 < 2560) stage_main(kv + 64, cur ^ 1);
    else if (ip) stage_ip(cur ^ 1);
    const char* Ks = smem + cur * 16384;
    const char* Vs = smem + 32768 + cur * 16384;
    char* Pw = smem + 65536 + w * 2048;
    f32x4 s[4] = {};
#pragma unroll
    for (int kt = 0; kt < 4; ++kt)
#pragma unroll
      for (int dc = 0; dc < 4; ++dc) {
        int row = kt * 16 + lr;
        int b = ((row << 8) + dc * 64 + lg * 16) ^ ((row & 7) << 4);
        s16x8 kf = *(const s16x8*)(Ks + b);
        s[kt] = __builtin_amdgcn_mfma_f32_16x16x32_bf16(qf[dc], kf, s[kt], 0, 0, 0);
      }
#pragma unroll
    for (int kt = 0; kt < 4; ++kt)
#pragma unroll
      for (int j = 0; j < 4; ++j) {
        float pv = __expf(fmaf(s[kt][j], sc, -12.0f));
        l_r[j] += pv;
        int prow = lg * 4 + j;
        int b = ((prow << 7) + (kt * 16 + lr) * 2) ^ ((prow & 7) << 4);
        *(u16*)(Pw + b) = f2bf(pv);
      }
    asm volatile("s_waitcnt lgkmcnt(0)" ::: "memory");
#pragma unroll
    for (int kc = 0; kc < 2; ++kc) {
      int pb = ((lr << 7) + kc * 64 + lg * 16) ^ ((lr & 7) << 4);
      s16x8 pf = *(const s16x8*)(Pw + pb);
#pragma unroll
      for (int dt = 0; dt < 8; ++dt) {
        int row = dt * 16 + lr;
        int b = ((row << 7) + kc * 64 + lg * 16) ^ ((row & 7) << 4);
        s16x8 vf = *(const s16x8*)(Vs + b);
        accO[dt] = __builtin_amdgcn_mfma_f32_16x16x32_bf16(pf, vf, accO[dt], 0, 0, 0);
      }
    }
    __syncthreads();
    cur ^= 1;
  }
#pragma unroll
  for (int j = 0; j < 4; ++j) {
#pragma unroll
    for (int st = 1; st < 16; st <<= 1) l_r[j] += __shfl_xor(l_r[j], st, 16);
    l_r[j] = 1.f / l_r[j];
  }
#pragma unroll
  for (int dt = 0; dt < 8; ++dt)
#pragma unroll
    for (int j = 0; j < 4; ++j) accO[dt][j] *= l_r[j];
  if (ip) {
    const char* Ks = smem + cur * 16384;
    const char* Vs = smem + 32768 + cur * 16384;
    char* Pw = smem + 65536 + w * 2048;
    f32x4 s2[4] = {};
#pragma unroll
    for (int kt = 0; kt < 4; ++kt)
#pragma unroll
      for (int dc = 0; dc < 4; ++dc) {
        int row = kt * 16 + lr;
        int b = ((row << 8) + dc * 64 + lg * 16) ^ ((row & 7) << 4);
        s16x8 kf = *(const s16x8*)(Ks + b);
        s2[kt] = __builtin_amdgcn_mfma_f32_16x16x32_bf16(qf[dc], kf, s2[kt], 0, 0, 0);
      }
    float p2[4][4];
    float l2[4] = {0.f, 0.f, 0.f, 0.f};
#pragma unroll
    for (int kt = 0; kt < 4; ++kt)
#pragma unroll
      for (int j = 0; j < 4; ++j) {
        float pv = __expf(fmaf(s2[kt][j], sc, -12.0f));
        p2[kt][j] = pv;
        l2[j] += pv;
      }
#pragma unroll
    for (int j = 0; j < 4; ++j) {
#pragma unroll
      for (int st = 1; st < 16; st <<= 1) l2[j] += __shfl_xor(l2[j], st, 16);
      l2[j] = 1.f / l2[j];
    }
#pragma unroll
    for (int kt = 0; kt < 4; ++kt)
#pragma unroll
      for (int j = 0; j < 4; ++j) {
        int prow = lg * 4 + j;
        int b = ((prow << 7) + (kt * 16 + lr) * 2) ^ ((prow & 7) << 4);
        *(u16*)(Pw + b) = f2bf(p2[kt][j] * l2[j]);
      }
    asm volatile("s_waitcnt lgkmcnt(0)" ::: "memory");
#pragma unroll
    for (int kc = 0; kc < 2; ++kc) {
      int pb = ((lr << 7) + kc * 64 + lg * 16) ^ ((lr & 7) << 4);
      s16x8 pf = *(const s16x8*)(Pw + pb);
#pragma unroll
      for (int dt = 0; dt < 8; ++dt) {
        int row = dt * 16 + lr;
        int b = ((row << 7) + kc * 64 + lg * 16) ^ ((row & 7) << 4);
        s16x8 vf = *(const s16x8*)(Vs + b);
        accO[dt] = __builtin_amdgcn_mfma_f32_16x16x32_bf16(pf, vf, accO[dt], 0, 0, 0);
      }
    }
  }
#pragma unroll
  for (int j = 0; j < 4; ++j) {
    long tok = q0 + w * 16 + lg * 4 + j;
#pragma unroll
    for (int dt = 0; dt < 8; ++dt) {
      long col = h * 128 + dt * 16 + lr;
      OutTok[tok * 3072 + col] = f2bf(accO[dt][j]);
    }
  }
}

// =====================================================================

extern "C" void kernel_launch(void* const* d_in, const int* in_sizes, int n_in,
                              void* d_out, int out_size, void* d_ws, size_t ws_size,
                              hipStream_t stream) {
  const float* hs    = (const float*)d_in[0];
  const float* ehs   = (const float*)d_in[1];
  const float* img   = (const float*)d_in[2];
  const float* Wq    = (const float*)d_in[3];
  const float* bq    = (const float*)d_in[4];
  const float* Wk    = (const float*)d_in[5];
  const float* bk    = (const float*)d_in[6];
  const float* Wv    = (const float*)d_in[7];
  const float* bv    = (const float*)d_in[8];
  const float* Waq   = (const float*)d_in[9];
  const float* baq   = (const float*)d_in[10];
  const float* Wak   = (const float*)d_in[11];
  const float* bak   = (const float*)d_in[12];
  const float* Wav   = (const float*)d_in[13];
  const float* bav   = (const float*)d_in[14];
  const float* Wo    = (const float*)d_in[15];
  const float* bo    = (const float*)d_in[16];
  const float* Wao   = (const float*)d_in[17];
  const float* bao   = (const float*)d_in[18];
  const float* Wkip  = (const float*)d_in[19];
  const float* Wvip  = (const float*)d_in[20];
  const float* lq_dn = (const float*)d_in[21];
  const float* lq_up = (const float*)d_in[22];
  const float* lk_dn = (const float*)d_in[23];
  const float* lk_up = (const float*)d_in[24];
  const float* lv_dn = (const float*)d_in[25];
  const float* lv_up = (const float*)d_in[26];
  const float* lp_dn = (const float*)d_in[27];
  const float* lp_up = (const float*)d_in[28];
  float* outp = (float*)d_out;

  char* ws = (char*)d_ws;
  size_t off = 0;
  auto take = [&](size_t b) { char* p = ws + off; off += (b + 255) & ~(size_t)255; return p; };
  u16*   WTb  = (u16*)take(9216LL * 3136 * 2);
  u16*   hsb  = (u16*)take(2048LL * 3136 * 2);
  u16*   ehsb = (u16*)take(512LL * 3072 * 2);
  u16*   imgb = (u16*)take(64LL * 3072 * 2);
  u16*   QBf  = (u16*)take(24LL * 2560 * 128 * 2);
  u16*   KBf  = (u16*)take(24LL * 2560 * 128 * 2);
  u16*   VTf  = (u16*)take(24LL * 128 * 2560 * 2);
  u16*   AttnTok = (u16*)take(2560LL * 3072 * 2);
  float* IP0  = (float*)take(4LL * 64 * 6144 * 4);
  u16*   KipB = (u16*)take(24LL * 64 * 128 * 2);
  u16*   VipB = (u16*)take(24LL * 64 * 128 * 2);
  u16*   VipT = (u16*)take(24LL * 128 * 64 * 2);
  float* bpk  = (float*)take(9216 * 4);
  float* tl   = (float*)take(1024LL * 48 * 4);

  // 1. LoRA-down (fp32 hs), activation converts (hsb embeds t tail)
  lora_dn3<<<1024, 256, 0, stream>>>(hs + 1024LL * 3072, 3072, lq_dn, lk_dn, lv_dn, tl);
  cvt_hs<<<3136, 256, 0, stream>>>(hs, tl, hsb);
  cvt_bf16<<<768, 256, 0, stream>>>(ehs, ehsb, 512LL * 3072);
  cvt_bf16<<<96, 256, 0, stream>>>(img, imgb, 64LL * 3072);

  // 2. encoder path: packed [Waq|Wak|Wav], fused GEMM + RMS/head epilogue
  pack_bias<<<36, 256, 0, stream>>>(baq, bak, bav, bpk);
  {
    WTArgs a;
    a.src[0] = Waq; a.dst[0] = WTb;
    a.src[1] = Wak; a.dst[1] = WTb + 3072LL * 3136;
    a.src[2] = Wav; a.dst[2] = WTb + 2 * 3072LL * 3136;
    transpose_w<<<dim3(96, 96, 3), 256, 0, stream>>>(a, 3136);
  }
  gemm_qkv<<<dim3(4, 36), 256, 0, stream>>>(ehsb, 3072, WTb, 3136, QBf, KBf, VTf, 0, bpk, 3072);

  // 3. IP projections: packed [Wkip|Wvip], K-split x4, fused sum+RMS
  {
    WTArgs a;
    a.src[0] = Wkip; a.dst[0] = WTb;
    a.src[1] = Wvip; a.dst[1] = WTb + 3072LL * 3136;
    a.src[2] = Wkip; a.dst[2] = WTb;  // unused
    transpose_w<<<dim3(96, 96, 2), 256, 0, stream>>>(a, 3136);
  }
  gemm_f32<64, 4, 2><<<dim3(1, 48, 4), 256, 0, stream>>>(imgb, 3072, WTb, 3136, IP0, 6144,
                                                          nullptr, 768, 64LL * 6144);
  rms_heads4<<<64, 256, 0, stream>>>(IP0, 0, KipB, 1);
  rms_heads4<<<64, 256, 0, stream>>>(IP0, 3072, VipB, 0);
  transpose_v<<<dim3(2, 4, 24), 256, 0, stream>>>(VipB, VipT, 64);

  // 4. main q/k/v: packed [Wq|Wk|Wv] + LoRA tail in K (3072->3136)
  pack_bias<<<36, 256, 0, stream>>>(bq, bk, bv, bpk);
  {
    WTArgs a;
    a.src[0] = Wq; a.dst[0] = WTb;
    a.src[1] = Wk; a.dst[1] = WTb + 3072LL * 3136;
    a.src[2] = Wv; a.dst[2] = WTb + 2 * 3072LL * 3136;
    transpose_w<<<dim3(96, 96, 3), 256, 0, stream>>>(a, 3136);
  }
  fill_wtail<<<2304, 256, 0, stream>>>(lq_up, lk_up, lv_up, WTb);
  gemm_qkv<<<dim3(16, 36), 256, 0, stream>>>(hsb, 3136, WTb, 3136, QBf, KBf, VTf, 512, bpk, 3136);

  // 5. attention (IP fused into main-token blocks)
  attn_fused<<<dim3(20, 24), 512, 0, stream>>>(QBf, KBf, VTf, KipB, VipT, AttnTok);

  // 6. output projections: packed [Wao|Wo], single 480-block dispatch
  {
    WTArgs a;
    a.src[0] = Wao; a.dst[0] = WTb;
    a.src[1] = Wo;  a.dst[1] = WTb + 3072LL * 3136;
    a.src[2] = Wao; a.dst[2] = WTb;  // unused
    transpose_w<<<dim3(96, 96, 2), 256, 0, stream>>>(a, 3136);
  }
  gemm_out<<<dim3(20, 24), 256, 0, stream>>>(AttnTok, WTb, outp, bao, bo);

  // 7. final LoRA on post-projection main (rows 1536.. of output)
  lora_dn<<<1024, 256, 0, stream>>>(outp + 1536LL * 3072, 3072, lp_dn, tl);
  lora_up<<<1024, 256, 0, stream>>>(tl, lp_up, outp + 1536LL * 3072, 3072);
}

// Round 6
// 642.459 us; speedup vs baseline: 1.2964x; 1.0405x over previous
//
#include <hip/hip_runtime.h>

typedef unsigned short u16;
typedef short s16x8 __attribute__((ext_vector_type(8)));
typedef float f32x4 __attribute__((ext_vector_type(4)));
typedef const __attribute__((address_space(1))) unsigned int* as1_u32p;
typedef __attribute__((address_space(3))) unsigned int* as3_u32p;

static_assert(sizeof(s16x8) == 16, "");

struct alignas(8) U16x4 { u16 x, y, z, w; };

__device__ __forceinline__ u16 f2bf(float f) {
  union { float f; unsigned u; } c; c.f = f;
  return (u16)((c.u + 0x7fffu + ((c.u >> 16) & 1u)) >> 16);
}
__device__ __forceinline__ float bf2f(u16 h) {
  union { unsigned u; float f; } c; c.u = ((unsigned)h) << 16;
  return c.f;
}
__device__ __forceinline__ void async16(const void* g, void* l) {
  __builtin_amdgcn_global_load_lds((as1_u32p)g, (as3_u32p)l, 16, 0, 0);
}

// ---------------- fused 3-way LoRA down: t[m][48] = hs_cond[m] @ [lq|lk|lv]_dn ----------------
__launch_bounds__(256)
__global__ void lora_dn3(const float* __restrict__ X, int ldx,
                         const float* __restrict__ d0, const float* __restrict__ d1,
                         const float* __restrict__ d2, float* __restrict__ t) {
  __shared__ float red[4][48];
  const int m = blockIdx.x;
  const float* xr = X + (long)m * ldx;
  float p[48];
#pragma unroll
  for (int r = 0; r < 48; ++r) p[r] = 0.f;
  for (int k = threadIdx.x; k < 3072; k += 256) {
    float a = xr[k];
    const float* e0 = d0 + (long)k * 16;
    const float* e1 = d1 + (long)k * 16;
    const float* e2 = d2 + (long)k * 16;
#pragma unroll
    for (int r = 0; r < 16; ++r) {
      p[r]      += a * e0[r];
      p[16 + r] += a * e1[r];
      p[32 + r] += a * e2[r];
    }
  }
#pragma unroll
  for (int r = 0; r < 48; ++r)
#pragma unroll
    for (int st = 1; st < 64; st <<= 1) p[r] += __shfl_xor(p[r], st, 64);
  int lane = threadIdx.x & 63, w = threadIdx.x >> 6;
  if (lane == 0) {
#pragma unroll
    for (int r = 0; r < 48; ++r) red[w][r] = p[r];
  }
  __syncthreads();
  if (threadIdx.x < 48) {
    int r = threadIdx.x;
    t[(long)m * 48 + r] = red[0][r] + red[1][r] + red[2][r] + red[3][r];
  }
}

// ---------------- Wod[k][16] = Wo[k,:] @ lp_dn; row 3072 = bo @ lp_dn ----------------
__launch_bounds__(256)
__global__ void wod_prep(const float* __restrict__ Wo, const float* __restrict__ bo,
                         const float* __restrict__ dn, float* __restrict__ Wod) {
  __shared__ float red[4][16];
  const int m = blockIdx.x;  // 0..3072
  const float* xr = (m < 3072) ? Wo + (long)m * 3072 : bo;
  float p[16];
#pragma unroll
  for (int r = 0; r < 16; ++r) p[r] = 0.f;
  for (int k = threadIdx.x; k < 3072; k += 256) {
    float a = xr[k];
    const float* d = dn + (long)k * 16;
#pragma unroll
    for (int r = 0; r < 16; ++r) p[r] += a * d[r];
  }
#pragma unroll
  for (int r = 0; r < 16; ++r)
#pragma unroll
    for (int st = 1; st < 64; st <<= 1) p[r] += __shfl_xor(p[r], st, 64);
  int lane = threadIdx.x & 63, w = threadIdx.x >> 6;
  if (lane == 0) {
#pragma unroll
    for (int r = 0; r < 16; ++r) red[w][r] = p[r];
  }
  __syncthreads();
  if (threadIdx.x < 16) {
    int r = threadIdx.x;
    Wod[(long)m * 16 + r] = red[0][r] + red[1][r] + red[2][r] + red[3][r];
  }
}

// ---------------- prep_all: cvt hs(+t tail), ehs, img; pack biases; fill QKV B-tails ----------------
__launch_bounds__(256)
__global__ void prep_all(const float* __restrict__ hs, const float* __restrict__ tl,
                         u16* __restrict__ hsb,
                         const float* __restrict__ ehs, u16* __restrict__ ehsb,
                         const float* __restrict__ img, u16* __restrict__ imgb,
                         const float* __restrict__ baq, const float* __restrict__ bak,
                         const float* __restrict__ bav, const float* __restrict__ bq,
                         const float* __restrict__ bk, const float* __restrict__ bv,
                         float* __restrict__ bpk,
                         const float* __restrict__ u0, const float* __restrict__ u1,
                         const float* __restrict__ u2, u16* __restrict__ WTbM) {
  const int b = blockIdx.x;
  if (b < 3136) {  // hs -> hsb (ld 3136, cols 3072.. = LoRA t tail)
    long idx = (long)b * 256 + threadIdx.x;
    long m = idx / 392, c = idx % 392;
    U16x4 o0, o1;
    if (c < 384) {
      const float* p = hs + m * 3072 + c * 8;
      float4 a = *(const float4*)p;
      float4 bb = *(const float4*)(p + 4);
      o0 = U16x4{f2bf(a.x), f2bf(a.y), f2bf(a.z), f2bf(a.w)};
      o1 = U16x4{f2bf(bb.x), f2bf(bb.y), f2bf(bb.z), f2bf(bb.w)};
    } else {
      u16 t[8];
#pragma unroll
      for (int i = 0; i < 8; ++i) {
        int r = (int)(c - 384) * 8 + i;
        float v = (m >= 1024 && r < 48) ? tl[(m - 1024) * 48 + r] : 0.f;
        t[i] = f2bf(v);
      }
      o0 = U16x4{t[0], t[1], t[2], t[3]};
      o1 = U16x4{t[4], t[5], t[6], t[7]};
    }
    u16* d = hsb + m * 3136 + c * 8;
    *(U16x4*)d = o0;
    *(U16x4*)(d + 4) = o1;
  } else if (b < 3904) {  // ehs convert
    long i = ((long)(b - 3136) * 256 + threadIdx.x) * 8;
    float4 a = *(const float4*)(ehs + i);
    float4 bb = *(const float4*)(ehs + i + 4);
    *(U16x4*)(ehsb + i) = U16x4{f2bf(a.x), f2bf(a.y), f2bf(a.z), f2bf(a.w)};
    *(U16x4*)(ehsb + i + 4) = U16x4{f2bf(bb.x), f2bf(bb.y), f2bf(bb.z), f2bf(bb.w)};
  } else if (b < 4000) {  // img convert
    long i = ((long)(b - 3904) * 256 + threadIdx.x) * 8;
    float4 a = *(const float4*)(img + i);
    float4 bb = *(const float4*)(img + i + 4);
    *(U16x4*)(imgb + i) = U16x4{f2bf(a.x), f2bf(a.y), f2bf(a.z), f2bf(a.w)};
    *(U16x4*)(imgb + i + 4) = U16x4{f2bf(bb.x), f2bf(bb.y), f2bf(bb.z), f2bf(bb.w)};
  } else if (b < 4072) {  // bias packs: [0,9216)=enc, [9216,18432)=main
    int i = (b - 4000) * 256 + threadIdx.x;
    if (i < 9216)
      bpk[i] = (i < 3072) ? baq[i] : (i < 6144) ? bak[i - 3072] : bav[i - 6144];
    else {
      int j = i - 9216;
      bpk[i] = (j < 3072) ? bq[j] : (j < 6144) ? bk[j - 3072] : bv[j - 6144];
    }
  } else {  // QKV weight B-tails: WTbM[n][3072+i]
    int idx = (b - 4072) * 256 + threadIdx.x;  // 9216*64
    int n = idx >> 6, i = idx & 63;
    int seg = n / 3072;
    const float* up = (seg == 0) ? u0 : (seg == 1) ? u1 : u2;
    int r = i - seg * 16;
    float v = (r >= 0 && r < 16) ? up[(long)r * 3072 + (n - seg * 3072)] : 0.f;
    WTbM[(long)n * 3136 + 3072 + i] = f2bf(v);
  }
}

// ---------------- weight transpose (up to 6 matrices, per-z dst ld) ----------------
struct WT6 { const float* src[6]; u16* dst[6]; int ldd[6]; };

__launch_bounds__(256)
__global__ void transpose_w(WT6 args) {
  const float* src = args.src[blockIdx.z];
  u16* dst = args.dst[blockIdx.z];
  const int ldd = args.ldd[blockIdx.z];
  __shared__ float tile[32][33];
  int k0 = blockIdx.x * 32, n0 = blockIdx.y * 32;
  int r = threadIdx.x >> 3, c4 = (threadIdx.x & 7) * 4;
  float4 v = *(const float4*)(src + (long)(k0 + r) * 3072 + n0 + c4);
  tile[r][c4 + 0] = v.x; tile[r][c4 + 1] = v.y;
  tile[r][c4 + 2] = v.z; tile[r][c4 + 3] = v.w;
  __syncthreads();
  U16x4 o{f2bf(tile[c4 + 0][r]), f2bf(tile[c4 + 1][r]),
          f2bf(tile[c4 + 2][r]), f2bf(tile[c4 + 3][r])};
  *(U16x4*)(dst + (long)(n0 + r) * ldd + k0 + c4) = o;
}

// ---------------- Wo B-tail: WTbM[n][3072+i] = i<16 ? lp_up[i][n] : 0 ----------------
__launch_bounds__(256)
__global__ void fill_wo_tail(const float* __restrict__ lp_up, u16* __restrict__ WTbM) {
  int idx = blockIdx.x * 256 + threadIdx.x;  // 3072*64
  int n = idx >> 6, i = idx & 63;
  float v = (i < 16) ? lp_up[(long)i * 3072 + n] : 0.f;
  WTbM[(long)n * 3136 + 3072 + i] = f2bf(v);
}

// ---------------- AttnTok K-tail: t[m][16] = AttnTok_row @ Wod + bod (cond rows), else 0 ----------------
__launch_bounds__(256)
__global__ void t_tail(u16* __restrict__ At, const float* __restrict__ Wod) {
  __shared__ float red[4][16];
  const int tok = blockIdx.x;  // 0..2047 (main token m)
  u16* tail = At + (long)(512 + tok) * 3136 + 3072;
  if (tok < 1024) {
    if (threadIdx.x < 64) tail[threadIdx.x] = 0;
    return;
  }
  const u16* xr = At + (long)(512 + tok) * 3136;
  float p[16];
#pragma unroll
  for (int r = 0; r < 16; ++r) p[r] = 0.f;
  for (int n = threadIdx.x; n < 3072; n += 256) {
    float a = bf2f(xr[n]);
    const float* wd = Wod + (long)n * 16;
#pragma unroll
    for (int r = 0; r < 16; ++r) p[r] += a * wd[r];
  }
#pragma unroll
  for (int r = 0; r < 16; ++r)
#pragma unroll
    for (int st = 1; st < 64; st <<= 1) p[r] += __shfl_xor(p[r], st, 64);
  int lane = threadIdx.x & 63, w = threadIdx.x >> 6;
  if (lane == 0) {
#pragma unroll
    for (int r = 0; r < 16; ++r) red[w][r] = p[r];
  }
  __syncthreads();
  if (threadIdx.x < 64) {
    if (threadIdx.x < 16) {
      int r = threadIdx.x;
      float t = red[0][r] + red[1][r] + red[2][r] + red[3][r] + Wod[3072L * 16 + r];
      tail[r] = f2bf(t);
    } else {
      tail[threadIdx.x] = 0;
    }
  }
}

// ---------------- generic 128-col-tile GEMM -> f32 (IP partials, K-split via z) ----------------
template <int BM, int MI, int NI>
__launch_bounds__(256)
__global__ void gemm_f32(const u16* __restrict__ A, int lda,
                         const u16* __restrict__ B, int ldb,
                         float* __restrict__ C, int ldc,
                         const float* __restrict__ bias, int KC, long cstride) {
  constexpr int WCOLS = 128 / (NI * 16);
  constexpr int ABYTES = BM * 128;
  __shared__ char smem[ABYTES + 128 * 128];
  char* As = smem;
  char* Bs = smem + ABYTES;
  const int tid = threadIdx.x;
  const int w = tid >> 6, lane = tid & 63;
  const int lr = lane & 15, lg = lane >> 4;
  const int wr = w / WCOLS, wc = w % WCOLS;
  const int nbx = gridDim.x;
  const int nwg = nbx * gridDim.y;
  const int flat = blockIdx.y * nbx + blockIdx.x;
  const int swz = (flat & 7) * (nwg >> 3) + (flat >> 3);
  const long m0 = (long)(swz % nbx) * BM;
  const long n0 = (long)(swz / nbx) * 128;
  const int k0 = blockIdx.z * KC;
  C += blockIdx.z * cstride;
  f32x4 acc[MI][NI] = {};
  constexpr int ACH = BM / 32;
  for (int kb = k0; kb < k0 + KC; kb += 64) {
    __syncthreads();
#pragma unroll
    for (int i = 0; i < ACH; ++i) {
      int x = (tid + 256 * i) * 16;
      int row = x >> 7;
      int sx = x ^ ((row & 7) << 4);
      async16((const char*)(A + (m0 + row) * lda + kb) + (sx & 127),
              As + ((w << 10) + (i << 12)));
    }
#pragma unroll
    for (int i = 0; i < 4; ++i) {
      int x = (tid + 256 * i) * 16;
      int row = x >> 7;
      int sx = x ^ ((row & 7) << 4);
      async16((const char*)(B + (n0 + row) * ldb + kb) + (sx & 127),
              Bs + ((w << 10) + (i << 12)));
    }
    __syncthreads();
#pragma unroll
    for (int kc = 0; kc < 2; ++kc) {
      s16x8 af[MI], bfr[NI];
#pragma unroll
      for (int mi = 0; mi < MI; ++mi) {
        int row = wr * (MI * 16) + mi * 16 + lr;
        int b = ((row << 7) + kc * 64 + lg * 16) ^ ((row & 7) << 4);
        af[mi] = *(const s16x8*)(As + b);
      }
#pragma unroll
      for (int ni = 0; ni < NI; ++ni) {
        int row = wc * (NI * 16) + ni * 16 + lr;
        int b = ((row << 7) + kc * 64 + lg * 16) ^ ((row & 7) << 4);
        bfr[ni] = *(const s16x8*)(Bs + b);
      }
#pragma unroll
      for (int mi = 0; mi < MI; ++mi)
#pragma unroll
        for (int ni = 0; ni < NI; ++ni)
          acc[mi][ni] = __builtin_amdgcn_mfma_f32_16x16x32_bf16(af[mi], bfr[ni], acc[mi][ni], 0, 0, 0);
    }
  }
#pragma unroll
  for (int mi = 0; mi < MI; ++mi) {
#pragma unroll
    for (int ni = 0; ni < NI; ++ni) {
      long col = n0 + wc * (NI * 16) + ni * 16 + lr;
      float bv = bias ? bias[col] : 0.f;
#pragma unroll
      for (int j = 0; j < 4; ++j) {
        long row = m0 + wr * (MI * 16) + mi * 16 + lg * 4 + j;
        C[row * ldc + col] = acc[mi][ni][j] + bv;
      }
    }
  }
}

// ---------------- IP: sum 4 K-split partials + RMS + to_heads (K & V in one grid) ----------------
__launch_bounds__(256)
__global__ void rms_ip(const float* __restrict__ in, u16* __restrict__ Ko,
                       u16* __restrict__ Vo) {
  const int t = blockIdx.x & 63;
  const int vhalf = blockIdx.x >> 6;
  const int col0 = vhalf ? 3072 : 0;
  u16* out = vhalf ? Vo : Ko;
  const int w = threadIdx.x >> 6, lane = threadIdx.x & 63;
  const long ps = 64LL * 6144;
#pragma unroll
  for (int hh = 0; hh < 6; ++hh) {
    int h = w * 6 + hh;
    const float* x = in + (long)t * 6144 + col0 + h * 128 + lane * 2;
    float a = x[0] + x[ps] + x[2 * ps] + x[3 * ps];
    float b = x[1] + x[1 + ps] + x[1 + 2 * ps] + x[1 + 3 * ps];
    float scale = 1.f;
    if (!vhalf) {
      float ss = a * a + b * b;
#pragma unroll
      for (int st = 1; st < 64; st <<= 1) ss += __shfl_xor(ss, st, 64);
      scale = rsqrtf(ss * (1.f / 128.f) + 1e-5f);
    }
    unsigned pa = f2bf(a * scale), pb = f2bf(b * scale);
    *(unsigned*)(out + ((long)h * 64 + t) * 128 + lane * 2) = pa | (pb << 16);
  }
}

// ---------------- bf16 head transpose (T,128)->(128,T) per head (Vip only) ----------------
__launch_bounds__(256)
__global__ void transpose_v(const u16* __restrict__ VB, u16* __restrict__ VT, int T) {
  __shared__ u16 tile[32][34];
  int h = blockIdx.z;
  int t0 = blockIdx.x * 32, d0 = blockIdx.y * 32;
  int r = threadIdx.x >> 3, c4 = (threadIdx.x & 7) * 4;
  U16x4 v = *(const U16x4*)(VB + ((long)h * T + t0 + r) * 128 + d0 + c4);
  tile[r][c4 + 0] = v.x; tile[r][c4 + 1] = v.y;
  tile[r][c4 + 2] = v.z; tile[r][c4 + 3] = v.w;
  __syncthreads();
  U16x4 o{tile[c4 + 0][r], tile[c4 + 1][r], tile[c4 + 2][r], tile[c4 + 3][r]};
  *(U16x4*)(VT + ((long)h * 128 + d0 + r) * T + t0 + c4) = o;
}

// ---------------- fused QKV GEMM (enc + main in one dispatch), BM=128 x BN=256 ----------------
// grid (20,36): mx<4 -> enc (ehs, K=3072), else main (hs, K=3136, LoRA in K).
// 4 waves: wr=w>>1 m-half, wc=w&1 head. Epilogue: bias + in-wave RMS(Q,K) +
// head-split + V^T, via XOR-swizzled LDS bounce -> coalesced 16B stores.
__launch_bounds__(256, 2)
__global__ void gemm_qkv(const u16* __restrict__ Aenc, const u16* __restrict__ Amain,
                         const u16* __restrict__ Benc, const u16* __restrict__ Bmain,
                         u16* __restrict__ Qo, u16* __restrict__ Ko, u16* __restrict__ VTo,
                         const float* __restrict__ bpk) {
  __shared__ char smem[49152];  // As 16KB, Bs 32KB; epilogue reuses first 32KB
  char* As = smem;
  char* Bs = smem + 16384;
  const int tid = threadIdx.x;
  const int w = tid >> 6, lane = tid & 63;
  const int lr = lane & 15, lg = lane >> 4;
  const int wr = w >> 1, wc = w & 1;
  const int flat = blockIdx.y * 20 + blockIdx.x;          // 720 blocks
  const int swz = (flat & 7) * 90 + (flat >> 3);          // bijective (720 = 8*90)
  const int mx = swz % 20;
  const long n0 = (long)(swz / 20) * 256;
  const u16* A;
  const u16* B;
  const float* bias;
  int lda, ldb, K, t0;
  long m0;
  if (mx < 4) {
    A = Aenc; lda = 3072; B = Benc; ldb = 3072; K = 3072; t0 = 0;
    m0 = (long)mx * 128; bias = bpk;
  } else {
    A = Amain; lda = 3136; B = Bmain; ldb = 3136; K = 3136; t0 = 512;
    m0 = (long)(mx - 4) * 128; bias = bpk + 9216;
  }
  f32x4 acc[4][8] = {};
  for (int kb = 0; kb < K; kb += 64) {
    __syncthreads();
#pragma unroll
    for (int i = 0; i < 4; ++i) {  // A: 128 rows x 128B
      int x = (tid + 256 * i) * 16;
      int row = x >> 7;
      int sx = (x & 127) ^ ((row & 7) << 4);
      async16((const char*)(A + (m0 + row) * lda + kb) + sx, As + x);
    }
#pragma unroll
    for (int i = 0; i < 8; ++i) {  // B: 256 rows x 128B
      int x = (tid + 256 * i) * 16;
      int row = x >> 7;
      int sx = (x & 127) ^ ((row & 7) << 4);
      async16((const char*)(B + (n0 + row) * ldb + kb) + sx, Bs + x);
    }
    __syncthreads();
#pragma unroll
    for (int kc = 0; kc < 2; ++kc) {
      s16x8 af[4], bfr[8];
#pragma unroll
      for (int mi = 0; mi < 4; ++mi) {
        int row = wr * 64 + mi * 16 + lr;
        af[mi] = *(const s16x8*)(As + (row << 7) + ((kc * 64 + lg * 16) ^ ((row & 7) << 4)));
      }
#pragma unroll
      for (int ni = 0; ni < 8; ++ni) {
        int row = wc * 128 + ni * 16 + lr;
        bfr[ni] = *(const s16x8*)(Bs + (row << 7) + ((kc * 64 + lg * 16) ^ ((row & 7) << 4)));
      }
#pragma unroll
      for (int mi = 0; mi < 4; ++mi)
#pragma unroll
        for (int ni = 0; ni < 8; ++ni)
          acc[mi][ni] = __builtin_amdgcn_mfma_f32_16x16x32_bf16(af[mi], bfr[ni], acc[mi][ni], 0, 0, 0);
    }
  }
  // ---- epilogue ----
  const int seg = (int)(n0 / 3072);
  const int head0 = (int)((n0 % 3072) >> 7);
#pragma unroll
  for (int ni = 0; ni < 8; ++ni) {
    float bv = bias[n0 + wc * 128 + ni * 16 + lr];
#pragma unroll
    for (int mi = 0; mi < 4; ++mi)
#pragma unroll
      for (int j = 0; j < 4; ++j) acc[mi][ni][j] += bv;
  }
  float scl[4][4];
  if (seg < 2) {  // in-wave RMS over the head's 128 dims
#pragma unroll
    for (int mi = 0; mi < 4; ++mi)
#pragma unroll
      for (int j = 0; j < 4; ++j) {
        float s = 0.f;
#pragma unroll
        for (int ni = 0; ni < 8; ++ni) s += acc[mi][ni][j] * acc[mi][ni][j];
#pragma unroll
        for (int st = 1; st < 16; st <<= 1) s += __shfl_xor(s, st, 16);
        scl[mi][j] = rsqrtf(s * (1.f / 128.f) + 1e-5f);
      }
  }
#pragma unroll
  for (int ph = 0; ph < 2; ++ph) {
    __syncthreads();
    if (wc == ph) {
      if (seg < 2) {  // LDS [tok][d] bf16, XOR-swizzled
#pragma unroll
        for (int mi = 0; mi < 4; ++mi)
#pragma unroll
          for (int ni = 0; ni < 8; ++ni) {
            int d2 = (ni * 16 + lr) * 2;
#pragma unroll
            for (int j = 0; j < 4; ++j) {
              int tok = wr * 64 + mi * 16 + lg * 4 + j;
              *(u16*)(smem + tok * 256 + (d2 ^ ((tok & 7) << 4))) =
                  f2bf(acc[mi][ni][j] * scl[mi][j]);
            }
          }
      } else {  // LDS [d][tok] bf16, XOR-swizzled, 8B packed writes
#pragma unroll
        for (int mi = 0; mi < 4; ++mi)
#pragma unroll
          for (int ni = 0; ni < 8; ++ni) {
            int d = ni * 16 + lr;
            int tok0b = (wr * 64 + mi * 16 + lg * 4) * 2;
            U16x4 o{f2bf(acc[mi][ni][0]), f2bf(acc[mi][ni][1]),
                    f2bf(acc[mi][ni][2]), f2bf(acc[mi][ni][3])};
            *(U16x4*)(smem + d * 256 + (tok0b ^ ((d & 7) << 4))) = o;
          }
      }
    }
    __syncthreads();
    const int headp = head0 + ph;
#pragma unroll
    for (int i = 0; i < 8; ++i) {
      int x = (tid + 256 * i) * 16;
      int row = x >> 8, col = x & 255;
      s16x8 vdat = *(const s16x8*)(smem + row * 256 + (col ^ ((row & 7) << 4)));
      if (seg < 2) {
        u16* g = (seg == 0 ? Qo : Ko) + ((long)headp * 2560 + t0 + m0 + row) * 128;
        *(s16x8*)((char*)g + col) = vdat;
      } else {
        u16* g = VTo + ((long)headp * 128 + row) * 2560 + t0 + m0;
        *(s16x8*)((char*)g + col) = vdat;
      }
    }
  }
}

// ---------------- fused output projection: enc(Wao,K=3072) + main(Wo+lp_up,K=3136) ----------------
__launch_bounds__(256)
__global__ void gemm_out(const u16* __restrict__ Atok, const u16* __restrict__ Benc,
                         const u16* __restrict__ Bmain, float* __restrict__ outp,
                         const float* __restrict__ bao, const float* __restrict__ bo) {
  __shared__ char smem[128 * 128 + 128 * 128];
  char* As = smem;
  char* Bs = smem + 128 * 128;
  const int tid = threadIdx.x;
  const int w = tid >> 6, lane = tid & 63;
  const int lr = lane & 15, lg = lane >> 4;
  const int wr = w >> 1, wc = w & 1;
  const int flat = blockIdx.y * 20 + blockIdx.x;
  const int swz = (flat & 7) * 60 + (flat >> 3);
  const int mx = swz % 20;
  const long n0 = (long)(swz / 20) * 128;
  const u16* A;
  const u16* B;
  const float* bias;
  float* C;
  int ldb, K;
  long m0;
  if (mx < 4) {
    A = Atok; B = Benc; ldb = 3072; K = 3072; bias = bao; C = outp;
    m0 = (long)mx * 128;
  } else {
    A = Atok + 512L * 3136; B = Bmain; ldb = 3136; K = 3136; bias = bo;
    C = outp + 512L * 3072; m0 = (long)(mx - 4) * 128;
  }
  f32x4 acc[4][4] = {};
  for (int kb = 0; kb < K; kb += 64) {
    __syncthreads();
#pragma unroll
    for (int i = 0; i < 4; ++i) {
      int x = (tid + 256 * i) * 16;
      int row = x >> 7;
      int sx = x ^ ((row & 7) << 4);
      async16((const char*)(A + (m0 + row) * 3136 + kb) + (sx & 127),
              As + ((w << 10) + (i << 12)));
    }
#pragma unroll
    for (int i = 0; i < 4; ++i) {
      int x = (tid + 256 * i) * 16;
      int row = x >> 7;
      int sx = x ^ ((row & 7) << 4);
      async16((const char*)(B + (n0 + row) * ldb + kb) + (sx & 127),
              Bs + ((w << 10) + (i << 12)));
    }
    __syncthreads();
#pragma unroll
    for (int kc = 0; kc < 2; ++kc) {
      s16x8 af[4], bfr[4];
#pragma unroll
      for (int mi = 0; mi < 4; ++mi) {
        int row = wr * 64 + mi * 16 + lr;
        int b = ((row << 7) + kc * 64 + lg * 16) ^ ((row & 7) << 4);
        af[mi] = *(const s16x8*)(As + b);
      }
#pragma unroll
      for (int ni = 0; ni < 4; ++ni) {
        int row = wc * 64 + ni * 16 + lr;
        int b = ((row << 7) + kc * 64 + lg * 16) ^ ((row & 7) << 4);
        bfr[ni] = *(const s16x8*)(Bs + b);
      }
#pragma unroll
      for (int mi = 0; mi < 4; ++mi)
#pragma unroll
        for (int ni = 0; ni < 4; ++ni)
          acc[mi][ni] = __builtin_amdgcn_mfma_f32_16x16x32_bf16(af[mi], bfr[ni], acc[mi][ni], 0, 0, 0);
    }
  }
#pragma unroll
  for (int mi = 0; mi < 4; ++mi) {
#pragma unroll
    for (int ni = 0; ni < 4; ++ni) {
      long col = n0 + wc * 64 + ni * 16 + lr;
      float bv = bias[col];
#pragma unroll
      for (int j = 0; j < 4; ++j) {
        long row = m0 + wr * 64 + mi * 16 + lg * 4 + j;
        C[row * 3072 + col] = acc[mi][ni][j] + bv;
      }
    }
  }
}

// ---------------- fused attention: 128 q/block (8 waves), dbuf KV, static-max softmax, IP fused ----------------
__launch_bounds__(512, 4)
__global__ void attn_fused(const u16* __restrict__ QB, const u16* __restrict__ KB,
                           const u16* __restrict__ VT, const u16* __restrict__ KipB,
                           const u16* __restrict__ VipT, u16* __restrict__ OutTok) {
  __shared__ char smem[81920];
  const int tid = threadIdx.x, w = tid >> 6, lane = tid & 63;
  const int lr = lane & 15, lg = lane >> 4;
  const int h = blockIdx.y;
  const int q0 = blockIdx.x * 128;
  const bool ip = (q0 >= 512);
  const u16* Qrow = QB + (long)(h * 2560 + q0 + w * 16 + lr) * 128;
  s16x8 qf[4];
#pragma unroll
  for (int dc = 0; dc < 4; ++dc) qf[dc] = *(const s16x8*)(Qrow + dc * 32 + lg * 8);
  f32x4 accO[8] = {};
  float l_r[4] = {0.f, 0.f, 0.f, 0.f};
  const int kv0 = (q0 >= 1536) ? 1536 : 0;
  const float sc = 0.08838834764831845f;

  auto stage_main = [&](int kv, int buf) {
#pragma unroll
    for (int i = 0; i < 2; ++i) {
      int x = (tid + 512 * i) * 16;
      int row = x >> 8;
      int sx = x ^ ((row & 7) << 4);
      async16((const char*)(KB + (long)(h * 2560 + kv + row) * 128) + (sx & 255),
              smem + buf * 16384 + ((i << 13) + (w << 10)));
    }
#pragma unroll
    for (int i = 0; i < 2; ++i) {
      int x = (tid + 512 * i) * 16;
      int row = x >> 7;
      int sx = x ^ ((row & 7) << 4);
      async16((const char*)(VT + (long)(h * 128 + row) * 2560 + kv) + (sx & 127),
              smem + 32768 + buf * 16384 + ((i << 13) + (w << 10)));
    }
  };
  auto stage_ip = [&](int buf) {
#pragma unroll
    for (int i = 0; i < 2; ++i) {
      int x = (tid + 512 * i) * 16;
      int row = x >> 8;
      int sx = x ^ ((row & 7) << 4);
      async16((const char*)(KipB + (long)(h * 64 + row) * 128) + (sx & 255),
              smem + buf * 16384 + ((i << 13) + (w << 10)));
    }
#pragma unroll
    for (int i = 0; i < 2; ++i) {
      int x = (tid + 512 * i) * 16;
      int row = x >> 7;
      int sx = x ^ ((row & 7) << 4);
      async16((const char*)(VipT + (long)(h * 128 + row) * 64) + (sx & 127),
              smem + 32768 + buf * 16384 + ((i << 13) + (w << 10)));
    }
  };

  stage_main(kv0, 0);
  __syncthreads();
  int cur = 0;
  for (int kv = kv0; kv < 2560; kv += 64) {
    if (kv + 64 < 2560) stage_main(kv + 64, cur ^ 1);
    else if (ip) stage_ip(cur ^ 1);
    const char* Ks = smem + cur * 16384;
    const char* Vs = smem + 32768 + cur * 16384;
    char* Pw = smem + 65536 + w * 2048;
    f32x4 s[4] = {};
#pragma unroll
    for (int kt = 0; kt < 4; ++kt)
#pragma unroll
      for (int dc = 0; dc < 4; ++dc) {
        int row = kt * 16 + lr;
        int b = ((row << 8) + dc * 64 + lg * 16) ^ ((row & 7) << 4);
        s16x8 kf = *(const s16x8*)(Ks + b);
        s[kt] = __builtin_amdgcn_mfma_f32_16x16x32_bf16(qf[dc], kf, s[kt], 0, 0, 0);
      }
#pragma unroll
    for (int kt = 0; kt < 4; ++kt)
#pragma unroll
      for (int j = 0; j < 4; ++j) {
        float pv = __expf(fmaf(s[kt][j], sc, -12.0f));
        l_r[j] += pv;
        int prow = lg * 4 + j;
        int b = ((prow << 7) + (kt * 16 + lr) * 2) ^ ((prow & 7) << 4);
        *(u16*)(Pw + b) = f2bf(pv);
      }
    asm volatile("s_waitcnt lgkmcnt(0)" ::: "memory");
#pragma unroll
    for (int kc = 0; kc < 2; ++kc) {
      int pb = ((lr << 7) + kc * 64 + lg * 16) ^ ((lr & 7) << 4);
      s16x8 pf = *(const s16x8*)(Pw + pb);
#pragma unroll
      for (int dt = 0; dt < 8; ++dt) {
        int row = dt * 16 + lr;
        int b = ((row << 7) + kc * 64 + lg * 16) ^ ((row & 7) << 4);
        s16x8 vf = *(const s16x8*)(Vs + b);
        accO[dt] = __builtin_amdgcn_mfma_f32_16x16x32_bf16(pf, vf, accO[dt], 0, 0, 0);
      }
    }
    __syncthreads();
    cur ^= 1;
  }
#pragma unroll
  for (int j = 0; j < 4; ++j) {
#pragma unroll
    for (int st = 1; st < 16; st <<= 1) l_r[j] += __shfl_xor(l_r[j], st, 16);
    l_r[j] = 1.f / l_r[j];
  }
#pragma unroll
  for (int dt = 0; dt < 8; ++dt)
#pragma unroll
    for (int j = 0; j < 4; ++j) accO[dt][j] *= l_r[j];
  if (ip) {
    const char* Ks = smem + cur * 16384;
    const char* Vs = smem + 32768 + cur * 16384;
    char* Pw = smem + 65536 + w * 2048;
    f32x4 s2[4] = {};
#pragma unroll
    for (int kt = 0; kt < 4; ++kt)
#pragma unroll
      for (int dc = 0; dc < 4; ++dc) {
        int row = kt * 16 + lr;
        int b = ((row << 8) + dc * 64 + lg * 16) ^ ((row & 7) << 4);
        s16x8 kf = *(const s16x8*)(Ks + b);
        s2[kt] = __builtin_amdgcn_mfma_f32_16x16x32_bf16(qf[dc], kf, s2[kt], 0, 0, 0);
      }
    float p2[4][4];
    float l2[4] = {0.f, 0.f, 0.f, 0.f};
#pragma unroll
    for (int kt = 0; kt < 4; ++kt)
#pragma unroll
      for (int j = 0; j < 4; ++j) {
        float pv = __expf(fmaf(s2[kt][j], sc, -12.0f));
        p2[kt][j] = pv;
        l2[j] += pv;
      }
#pragma unroll
    for (int j = 0; j < 4; ++j) {
#pragma unroll
      for (int st = 1; st < 16; st <<= 1) l2[j] += __shfl_xor(l2[j], st, 16);
      l2[j] = 1.f / l2[j];
    }
#pragma unroll
    for (int kt = 0; kt < 4; ++kt)
#pragma unroll
      for (int j = 0; j < 4; ++j) {
        int prow = lg * 4 + j;
        int b = ((prow << 7) + (kt * 16 + lr) * 2) ^ ((prow & 7) << 4);
        *(u16*)(Pw + b) = f2bf(p2[kt][j] * l2[j]);
      }
    asm volatile("s_waitcnt lgkmcnt(0)" ::: "memory");
#pragma unroll
    for (int kc = 0; kc < 2; ++kc) {
      int pb = ((lr << 7) + kc * 64 + lg * 16) ^ ((lr & 7) << 4);
      s16x8 pf = *(const s16x8*)(Pw + pb);
#pragma unroll
      for (int dt = 0; dt < 8; ++dt) {
        int row = dt * 16 + lr;
        int b = ((row << 7) + kc * 64 + lg * 16) ^ ((row & 7) << 4);
        s16x8 vf = *(const s16x8*)(Vs + b);
        accO[dt] = __builtin_amdgcn_mfma_f32_16x16x32_bf16(pf, vf, accO[dt], 0, 0, 0);
      }
    }
  }
#pragma unroll
  for (int j = 0; j < 4; ++j) {
    long tok = q0 + w * 16 + lg * 4 + j;
#pragma unroll
    for (int dt = 0; dt < 8; ++dt) {
      long col = h * 128 + dt * 16 + lr;
      OutTok[tok * 3136 + col] = f2bf(accO[dt][j]);
    }
  }
}

// =====================================================================

extern "C" void kernel_launch(void* const* d_in, const int* in_sizes, int n_in,
                              void* d_out, int out_size, void* d_ws, size_t ws_size,
                              hipStream_t stream) {
  const float* hs    = (const float*)d_in[0];
  const float* ehs   = (const float*)d_in[1];
  const float* img   = (const float*)d_in[2];
  const float* Wq    = (const float*)d_in[3];
  const float* bq    = (const float*)d_in[4];
  const float* Wk    = (const float*)d_in[5];
  const float* bk    = (const float*)d_in[6];
  const float* Wv    = (const float*)d_in[7];
  const float* bv    = (const float*)d_in[8];
  const float* Waq   = (const float*)d_in[9];
  const float* baq   = (const float*)d_in[10];
  const float* Wak   = (const float*)d_in[11];
  const float* bak   = (const float*)d_in[12];
  const float* Wav   = (const float*)d_in[13];
  const float* bav   = (const float*)d_in[14];
  const float* Wo    = (const float*)d_in[15];
  const float* bo    = (const float*)d_in[16];
  const float* Wao   = (const float*)d_in[17];
  const float* bao   = (const float*)d_in[18];
  const float* Wkip  = (const float*)d_in[19];
  const float* Wvip  = (const float*)d_in[20];
  const float* lq_dn = (const float*)d_in[21];
  const float* lq_up = (const float*)d_in[22];
  const float* lk_dn = (const float*)d_in[23];
  const float* lk_up = (const float*)d_in[24];
  const float* lv_dn = (const float*)d_in[25];
  const float* lv_up = (const float*)d_in[26];
  const float* lp_dn = (const float*)d_in[27];
  const float* lp_up = (const float*)d_in[28];
  float* outp = (float*)d_out;

  char* ws = (char*)d_ws;
  size_t off = 0;
  auto take = [&](size_t b) { char* p = ws + off; off += (b + 255) & ~(size_t)255; return p; };
  u16*   WTbE = (u16*)take(3LL * 3072 * 3072 * 2);  // enc-weight slots, ld 3072
  u16*   WTbM = (u16*)take(3LL * 3072 * 3136 * 2);  // main-weight slots, ld 3136 (K-tail)
  u16*   hsb  = (u16*)take(2048LL * 3136 * 2);      // + AttnTok alias base
  u16*   ehsb = (u16*)take(512LL * 3072 * 2);
  u16*   imgb = (u16*)take(64LL * 3072 * 2);
  u16*   VTf  = (u16*)take(24LL * 128 * 2560 * 2);
  float* IP0  = (float*)take(4LL * 64 * 6144 * 4);
  u16*   KipB = (u16*)take(24LL * 64 * 128 * 2);
  u16*   VipB = (u16*)take(24LL * 64 * 128 * 2);
  u16*   VipT = (u16*)take(24LL * 128 * 64 * 2);
  float* bpk  = (float*)take(2 * 9216 * 4);
  float* tl   = (float*)take(1024LL * 48 * 4);
  float* Wod  = (float*)take(3073LL * 16 * 4);
  // aliases: QBf/KBf live in d_out (dead before gemm_out writes it);
  // AttnTok (2560x3136 bf16) overlays hsb+ehsb+imgb (dead after projections).
  u16* QBf = (u16*)d_out;
  u16* KBf = (u16*)d_out + 24LL * 2560 * 128;
  u16* AttnTok = hsb;
  u16* E1 = WTbE + 3072LL * 3072;

  // 1. LoRA-down (fp32 hs) -> t; prep (converts + bias packs + QKV B-tails); Wod
  lora_dn3<<<1024, 256, 0, stream>>>(hs + 1024LL * 3072, 3072, lq_dn, lk_dn, lv_dn, tl);
  prep_all<<<6376, 256, 0, stream>>>(hs, tl, hsb, ehs, ehsb, img, imgb,
                                     baq, bak, bav, bq, bk, bv, bpk,
                                     lq_up, lk_up, lv_up, WTbM);
  wod_prep<<<3073, 256, 0, stream>>>(Wo, bo, lp_dn, Wod);

  // 2. transpose all 6 QKV weights in one dispatch
  {
    WT6 a;
    a.src[0] = Waq; a.dst[0] = WTbE;                    a.ldd[0] = 3072;
    a.src[1] = Wak; a.dst[1] = WTbE + 3072LL * 3072;    a.ldd[1] = 3072;
    a.src[2] = Wav; a.dst[2] = WTbE + 2 * 3072LL * 3072; a.ldd[2] = 3072;
    a.src[3] = Wq;  a.dst[3] = WTbM;                    a.ldd[3] = 3136;
    a.src[4] = Wk;  a.dst[4] = WTbM + 3072LL * 3136;    a.ldd[4] = 3136;
    a.src[5] = Wv;  a.dst[5] = WTbM + 2 * 3072LL * 3136; a.ldd[5] = 3136;
    transpose_w<<<dim3(96, 96, 6), 256, 0, stream>>>(a);
  }

  // 3. fused enc+main QKV GEMM (720 blocks, all resident)
  gemm_qkv<<<dim3(20, 36), 256, 0, stream>>>(ehsb, hsb, WTbE, WTbM, QBf, KBf, VTf, bpk);

  // 4. transpose IP/out weights (reusing slots), fill Wo's lp_up K-tail
  {
    WT6 a;
    a.src[0] = Wao;  a.dst[0] = WTbE;                    a.ldd[0] = 3072;
    a.src[1] = Wkip; a.dst[1] = E1;                      a.ldd[1] = 3072;
    a.src[2] = Wvip; a.dst[2] = WTbE + 2 * 3072LL * 3072; a.ldd[2] = 3072;
    a.src[3] = Wo;   a.dst[3] = WTbM;                    a.ldd[3] = 3136;
    a.src[4] = Wao;  a.dst[4] = WTbE;                    a.ldd[4] = 3072;  // unused
    a.src[5] = Wao;  a.dst[5] = WTbE;                    a.ldd[5] = 3072;  // unused
    transpose_w<<<dim3(96, 96, 4), 256, 0, stream>>>(a);
  }
  fill_wo_tail<<<768, 256, 0, stream>>>(lp_up, WTbM);

  // 5. IP projections (K-split x4) + fused sum/RMS + Vip transpose
  gemm_f32<64, 4, 2><<<dim3(1, 48, 4), 256, 0, stream>>>(imgb, 3072, E1, 3072, IP0, 6144,
                                                          nullptr, 768, 64LL * 6144);
  rms_ip<<<128, 256, 0, stream>>>(IP0, KipB, VipB);
  transpose_v<<<dim3(2, 4, 24), 256, 0, stream>>>(VipB, VipT, 64);

  // 6. attention (IP fused), writes AttnTok (ld 3136)
  attn_fused<<<dim3(20, 24), 512, 0, stream>>>(QBf, KBf, VTf, KipB, VipT, AttnTok);

  // 7. LoRA-p t into AttnTok K-tail, then fused output projection (lp folded in K)
  t_tail<<<2048, 256, 0, stream>>>(AttnTok, Wod);
  gemm_out<<<dim3(20, 24), 256, 0, stream>>>(AttnTok, WTbE, WTbM, outp, bao, bo);
}

// Round 7
// 577.234 us; speedup vs baseline: 1.4428x; 1.1130x over previous
//
#include <hip/hip_runtime.h>

typedef unsigned short u16;
typedef short s16x8 __attribute__((ext_vector_type(8)));
typedef float f32x4 __attribute__((ext_vector_type(4)));
typedef const __attribute__((address_space(1))) unsigned int* as1_u32p;
typedef __attribute__((address_space(3))) unsigned int* as3_u32p;

static_assert(sizeof(s16x8) == 16, "");

struct alignas(8) U16x4 { u16 x, y, z, w; };

__device__ __forceinline__ u16 f2bf(float f) {
  union { float f; unsigned u; } c; c.f = f;
  return (u16)((c.u + 0x7fffu + ((c.u >> 16) & 1u)) >> 16);
}
__device__ __forceinline__ float bf2f(u16 h) {
  union { unsigned u; float f; } c; c.u = ((unsigned)h) << 16;
  return c.f;
}
__device__ __forceinline__ void async16(const void* g, void* l) {
  __builtin_amdgcn_global_load_lds((as1_u32p)g, (as3_u32p)l, 16, 0, 0);
}

// ---------------- fused 3-way LoRA down: t[m][48] = hs_cond[m] @ [lq|lk|lv]_dn ----------------
__launch_bounds__(256)
__global__ void lora_dn3(const float* __restrict__ X, int ldx,
                         const float* __restrict__ d0, const float* __restrict__ d1,
                         const float* __restrict__ d2, float* __restrict__ t) {
  __shared__ float red[4][48];
  const int m = blockIdx.x;
  const float* xr = X + (long)m * ldx;
  float p[48];
#pragma unroll
  for (int r = 0; r < 48; ++r) p[r] = 0.f;
  for (int k = threadIdx.x; k < 3072; k += 256) {
    float a = xr[k];
    const float* e0 = d0 + (long)k * 16;
    const float* e1 = d1 + (long)k * 16;
    const float* e2 = d2 + (long)k * 16;
#pragma unroll
    for (int r = 0; r < 16; ++r) {
      p[r]      += a * e0[r];
      p[16 + r] += a * e1[r];
      p[32 + r] += a * e2[r];
    }
  }
#pragma unroll
  for (int r = 0; r < 48; ++r)
#pragma unroll
    for (int st = 1; st < 64; st <<= 1) p[r] += __shfl_xor(p[r], st, 64);
  int lane = threadIdx.x & 63, w = threadIdx.x >> 6;
  if (lane == 0) {
#pragma unroll
    for (int r = 0; r < 48; ++r) red[w][r] = p[r];
  }
  __syncthreads();
  if (threadIdx.x < 48) {
    int r = threadIdx.x;
    t[(long)m * 48 + r] = red[0][r] + red[1][r] + red[2][r] + red[3][r];
  }
}

// ---------------- MEGA prep: 6 weight transposes + wod_prep + activation/bias/tail prep ----------------
// blocks [0,55296): transpose {Waq,Wak,Wav}->WTbE(ld3072), {Wq,Wk,Wv}->WTbM(ld3136)
// blocks [55296,58369): Wod[k][16] = Wo[k,:]@lp_dn (row 3072 = bo@lp_dn)
// blocks [58369,64745): prep_all body (hs+t tail, ehs, img, bias packs, WTbM K-tails)
__launch_bounds__(256)
__global__ void mega_prep(const float* __restrict__ Waq, const float* __restrict__ Wak,
                          const float* __restrict__ Wav, const float* __restrict__ Wq,
                          const float* __restrict__ Wk, const float* __restrict__ Wv,
                          u16* __restrict__ WTbE, u16* __restrict__ WTbM,
                          const float* __restrict__ Wo, const float* __restrict__ bo,
                          const float* __restrict__ lp_dn, float* __restrict__ Wod,
                          const float* __restrict__ hs, const float* __restrict__ tl,
                          u16* __restrict__ hsb,
                          const float* __restrict__ ehs, u16* __restrict__ ehsb,
                          const float* __restrict__ img, u16* __restrict__ imgb,
                          const float* __restrict__ baq, const float* __restrict__ bak,
                          const float* __restrict__ bav, const float* __restrict__ bq,
                          const float* __restrict__ bk, const float* __restrict__ bv,
                          float* __restrict__ bpk,
                          const float* __restrict__ u0, const float* __restrict__ u1,
                          const float* __restrict__ u2) {
  __shared__ char lmem[4352];
  const int b = blockIdx.x;
  if (b < 55296) {  // weight transpose, one 32x32 tile
    int mat = b / 9216, tile = b % 9216;
    const float* src = (mat == 0) ? Waq : (mat == 1) ? Wak : (mat == 2) ? Wav
                       : (mat == 3) ? Wq : (mat == 4) ? Wk : Wv;
    u16* dst = (mat < 3) ? WTbE + (long)mat * 3072 * 3072
                         : WTbM + (long)(mat - 3) * 3072 * 3136;
    const int ldd = (mat < 3) ? 3072 : 3136;
    float (*tile2)[33] = (float(*)[33])lmem;
    int k0 = (tile / 96) * 32, n0 = (tile % 96) * 32;
    int r = threadIdx.x >> 3, c4 = (threadIdx.x & 7) * 4;
    float4 v = *(const float4*)(src + (long)(k0 + r) * 3072 + n0 + c4);
    tile2[r][c4 + 0] = v.x; tile2[r][c4 + 1] = v.y;
    tile2[r][c4 + 2] = v.z; tile2[r][c4 + 3] = v.w;
    __syncthreads();
    U16x4 o{f2bf(tile2[c4 + 0][r]), f2bf(tile2[c4 + 1][r]),
            f2bf(tile2[c4 + 2][r]), f2bf(tile2[c4 + 3][r])};
    *(U16x4*)(dst + (long)(n0 + r) * ldd + k0 + c4) = o;
  } else if (b < 58369) {  // wod_prep
    const int m = b - 55296;  // 0..3072
    float (*red)[16] = (float(*)[16])lmem;
    const float* xr = (m < 3072) ? Wo + (long)m * 3072 : bo;
    float p[16];
#pragma unroll
    for (int r = 0; r < 16; ++r) p[r] = 0.f;
    for (int k = threadIdx.x; k < 3072; k += 256) {
      float a = xr[k];
      const float* d = lp_dn + (long)k * 16;
#pragma unroll
      for (int r = 0; r < 16; ++r) p[r] += a * d[r];
    }
#pragma unroll
    for (int r = 0; r < 16; ++r)
#pragma unroll
      for (int st = 1; st < 64; st <<= 1) p[r] += __shfl_xor(p[r], st, 64);
    int lane = threadIdx.x & 63, w = threadIdx.x >> 6;
    if (lane == 0) {
#pragma unroll
      for (int r = 0; r < 16; ++r) red[w][r] = p[r];
    }
    __syncthreads();
    if (threadIdx.x < 16) {
      int r = threadIdx.x;
      Wod[(long)m * 16 + r] = red[0][r] + red[1][r] + red[2][r] + red[3][r];
    }
  } else {  // prep_all body
    const int pb = b - 58369;
    if (pb < 3136) {  // hs -> hsb (ld 3136, cols 3072.. = LoRA t tail)
      long idx = (long)pb * 256 + threadIdx.x;
      long m = idx / 392, c = idx % 392;
      U16x4 o0, o1;
      if (c < 384) {
        const float* p = hs + m * 3072 + c * 8;
        float4 a = *(const float4*)p;
        float4 bb = *(const float4*)(p + 4);
        o0 = U16x4{f2bf(a.x), f2bf(a.y), f2bf(a.z), f2bf(a.w)};
        o1 = U16x4{f2bf(bb.x), f2bf(bb.y), f2bf(bb.z), f2bf(bb.w)};
      } else {
        u16 t[8];
#pragma unroll
        for (int i = 0; i < 8; ++i) {
          int r = (int)(c - 384) * 8 + i;
          float v = (m >= 1024 && r < 48) ? tl[(m - 1024) * 48 + r] : 0.f;
          t[i] = f2bf(v);
        }
        o0 = U16x4{t[0], t[1], t[2], t[3]};
        o1 = U16x4{t[4], t[5], t[6], t[7]};
      }
      u16* d = hsb + m * 3136 + c * 8;
      *(U16x4*)d = o0;
      *(U16x4*)(d + 4) = o1;
    } else if (pb < 3904) {  // ehs convert
      long i = ((long)(pb - 3136) * 256 + threadIdx.x) * 8;
      float4 a = *(const float4*)(ehs + i);
      float4 bb = *(const float4*)(ehs + i + 4);
      *(U16x4*)(ehsb + i) = U16x4{f2bf(a.x), f2bf(a.y), f2bf(a.z), f2bf(a.w)};
      *(U16x4*)(ehsb + i + 4) = U16x4{f2bf(bb.x), f2bf(bb.y), f2bf(bb.z), f2bf(bb.w)};
    } else if (pb < 4000) {  // img convert
      long i = ((long)(pb - 3904) * 256 + threadIdx.x) * 8;
      float4 a = *(const float4*)(img + i);
      float4 bb = *(const float4*)(img + i + 4);
      *(U16x4*)(imgb + i) = U16x4{f2bf(a.x), f2bf(a.y), f2bf(a.z), f2bf(a.w)};
      *(U16x4*)(imgb + i + 4) = U16x4{f2bf(bb.x), f2bf(bb.y), f2bf(bb.z), f2bf(bb.w)};
    } else if (pb < 4072) {  // bias packs
      int i = (pb - 4000) * 256 + threadIdx.x;
      if (i < 9216)
        bpk[i] = (i < 3072) ? baq[i] : (i < 6144) ? bak[i - 3072] : bav[i - 6144];
      else {
        int j = i - 9216;
        bpk[i] = (j < 3072) ? bq[j] : (j < 6144) ? bk[j - 3072] : bv[j - 6144];
      }
    } else {  // QKV weight K-tails
      int idx = (pb - 4072) * 256 + threadIdx.x;  // 9216*64
      int n = idx >> 6, i = idx & 63;
      int seg = n / 3072;
      const float* up = (seg == 0) ? u0 : (seg == 1) ? u1 : u2;
      int r = i - seg * 16;
      float v = (r >= 0 && r < 16) ? up[(long)r * 3072 + (n - seg * 3072)] : 0.f;
      WTbM[(long)n * 3136 + 3072 + i] = f2bf(v);
    }
  }
}

// ---------------- small weight transpose (Wkip/Wvip) ----------------
struct WT2 { const float* src[2]; u16* dst[2]; };

__launch_bounds__(256)
__global__ void transpose_kv(WT2 args) {
  const float* src = args.src[blockIdx.z];
  u16* dst = args.dst[blockIdx.z];
  __shared__ float tile[32][33];
  int k0 = blockIdx.x * 32, n0 = blockIdx.y * 32;
  int r = threadIdx.x >> 3, c4 = (threadIdx.x & 7) * 4;
  float4 v = *(const float4*)(src + (long)(k0 + r) * 3072 + n0 + c4);
  tile[r][c4 + 0] = v.x; tile[r][c4 + 1] = v.y;
  tile[r][c4 + 2] = v.z; tile[r][c4 + 3] = v.w;
  __syncthreads();
  U16x4 o{f2bf(tile[c4 + 0][r]), f2bf(tile[c4 + 1][r]),
          f2bf(tile[c4 + 2][r]), f2bf(tile[c4 + 3][r])};
  *(U16x4*)(dst + (long)(n0 + r) * 3072 + k0 + c4) = o;
}

// ---------------- AttnTok K-tail ----------------
__launch_bounds__(256)
__global__ void t_tail(u16* __restrict__ At, const float* __restrict__ Wod) {
  __shared__ float red[4][16];
  const int tok = blockIdx.x;
  u16* tail = At + (long)(512 + tok) * 3136 + 3072;
  if (tok < 1024) {
    if (threadIdx.x < 64) tail[threadIdx.x] = 0;
    return;
  }
  const u16* xr = At + (long)(512 + tok) * 3136;
  float p[16];
#pragma unroll
  for (int r = 0; r < 16; ++r) p[r] = 0.f;
  for (int n = threadIdx.x; n < 3072; n += 256) {
    float a = bf2f(xr[n]);
    const float* wd = Wod + (long)n * 16;
#pragma unroll
    for (int r = 0; r < 16; ++r) p[r] += a * wd[r];
  }
#pragma unroll
  for (int r = 0; r < 16; ++r)
#pragma unroll
    for (int st = 1; st < 64; st <<= 1) p[r] += __shfl_xor(p[r], st, 64);
  int lane = threadIdx.x & 63, w = threadIdx.x >> 6;
  if (lane == 0) {
#pragma unroll
    for (int r = 0; r < 16; ++r) red[w][r] = p[r];
  }
  __syncthreads();
  if (threadIdx.x < 64) {
    if (threadIdx.x < 16) {
      int r = threadIdx.x;
      float t = red[0][r] + red[1][r] + red[2][r] + red[3][r] + Wod[3072L * 16 + r];
      tail[r] = f2bf(t);
    } else {
      tail[threadIdx.x] = 0;
    }
  }
}

// ---------------- generic 128-col-tile GEMM -> f32 (IP partials, K-split via z) ----------------
template <int BM, int MI, int NI>
__launch_bounds__(256)
__global__ void gemm_f32(const u16* __restrict__ A, int lda,
                         const u16* __restrict__ B, int ldb,
                         float* __restrict__ C, int ldc,
                         const float* __restrict__ bias, int KC, long cstride) {
  constexpr int WCOLS = 128 / (NI * 16);
  constexpr int ABYTES = BM * 128;
  __shared__ char smem[ABYTES + 128 * 128];
  char* As = smem;
  char* Bs = smem + ABYTES;
  const int tid = threadIdx.x;
  const int w = tid >> 6, lane = tid & 63;
  const int lr = lane & 15, lg = lane >> 4;
  const int wr = w / WCOLS, wc = w % WCOLS;
  const int nbx = gridDim.x;
  const int nwg = nbx * gridDim.y;
  const int flat = blockIdx.y * nbx + blockIdx.x;
  const int swz = (flat & 7) * (nwg >> 3) + (flat >> 3);
  const long m0 = (long)(swz % nbx) * BM;
  const long n0 = (long)(swz / nbx) * 128;
  const int k0 = blockIdx.z * KC;
  C += blockIdx.z * cstride;
  f32x4 acc[MI][NI] = {};
  constexpr int ACH = BM / 32;
  for (int kb = k0; kb < k0 + KC; kb += 64) {
    __syncthreads();
#pragma unroll
    for (int i = 0; i < ACH; ++i) {
      int x = (tid + 256 * i) * 16;
      int row = x >> 7;
      int sx = x ^ ((row & 7) << 4);
      async16((const char*)(A + (m0 + row) * lda + kb) + (sx & 127),
              As + ((w << 10) + (i << 12)));
    }
#pragma unroll
    for (int i = 0; i < 4; ++i) {
      int x = (tid + 256 * i) * 16;
      int row = x >> 7;
      int sx = x ^ ((row & 7) << 4);
      async16((const char*)(B + (n0 + row) * ldb + kb) + (sx & 127),
              Bs + ((w << 10) + (i << 12)));
    }
    __syncthreads();
#pragma unroll
    for (int kc = 0; kc < 2; ++kc) {
      s16x8 af[MI], bfr[NI];
#pragma unroll
      for (int mi = 0; mi < MI; ++mi) {
        int row = wr * (MI * 16) + mi * 16 + lr;
        int b = ((row << 7) + kc * 64 + lg * 16) ^ ((row & 7) << 4);
        af[mi] = *(const s16x8*)(As + b);
      }
#pragma unroll
      for (int ni = 0; ni < NI; ++ni) {
        int row = wc * (NI * 16) + ni * 16 + lr;
        int b = ((row << 7) + kc * 64 + lg * 16) ^ ((row & 7) << 4);
        bfr[ni] = *(const s16x8*)(Bs + b);
      }
#pragma unroll
      for (int mi = 0; mi < MI; ++mi)
#pragma unroll
        for (int ni = 0; ni < NI; ++ni)
          acc[mi][ni] = __builtin_amdgcn_mfma_f32_16x16x32_bf16(af[mi], bfr[ni], acc[mi][ni], 0, 0, 0);
    }
  }
#pragma unroll
  for (int mi = 0; mi < MI; ++mi) {
#pragma unroll
    for (int ni = 0; ni < NI; ++ni) {
      long col = n0 + wc * (NI * 16) + ni * 16 + lr;
      float bv = bias ? bias[col] : 0.f;
#pragma unroll
      for (int j = 0; j < 4; ++j) {
        long row = m0 + wr * (MI * 16) + mi * 16 + lg * 4 + j;
        C[row * ldc + col] = acc[mi][ni][j] + bv;
      }
    }
  }
}

// ---------------- IP: sum 4 K-split partials + RMS + to_heads ----------------
__launch_bounds__(256)
__global__ void rms_ip(const float* __restrict__ in, u16* __restrict__ Ko,
                       u16* __restrict__ Vo) {
  const int t = blockIdx.x & 63;
  const int vhalf = blockIdx.x >> 6;
  const int col0 = vhalf ? 3072 : 0;
  u16* out = vhalf ? Vo : Ko;
  const int w = threadIdx.x >> 6, lane = threadIdx.x & 63;
  const long ps = 64LL * 6144;
#pragma unroll
  for (int hh = 0; hh < 6; ++hh) {
    int h = w * 6 + hh;
    const float* x = in + (long)t * 6144 + col0 + h * 128 + lane * 2;
    float a = x[0] + x[ps] + x[2 * ps] + x[3 * ps];
    float b = x[1] + x[1 + ps] + x[1 + 2 * ps] + x[1 + 3 * ps];
    float scale = 1.f;
    if (!vhalf) {
      float ss = a * a + b * b;
#pragma unroll
      for (int st = 1; st < 64; st <<= 1) ss += __shfl_xor(ss, st, 64);
      scale = rsqrtf(ss * (1.f / 128.f) + 1e-5f);
    }
    unsigned pa = f2bf(a * scale), pb = f2bf(b * scale);
    *(unsigned*)(out + ((long)h * 64 + t) * 128 + lane * 2) = pa | (pb << 16);
  }
}

// ---------------- bf16 head transpose (Vip only) ----------------
__launch_bounds__(256)
__global__ void transpose_v(const u16* __restrict__ VB, u16* __restrict__ VT, int T) {
  __shared__ u16 tile[32][34];
  int h = blockIdx.z;
  int t0 = blockIdx.x * 32, d0 = blockIdx.y * 32;
  int r = threadIdx.x >> 3, c4 = (threadIdx.x & 7) * 4;
  U16x4 v = *(const U16x4*)(VB + ((long)h * T + t0 + r) * 128 + d0 + c4);
  tile[r][c4 + 0] = v.x; tile[r][c4 + 1] = v.y;
  tile[r][c4 + 2] = v.z; tile[r][c4 + 3] = v.w;
  __syncthreads();
  U16x4 o{tile[c4 + 0][r], tile[c4 + 1][r], tile[c4 + 2][r], tile[c4 + 3][r]};
  *(U16x4*)(VT + ((long)h * 128 + d0 + r) * T + t0 + c4) = o;
}

// ---------------- fused QKV GEMM: BM=128 x BN=128 (tile = one head), 3 blocks/CU ----------------
// grid (20,72): mx<4 -> enc (K=3072), else main (K=3136, LoRA in K).
// 4 waves 2x2 (wr: 64-row half, wc: 64-col half), acc[4][4] (64 regs -> 3 waves/SIMD).
// Epilogue: bias + RMS (shfl + cross-wave LDS) + head-split/V^T via swizzled LDS bounce.
__launch_bounds__(256, 3)
__global__ void gemm_qkv(const u16* __restrict__ Aenc, const u16* __restrict__ Amain,
                         const u16* __restrict__ Benc, const u16* __restrict__ Bmain,
                         u16* __restrict__ Qo, u16* __restrict__ Ko, u16* __restrict__ VTo,
                         const float* __restrict__ bpk) {
  __shared__ char smem[32768];  // As 16KB + Bs 16KB; epilogue reuses all 32KB
  char* As = smem;
  char* Bs = smem + 16384;
  const int tid = threadIdx.x;
  const int w = tid >> 6, lane = tid & 63;
  const int lr = lane & 15, lg = lane >> 4;
  const int wr = w >> 1, wc = w & 1;
  const int flat = blockIdx.y * 20 + blockIdx.x;  // 1440 blocks
  const int swz = (flat & 7) * 180 + (flat >> 3); // bijective (1440 = 8*180)
  const int mx = swz % 20;
  const long n0 = (long)(swz / 20) * 128;
  const u16* A;
  const u16* B;
  const float* bias;
  int lda, ldb, K, t0;
  long m0;
  if (mx < 4) {
    A = Aenc; lda = 3072; B = Benc; ldb = 3072; K = 3072; t0 = 0;
    m0 = (long)mx * 128; bias = bpk;
  } else {
    A = Amain; lda = 3136; B = Bmain; ldb = 3136; K = 3136; t0 = 512;
    m0 = (long)(mx - 4) * 128; bias = bpk + 9216;
  }
  f32x4 acc[4][4] = {};
  for (int kb = 0; kb < K; kb += 64) {
    __syncthreads();
#pragma unroll
    for (int i = 0; i < 4; ++i) {  // A: 128 rows x 128B
      int x = (tid + 256 * i) * 16;
      int row = x >> 7;
      int sx = (x & 127) ^ ((row & 7) << 4);
      async16((const char*)(A + (m0 + row) * lda + kb) + sx, As + x);
    }
#pragma unroll
    for (int i = 0; i < 4; ++i) {  // B: 128 rows x 128B
      int x = (tid + 256 * i) * 16;
      int row = x >> 7;
      int sx = (x & 127) ^ ((row & 7) << 4);
      async16((const char*)(B + (n0 + row) * ldb + kb) + sx, Bs + x);
    }
    __syncthreads();
#pragma unroll
    for (int kc = 0; kc < 2; ++kc) {
      s16x8 af[4], bfr[4];
#pragma unroll
      for (int mi = 0; mi < 4; ++mi) {
        int row = wr * 64 + mi * 16 + lr;
        af[mi] = *(const s16x8*)(As + (row << 7) + ((kc * 64 + lg * 16) ^ ((row & 7) << 4)));
      }
#pragma unroll
      for (int ni = 0; ni < 4; ++ni) {
        int row = wc * 64 + ni * 16 + lr;
        bfr[ni] = *(const s16x8*)(Bs + (row << 7) + ((kc * 64 + lg * 16) ^ ((row & 7) << 4)));
      }
#pragma unroll
      for (int mi = 0; mi < 4; ++mi)
#pragma unroll
        for (int ni = 0; ni < 4; ++ni)
          acc[mi][ni] = __builtin_amdgcn_mfma_f32_16x16x32_bf16(af[mi], bfr[ni], acc[mi][ni], 0, 0, 0);
    }
  }
  // ---- epilogue ----
  const int seg = (int)(n0 / 3072);
  const int head = (int)((n0 % 3072) >> 7);
#pragma unroll
  for (int ni = 0; ni < 4; ++ni) {
    float bv = bias[n0 + wc * 64 + ni * 16 + lr];
#pragma unroll
    for (int mi = 0; mi < 4; ++mi)
#pragma unroll
      for (int j = 0; j < 4; ++j) acc[mi][ni][j] += bv;
  }
  __syncthreads();  // GEMM LDS reads done; smem free for reuse
  float scl[4][4];
  if (seg < 2) {  // RMS over 128 dims: 16-lane shfl partial + cross-wave pair via LDS
    float* red = (float*)smem;  // [128 rows][2 halves]
#pragma unroll
    for (int mi = 0; mi < 4; ++mi)
#pragma unroll
      for (int j = 0; j < 4; ++j) {
        float s = 0.f;
#pragma unroll
        for (int ni = 0; ni < 4; ++ni) s += acc[mi][ni][j] * acc[mi][ni][j];
#pragma unroll
        for (int st = 1; st < 16; st <<= 1) s += __shfl_xor(s, st, 16);
        if (lr == 0) red[(wr * 64 + mi * 16 + lg * 4 + j) * 2 + wc] = s;
        scl[mi][j] = s;
      }
    __syncthreads();
#pragma unroll
    for (int mi = 0; mi < 4; ++mi)
#pragma unroll
      for (int j = 0; j < 4; ++j) {
        int row = wr * 64 + mi * 16 + lg * 4 + j;
        float t = red[row * 2] + red[row * 2 + 1];
        scl[mi][j] = rsqrtf(t * (1.f / 128.f) + 1e-5f);
      }
    __syncthreads();  // done reading red before bounce overwrites
  }
  // bounce: write full 128x128 head tile into swizzled 32KB LDS
  if (seg < 2) {  // [tok][d]
#pragma unroll
    for (int mi = 0; mi < 4; ++mi)
#pragma unroll
      for (int ni = 0; ni < 4; ++ni) {
        int d2 = (wc * 64 + ni * 16 + lr) * 2;
#pragma unroll
        for (int j = 0; j < 4; ++j) {
          int tok = wr * 64 + mi * 16 + lg * 4 + j;
          *(u16*)(smem + tok * 256 + (d2 ^ ((tok & 7) << 4))) =
              f2bf(acc[mi][ni][j] * scl[mi][j]);
        }
      }
  } else {  // [d][tok], 8B packed
#pragma unroll
    for (int mi = 0; mi < 4; ++mi)
#pragma unroll
      for (int ni = 0; ni < 4; ++ni) {
        int d = wc * 64 + ni * 16 + lr;
        int tok0b = (wr * 64 + mi * 16 + lg * 4) * 2;
        U16x4 o{f2bf(acc[mi][ni][0]), f2bf(acc[mi][ni][1]),
                f2bf(acc[mi][ni][2]), f2bf(acc[mi][ni][3])};
        *(U16x4*)(smem + d * 256 + (tok0b ^ ((d & 7) << 4))) = o;
      }
  }
  __syncthreads();
  // cooperative coalesced store of the 32KB tile (128 rows x 256B)
#pragma unroll
  for (int i = 0; i < 8; ++i) {
    int x = (tid + 256 * i) * 16;
    int row = x >> 8, col = x & 255;
    s16x8 vdat = *(const s16x8*)(smem + row * 256 + (col ^ ((row & 7) << 4)));
    if (seg < 2) {
      u16* g = (seg == 0 ? Qo : Ko) + ((long)head * 2560 + t0 + m0 + row) * 128;
      *(s16x8*)((char*)g + col) = vdat;
    } else {
      u16* g = VTo + ((long)head * 128 + row) * 2560 + t0 + m0;
      *(s16x8*)((char*)g + col) = vdat;
    }
  }
}

// ---------------- fused output projection: enc(Wao,K=3072) + main(Wo+lp_up,K=3136) ----------------
__launch_bounds__(256)
__global__ void gemm_out(const u16* __restrict__ Atok, const u16* __restrict__ Benc,
                         const u16* __restrict__ Bmain, float* __restrict__ outp,
                         const float* __restrict__ bao, const float* __restrict__ bo) {
  __shared__ char smem[128 * 128 + 128 * 128];
  char* As = smem;
  char* Bs = smem + 128 * 128;
  const int tid = threadIdx.x;
  const int w = tid >> 6, lane = tid & 63;
  const int lr = lane & 15, lg = lane >> 4;
  const int wr = w >> 1, wc = w & 1;
  const int flat = blockIdx.y * 20 + blockIdx.x;
  const int swz = (flat & 7) * 60 + (flat >> 3);
  const int mx = swz % 20;
  const long n0 = (long)(swz / 20) * 128;
  const u16* A;
  const u16* B;
  const float* bias;
  float* C;
  int ldb, K;
  long m0;
  if (mx < 4) {
    A = Atok; B = Benc; ldb = 3072; K = 3072; bias = bao; C = outp;
    m0 = (long)mx * 128;
  } else {
    A = Atok + 512L * 3136; B = Bmain; ldb = 3136; K = 3136; bias = bo;
    C = outp + 512L * 3072; m0 = (long)(mx - 4) * 128;
  }
  f32x4 acc[4][4] = {};
  for (int kb = 0; kb < K; kb += 64) {
    __syncthreads();
#pragma unroll
    for (int i = 0; i < 4; ++i) {
      int x = (tid + 256 * i) * 16;
      int row = x >> 7;
      int sx = x ^ ((row & 7) << 4);
      async16((const char*)(A + (m0 + row) * 3136 + kb) + (sx & 127),
              As + ((w << 10) + (i << 12)));
    }
#pragma unroll
    for (int i = 0; i < 4; ++i) {
      int x = (tid + 256 * i) * 16;
      int row = x >> 7;
      int sx = x ^ ((row & 7) << 4);
      async16((const char*)(B + (n0 + row) * ldb + kb) + (sx & 127),
              Bs + ((w << 10) + (i << 12)));
    }
    __syncthreads();
#pragma unroll
    for (int kc = 0; kc < 2; ++kc) {
      s16x8 af[4], bfr[4];
#pragma unroll
      for (int mi = 0; mi < 4; ++mi) {
        int row = wr * 64 + mi * 16 + lr;
        int b = ((row << 7) + kc * 64 + lg * 16) ^ ((row & 7) << 4);
        af[mi] = *(const s16x8*)(As + b);
      }
#pragma unroll
      for (int ni = 0; ni < 4; ++ni) {
        int row = wc * 64 + ni * 16 + lr;
        int b = ((row << 7) + kc * 64 + lg * 16) ^ ((row & 7) << 4);
        bfr[ni] = *(const s16x8*)(Bs + b);
      }
#pragma unroll
      for (int mi = 0; mi < 4; ++mi)
#pragma unroll
        for (int ni = 0; ni < 4; ++ni)
          acc[mi][ni] = __builtin_amdgcn_mfma_f32_16x16x32_bf16(af[mi], bfr[ni], acc[mi][ni], 0, 0, 0);
    }
  }
#pragma unroll
  for (int mi = 0; mi < 4; ++mi) {
#pragma unroll
    for (int ni = 0; ni < 4; ++ni) {
      long col = n0 + wc * 64 + ni * 16 + lr;
      float bv = bias[col];
#pragma unroll
      for (int j = 0; j < 4; ++j) {
        long row = m0 + wr * 64 + mi * 16 + lg * 4 + j;
        C[row * 3072 + col] = acc[mi][ni][j] + bv;
      }
    }
  }
}

// ---------------- attn MEGA: attention + Wao/Wo transpose + lp_up tail fill ----------------
// blocks [0,480): attention (long q-blocks first); [480,9696): Wao/Wo transpose
// (2 tiles per 512-thr block); [9696,10080): fill Wo K-tail with lp_up.
__launch_bounds__(512, 2)
__global__ void attn_mega(const u16* __restrict__ QB, const u16* __restrict__ KB,
                          const u16* __restrict__ VT, const u16* __restrict__ KipB,
                          const u16* __restrict__ VipT, u16* __restrict__ OutTok,
                          const float* __restrict__ Wao, const float* __restrict__ Wo,
                          u16* __restrict__ WTbE, u16* __restrict__ WTbM,
                          const float* __restrict__ lp_up) {
  __shared__ char smem[81920];
  const int bf = blockIdx.x;
  const int tid = threadIdx.x;
  if (bf >= 480) {
    if (bf < 9696) {  // weight transpose: 2 tiles per block
      int t2 = (bf - 480) * 2 + (tid >> 8);  // 0..18431
      int mat = t2 / 9216, tile = t2 % 9216;
      const float* src = mat ? Wo : Wao;
      u16* dst = mat ? WTbM : WTbE;
      const int ldd = mat ? 3136 : 3072;
      float (*tl2)[32][33] = (float(*)[32][33])smem;
      int half = tid >> 8, lt = tid & 255;
      int k0 = (tile / 96) * 32, n0t = (tile % 96) * 32;
      int r = lt >> 3, c4 = (lt & 7) * 4;
      float4 v = *(const float4*)(src + (long)(k0 + r) * 3072 + n0t + c4);
      tl2[half][r][c4 + 0] = v.x; tl2[half][r][c4 + 1] = v.y;
      tl2[half][r][c4 + 2] = v.z; tl2[half][r][c4 + 3] = v.w;
      __syncthreads();
      U16x4 o{f2bf(tl2[half][c4 + 0][r]), f2bf(tl2[half][c4 + 1][r]),
              f2bf(tl2[half][c4 + 2][r]), f2bf(tl2[half][c4 + 3][r])};
      *(U16x4*)(dst + (long)(n0t + r) * ldd + k0 + c4) = o;
    } else {  // Wo K-tail = lp_up
      int idx = (bf - 9696) * 512 + tid;  // 3072*64
      int n = idx >> 6, i = idx & 63;
      float v = (i < 16) ? lp_up[(long)i * 3072 + n] : 0.f;
      WTbM[(long)n * 3136 + 3072 + i] = f2bf(v);
    }
    return;
  }
  // ---- attention ----
  const int w = tid >> 6, lane = tid & 63;
  const int lr = lane & 15, lg = lane >> 4;
  int h, qb;
  if (bf < 288) { h = bf / 12; qb = bf % 12; }       // long blocks (40 KV tiles)
  else { int s = bf - 288; h = s / 8; qb = 12 + s % 8; }  // short (16 tiles)
  const int q0 = qb * 128;
  const bool ip = (q0 >= 512);
  const u16* Qrow = QB + (long)(h * 2560 + q0 + w * 16 + lr) * 128;
  s16x8 qf[4];
#pragma unroll
  for (int dc = 0; dc < 4; ++dc) qf[dc] = *(const s16x8*)(Qrow + dc * 32 + lg * 8);
  f32x4 accO[8] = {};
  float l_r[4] = {0.f, 0.f, 0.f, 0.f};
  const int kv0 = (q0 >= 1536) ? 1536 : 0;
  const float sc = 0.08838834764831845f;

  auto stage_main = [&](int kv, int buf) {
#pragma unroll
    for (int i = 0; i < 2; ++i) {
      int x = (tid + 512 * i) * 16;
      int row = x >> 8;
      int sx = x ^ ((row & 7) << 4);
      async16((const char*)(KB + (long)(h * 2560 + kv + row) * 128) + (sx & 255),
              smem + buf * 16384 + ((i << 13) + (w << 10)));
    }
#pragma unroll
    for (int i = 0; i < 2; ++i) {
      int x = (tid + 512 * i) * 16;
      int row = x >> 7;
      int sx = x ^ ((row & 7) << 4);
      async16((const char*)(VT + (long)(h * 128 + row) * 2560 + kv) + (sx & 127),
              smem + 32768 + buf * 16384 + ((i << 13) + (w << 10)));
    }
  };
  auto stage_ip = [&](int buf) {
#pragma unroll
    for (int i = 0; i < 2; ++i) {
      int x = (tid + 512 * i) * 16;
      int row = x >> 8;
      int sx = x ^ ((row & 7) << 4);
      async16((const char*)(KipB + (long)(h * 64 + row) * 128) + (sx & 255),
              smem + buf * 16384 + ((i << 13) + (w << 10)));
    }
#pragma unroll
    for (int i = 0; i < 2; ++i) {
      int x = (tid + 512 * i) * 16;
      int row = x >> 7;
      int sx = x ^ ((row & 7) << 4);
      async16((const char*)(VipT + (long)(h * 128 + row) * 64) + (sx & 127),
              smem + 32768 + buf * 16384 + ((i << 13) + (w << 10)));
    }
  };

  stage_main(kv0, 0);
  __syncthreads();
  int cur = 0;
  for (int kv = kv0; kv < 2560; kv += 64) {
    if (kv + 64 < 2560) stage_main(kv + 64, cur ^ 1);
    else if (ip) stage_ip(cur ^ 1);
    const char* Ks = smem + cur * 16384;
    const char* Vs = smem + 32768 + cur * 16384;
    char* Pw = smem + 65536 + w * 2048;
    f32x4 s[4] = {};
    __builtin_amdgcn_s_setprio(1);
#pragma unroll
    for (int kt = 0; kt < 4; ++kt)
#pragma unroll
      for (int dc = 0; dc < 4; ++dc) {
        int row = kt * 16 + lr;
        int b = ((row << 8) + dc * 64 + lg * 16) ^ ((row & 7) << 4);
        s16x8 kf = *(const s16x8*)(Ks + b);
        s[kt] = __builtin_amdgcn_mfma_f32_16x16x32_bf16(qf[dc], kf, s[kt], 0, 0, 0);
      }
    __builtin_amdgcn_s_setprio(0);
#pragma unroll
    for (int kt = 0; kt < 4; ++kt)
#pragma unroll
      for (int j = 0; j < 4; ++j) {
        float pv = __expf(fmaf(s[kt][j], sc, -12.0f));
        l_r[j] += pv;
        int prow = lg * 4 + j;
        int b = ((prow << 7) + (kt * 16 + lr) * 2) ^ ((prow & 7) << 4);
        *(u16*)(Pw + b) = f2bf(pv);
      }
    asm volatile("s_waitcnt lgkmcnt(0)" ::: "memory");
    __builtin_amdgcn_s_setprio(1);
#pragma unroll
    for (int kc = 0; kc < 2; ++kc) {
      int pb = ((lr << 7) + kc * 64 + lg * 16) ^ ((lr & 7) << 4);
      s16x8 pf = *(const s16x8*)(Pw + pb);
#pragma unroll
      for (int dt = 0; dt < 8; ++dt) {
        int row = dt * 16 + lr;
        int b = ((row << 7) + kc * 64 + lg * 16) ^ ((row & 7) << 4);
        s16x8 vf = *(const s16x8*)(Vs + b);
        accO[dt] = __builtin_amdgcn_mfma_f32_16x16x32_bf16(pf, vf, accO[dt], 0, 0, 0);
      }
    }
    __builtin_amdgcn_s_setprio(0);
    __syncthreads();
    cur ^= 1;
  }
#pragma unroll
  for (int j = 0; j < 4; ++j) {
#pragma unroll
    for (int st = 1; st < 16; st <<= 1) l_r[j] += __shfl_xor(l_r[j], st, 16);
    l_r[j] = 1.f / l_r[j];
  }
#pragma unroll
  for (int dt = 0; dt < 8; ++dt)
#pragma unroll
    for (int j = 0; j < 4; ++j) accO[dt][j] *= l_r[j];
  if (ip) {
    const char* Ks = smem + cur * 16384;
    const char* Vs = smem + 32768 + cur * 16384;
    char* Pw = smem + 65536 + w * 2048;
    f32x4 s2[4] = {};
#pragma unroll
    for (int kt = 0; kt < 4; ++kt)
#pragma unroll
      for (int dc = 0; dc < 4; ++dc) {
        int row = kt * 16 + lr;
        int b = ((row << 8) + dc * 64 + lg * 16) ^ ((row & 7) << 4);
        s16x8 kf = *(const s16x8*)(Ks + b);
        s2[kt] = __builtin_amdgcn_mfma_f32_16x16x32_bf16(qf[dc], kf, s2[kt], 0, 0, 0);
      }
    float p2[4][4];
    float l2[4] = {0.f, 0.f, 0.f, 0.f};
#pragma unroll
    for (int kt = 0; kt < 4; ++kt)
#pragma unroll
      for (int j = 0; j < 4; ++j) {
        float pv = __expf(fmaf(s2[kt][j], sc, -12.0f));
        p2[kt][j] = pv;
        l2[j] += pv;
      }
#pragma unroll
    for (int j = 0; j < 4; ++j) {
#pragma unroll
      for (int st = 1; st < 16; st <<= 1) l2[j] += __shfl_xor(l2[j], st, 16);
      l2[j] = 1.f / l2[j];
    }
#pragma unroll
    for (int kt = 0; kt < 4; ++kt)
#pragma unroll
      for (int j = 0; j < 4; ++j) {
        int prow = lg * 4 + j;
        int b = ((prow << 7) + (kt * 16 + lr) * 2) ^ ((prow & 7) << 4);
        *(u16*)(Pw + b) = f2bf(p2[kt][j] * l2[j]);
      }
    asm volatile("s_waitcnt lgkmcnt(0)" ::: "memory");
#pragma unroll
    for (int kc = 0; kc < 2; ++kc) {
      int pb = ((lr << 7) + kc * 64 + lg * 16) ^ ((lr & 7) << 4);
      s16x8 pf = *(const s16x8*)(Pw + pb);
#pragma unroll
      for (int dt = 0; dt < 8; ++dt) {
        int row = dt * 16 + lr;
        int b = ((row << 7) + kc * 64 + lg * 16) ^ ((row & 7) << 4);
        s16x8 vf = *(const s16x8*)(Vs + b);
        accO[dt] = __builtin_amdgcn_mfma_f32_16x16x32_bf16(pf, vf, accO[dt], 0, 0, 0);
      }
    }
  }
#pragma unroll
  for (int j = 0; j < 4; ++j) {
    long tok = q0 + w * 16 + lg * 4 + j;
#pragma unroll
    for (int dt = 0; dt < 8; ++dt) {
      long col = h * 128 + dt * 16 + lr;
      OutTok[tok * 3136 + col] = f2bf(accO[dt][j]);
    }
  }
}

// =====================================================================

extern "C" void kernel_launch(void* const* d_in, const int* in_sizes, int n_in,
                              void* d_out, int out_size, void* d_ws, size_t ws_size,
                              hipStream_t stream) {
  const float* hs    = (const float*)d_in[0];
  const float* ehs   = (const float*)d_in[1];
  const float* img   = (const float*)d_in[2];
  const float* Wq    = (const float*)d_in[3];
  const float* bq    = (const float*)d_in[4];
  const float* Wk    = (const float*)d_in[5];
  const float* bk    = (const float*)d_in[6];
  const float* Wv    = (const float*)d_in[7];
  const float* bv    = (const float*)d_in[8];
  const float* Waq   = (const float*)d_in[9];
  const float* baq   = (const float*)d_in[10];
  const float* Wak   = (const float*)d_in[11];
  const float* bak   = (const float*)d_in[12];
  const float* Wav   = (const float*)d_in[13];
  const float* bav   = (const float*)d_in[14];
  const float* Wo    = (const float*)d_in[15];
  const float* bo    = (const float*)d_in[16];
  const float* Wao   = (const float*)d_in[17];
  const float* bao   = (const float*)d_in[18];
  const float* Wkip  = (const float*)d_in[19];
  const float* Wvip  = (const float*)d_in[20];
  const float* lq_dn = (const float*)d_in[21];
  const float* lq_up = (const float*)d_in[22];
  const float* lk_dn = (const float*)d_in[23];
  const float* lk_up = (const float*)d_in[24];
  const float* lv_dn = (const float*)d_in[25];
  const float* lv_up = (const float*)d_in[26];
  const float* lp_dn = (const float*)d_in[27];
  const float* lp_up = (const float*)d_in[28];
  float* outp = (float*)d_out;

  char* ws = (char*)d_ws;
  size_t off = 0;
  auto take = [&](size_t b) { char* p = ws + off; off += (b + 255) & ~(size_t)255; return p; };
  u16*   WTbE = (u16*)take(3LL * 3072 * 3072 * 2);  // enc slots (Waq,Wak,Wav -> later Wao,Wkip,Wvip)
  u16*   WTbM = (u16*)take(3LL * 3072 * 3136 * 2);  // main slots (Wq,Wk,Wv -> later Wo)
  u16*   hsb  = (u16*)take(2048LL * 3136 * 2);      // + AttnTok alias base
  u16*   ehsb = (u16*)take(512LL * 3072 * 2);
  u16*   imgb = (u16*)take(64LL * 3072 * 2);
  u16*   VTf  = (u16*)take(24LL * 128 * 2560 * 2);
  float* IP0  = (float*)take(4LL * 64 * 6144 * 4);
  u16*   KipB = (u16*)take(24LL * 64 * 128 * 2);
  u16*   VipB = (u16*)take(24LL * 64 * 128 * 2);
  u16*   VipT = (u16*)take(24LL * 128 * 64 * 2);
  float* bpk  = (float*)take(2 * 9216 * 4);
  float* tl   = (float*)take(1024LL * 48 * 4);
  float* Wod  = (float*)take(3073LL * 16 * 4);
  u16* QBf = (u16*)d_out;                        // alias: d_out dead until gemm_out
  u16* KBf = (u16*)d_out + 24LL * 2560 * 128;
  u16* AttnTok = hsb;                            // alias: hsb dead after gemm_qkv
  u16* E1 = WTbE + 3072LL * 3072;
  u16* E2 = WTbE + 2 * 3072LL * 3072;

  // 1. LoRA-down, then MEGA prep (converts + biases + tails + 6 transposes + Wod)
  lora_dn3<<<1024, 256, 0, stream>>>(hs + 1024LL * 3072, 3072, lq_dn, lk_dn, lv_dn, tl);
  mega_prep<<<64745, 256, 0, stream>>>(Waq, Wak, Wav, Wq, Wk, Wv, WTbE, WTbM,
                                       Wo, bo, lp_dn, Wod,
                                       hs, tl, hsb, ehs, ehsb, img, imgb,
                                       baq, bak, bav, bq, bk, bv, bpk,
                                       lq_up, lk_up, lv_up);

  // 2. fused enc+main QKV GEMM (1440 blocks, 3/CU)
  gemm_qkv<<<dim3(20, 72), 256, 0, stream>>>(ehsb, hsb, WTbE, WTbM, QBf, KBf, VTf, bpk);

  // 3. IP path: transpose Wkip/Wvip into E1/E2, K-split GEMM, fused sum/RMS, Vip^T
  {
    WT2 a;
    a.src[0] = Wkip; a.dst[0] = E1;
    a.src[1] = Wvip; a.dst[1] = E2;
    transpose_kv<<<dim3(96, 96, 2), 256, 0, stream>>>(a);
  }
  gemm_f32<64, 4, 2><<<dim3(1, 48, 4), 256, 0, stream>>>(imgb, 3072, E1, 3072, IP0, 6144,
                                                          nullptr, 768, 64LL * 6144);
  rms_ip<<<128, 256, 0, stream>>>(IP0, KipB, VipB);
  transpose_v<<<dim3(2, 4, 24), 256, 0, stream>>>(VipB, VipT, 64);

  // 4. attention MEGA (attn + Wao/Wo transposes + lp_up tail, co-scheduled)
  attn_mega<<<10080, 512, 0, stream>>>(QBf, KBf, VTf, KipB, VipT, AttnTok,
                                       Wao, Wo, WTbE, WTbM, lp_up);

  // 5. LoRA-p t into AttnTok K-tail, then fused output projection (lp folded in K)
  t_tail<<<2048, 256, 0, stream>>>(AttnTok, Wod);
  gemm_out<<<dim3(20, 24), 256, 0, stream>>>(AttnTok, WTbE, WTbM, outp, bao, bo);
}